// Round 1
// baseline (1656.940 us; speedup 1.0000x reference)
//
#include <hip/hip_runtime.h>
#include <math.h>

#define BB 2
#define SS 2048
#define DD 256
#define HH 8
#define DKK 32
#define DVV 32
#define DFF 512
#define NL 2
#define QB 8

static __device__ __forceinline__ float ln_eps2() { return 1.4210854715202004e-14f; }

// ---------------- Kernel 1: QKV projection ----------------
// grid = B*S blocks, 256 threads. Each thread: one (h, dk) column of q,k,v.
__global__ __launch_bounds__(256) void qkv_kernel(
    const float* __restrict__ x,
    const float* __restrict__ Wq, const float* __restrict__ Wk,
    const float* __restrict__ Wv,
    float* __restrict__ q, float* __restrict__ k, float* __restrict__ v)
{
    __shared__ float xr[DD];
    const int row = blockIdx.x;            // b*S + s
    const int tid = threadIdx.x;
    xr[tid] = x[(size_t)row * DD + tid];
    __syncthreads();

    const int h  = tid >> 5;
    const int kk = tid & 31;
    const float* wq = Wq + (size_t)(h * DD) * DKK + kk;
    const float* wk = Wk + (size_t)(h * DD) * DKK + kk;
    const float* wv = Wv + (size_t)(h * DD) * DKK + kk;

    float aq = 0.f, ak = 0.f, av = 0.f;
#pragma unroll 8
    for (int d = 0; d < DD; ++d) {
        const float xv = xr[d];
        aq += xv * wq[d * DKK];
        ak += xv * wk[d * DKK];
        av += xv * wv[d * DKK];
    }
    const int b = row / SS, s = row % SS;
    const size_t off = ((size_t)(b * HH + h) * SS + s) * DKK + kk;
    q[off] = aq; k[off] = ak; v[off] = av;
}

// ---------------- Kernel 2: attention (softmax(QK^T) V), no 1/sqrt(dk) ----------------
// grid = B*H*(S/QB) blocks, 256 threads. Scores for QB queries kept in LDS.
__global__ __launch_bounds__(256) void attn_kernel(
    const float* __restrict__ q, const float* __restrict__ k,
    const float* __restrict__ v, float* __restrict__ o)
{
    __shared__ float qs[QB][DKK];        // 1 KB
    __shared__ float sc[QB][SS];         // 64 KB
    __shared__ float red[QB][33];
    __shared__ float mx[QB], inv[QB];

    const int tid = threadIdx.x;
    const int nqb = SS / QB;             // 256
    const int bh  = blockIdx.x / nqb;    // 0..B*H-1
    const int qb  = blockIdx.x % nqb;

    const float* qp = q + ((size_t)bh * SS + (size_t)qb * QB) * DKK;
    const float* kp = k + (size_t)bh * SS * DKK;
    const float* vp = v + (size_t)bh * SS * DKK;

    // load QB query rows
    qs[tid / DKK][tid % DKK] = qp[tid];  // QB*DKK == 256
    __syncthreads();

    // scores: each thread handles 8 key rows
    for (int key = tid; key < SS; key += 256) {
        float kr[DKK];
        const float4* k4 = (const float4*)(kp + (size_t)key * DKK);
#pragma unroll
        for (int j = 0; j < DKK / 4; ++j) ((float4*)kr)[j] = k4[j];
#pragma unroll
        for (int qi = 0; qi < QB; ++qi) {
            float acc = 0.f;
#pragma unroll
            for (int d = 0; d < DKK; ++d) acc += qs[qi][d] * kr[d];
            sc[qi][key] = acc;
        }
    }
    __syncthreads();

    // softmax: 32 threads per query row
    {
        const int qi = tid >> 5, lane = tid & 31;
        float m = -1e30f;
        for (int s0 = lane; s0 < SS; s0 += 32) m = fmaxf(m, sc[qi][s0]);
        red[qi][lane] = m;
        __syncthreads();
        if (lane == 0) {
            float mm = red[qi][0];
#pragma unroll
            for (int j = 1; j < 32; ++j) mm = fmaxf(mm, red[qi][j]);
            mx[qi] = mm;
        }
        __syncthreads();
        const float mm = mx[qi];
        float sum = 0.f;
        for (int s0 = lane; s0 < SS; s0 += 32) {
            const float p = expf(sc[qi][s0] - mm);
            sc[qi][s0] = p;
            sum += p;
        }
        red[qi][lane] = sum;
        __syncthreads();
        if (lane == 0) {
            float ss = 0.f;
#pragma unroll
            for (int j = 0; j < 32; ++j) ss += red[qi][j];
            inv[qi] = 1.0f / ss;
        }
        __syncthreads();
    }

    // AV: 32 dv columns x 8 key-slices
    {
        const int dv = tid & 31, slice = tid >> 5;
        float acc[QB];
#pragma unroll
        for (int i = 0; i < QB; ++i) acc[i] = 0.f;
        const int s_beg = slice * (SS / 8), s_end = s_beg + (SS / 8);
        for (int s0 = s_beg; s0 < s_end; ++s0) {
            const float vv = vp[(size_t)s0 * DVV + dv];
#pragma unroll
            for (int i = 0; i < QB; ++i) acc[i] += sc[i][s0] * vv;
        }
        __syncthreads();                 // done reading probabilities
        float* part = (float*)sc;        // reuse as [QB][32][8]
#pragma unroll
        for (int i = 0; i < QB; ++i) part[((i * 32) + dv) * 8 + slice] = acc[i];
        __syncthreads();
        if (tid < QB * 32) {
            const int i = tid >> 5, d2 = tid & 31;
            float ssum = 0.f;
#pragma unroll
            for (int j = 0; j < 8; ++j) ssum += part[((i * 32) + d2) * 8 + j];
            const int bhq = blockIdx.x / nqb;
            o[((size_t)bhq * SS + (size_t)qb * QB + i) * DVV + d2] = ssum * inv[i];
        }
    }
}

// ---------------- Kernel 3: concat-heads @ Wo + residual + LayerNorm ----------------
__global__ __launch_bounds__(256) void proj_ln_kernel(
    const float* __restrict__ xin, const float* __restrict__ o,
    const float* __restrict__ Wo, const float* __restrict__ gamma,
    const float* __restrict__ beta, float* __restrict__ xout)
{
    __shared__ float cr[DD];
    __shared__ float red[256];
    const int row = blockIdx.x;
    const int tid = threadIdx.x;
    const int b = row / SS, s = row % SS;
    const int h = tid >> 5, dv = tid & 31;
    cr[tid] = o[((size_t)(b * HH + h) * SS + s) * DVV + dv]; // conc[h*32+dv]
    __syncthreads();

    float acc = 0.f;
#pragma unroll 8
    for (int c = 0; c < DD; ++c) acc += cr[c] * Wo[(size_t)c * DD + tid];
    const float y = xin[(size_t)row * DD + tid] + acc;

    // LayerNorm over D=256
    red[tid] = y; __syncthreads();
    for (int st = 128; st > 0; st >>= 1) { if (tid < st) red[tid] += red[tid + st]; __syncthreads(); }
    const float mean = red[0] * (1.0f / DD);
    __syncthreads();
    const float dy = y - mean;
    red[tid] = dy * dy; __syncthreads();
    for (int st = 128; st > 0; st >>= 1) { if (tid < st) red[tid] += red[tid + st]; __syncthreads(); }
    const float var = red[0] * (1.0f / DD);
    const float r = 1.0f / sqrtf(var + ln_eps2());
    xout[(size_t)row * DD + tid] = dy * r * gamma[0] + beta[0];
}

// ---------------- Kernel 4: FFN (relu(xW1+b1)W2+b2) + residual + LayerNorm ----------------
__global__ __launch_bounds__(256) void ffn_ln_kernel(
    const float* __restrict__ xin, const float* __restrict__ W1,
    const float* __restrict__ b1, const float* __restrict__ W2,
    const float* __restrict__ b2, const float* __restrict__ gamma,
    const float* __restrict__ beta, float* __restrict__ xout)
{
    __shared__ float xr[DD];
    __shared__ float hid[DFF];
    __shared__ float red[256];
    const int row = blockIdx.x;
    const int tid = threadIdx.x;
    xr[tid] = xin[(size_t)row * DD + tid];
    __syncthreads();

#pragma unroll
    for (int r2 = 0; r2 < 2; ++r2) {
        const int f = tid + r2 * 256;
        float acc = b1[f];
#pragma unroll 8
        for (int d = 0; d < DD; ++d) acc += xr[d] * W1[(size_t)d * DFF + f];
        hid[f] = fmaxf(acc, 0.0f);
    }
    __syncthreads();

    float acc = b2[tid];
#pragma unroll 8
    for (int f = 0; f < DFF; ++f) acc += hid[f] * W2[(size_t)f * DD + tid];
    const float y = xr[tid] + acc;

    red[tid] = y; __syncthreads();
    for (int st = 128; st > 0; st >>= 1) { if (tid < st) red[tid] += red[tid + st]; __syncthreads(); }
    const float mean = red[0] * (1.0f / DD);
    __syncthreads();
    const float dy = y - mean;
    red[tid] = dy * dy; __syncthreads();
    for (int st = 128; st > 0; st >>= 1) { if (tid < st) red[tid] += red[tid + st]; __syncthreads(); }
    const float var = red[0] * (1.0f / DD);
    const float r = 1.0f / sqrtf(var + ln_eps2());
    xout[(size_t)row * DD + tid] = dy * r * gamma[0] + beta[0];
}

// ---------------- host launch ----------------
extern "C" void kernel_launch(void* const* d_in, const int* in_sizes, int n_in,
                              void* d_out, int out_size, void* d_ws, size_t ws_size,
                              hipStream_t stream) {
    const float* x     = (const float*)d_in[0];
    const float* Wq    = (const float*)d_in[1];
    const float* Wk    = (const float*)d_in[2];
    const float* Wv    = (const float*)d_in[3];
    const float* Wo    = (const float*)d_in[4];
    const float* W1    = (const float*)d_in[5];
    const float* b1    = (const float*)d_in[6];
    const float* W2    = (const float*)d_in[7];
    const float* b2    = (const float*)d_in[8];
    const float* gamma = (const float*)d_in[9];
    const float* beta  = (const float*)d_in[10];
    float* out = (float*)d_out;
    float* ws  = (float*)d_ws;

    const size_t NTOK = (size_t)BB * SS * DD;   // 1,048,576 floats
    float* q  = ws;
    float* k  = ws + NTOK;
    float* v  = ws + 2 * NTOK;
    float* o  = ws + 3 * NTOK;
    float* xa = ws + 4 * NTOK;
    float* xb = ws + 5 * NTOK;

    const float* cur = x;
    for (int l = 0; l < NL; ++l) {
        const float* wq = Wq + (size_t)l * HH * DD * DKK;
        const float* wk = Wk + (size_t)l * HH * DD * DKK;
        const float* wv = Wv + (size_t)l * HH * DD * DKK;
        const float* wo = Wo + (size_t)l * (HH * DVV) * DD;
        const float* w1 = W1 + (size_t)l * DD * DFF;
        const float* w2 = W2 + (size_t)l * DFF * DD;

        qkv_kernel<<<BB * SS, 256, 0, stream>>>(cur, wq, wk, wv, q, k, v);
        attn_kernel<<<BB * HH * (SS / QB), 256, 0, stream>>>(q, k, v, o);
        proj_ln_kernel<<<BB * SS, 256, 0, stream>>>(cur, o, wo,
                                                    gamma + 2 * l, beta + 2 * l, xa);
        float* nxt = (l == NL - 1) ? out : xb;
        ffn_ln_kernel<<<BB * SS, 256, 0, stream>>>(xa, w1, b1 + (size_t)l * DFF, w2,
                                                   b2 + (size_t)l * DD,
                                                   gamma + 2 * l + 1, beta + 2 * l + 1, nxt);
        cur = nxt;
    }
}

// Round 4
// 453.424 us; speedup vs baseline: 3.6543x; 3.6543x over previous
//
#include <hip/hip_runtime.h>
#include <math.h>

#define BB 2
#define SS 2048
#define DD 256
#define HH 8
#define DKK 32
#define DVV 32
#define DFF 512
#define NL 2
#define RB 4

// attention tiling
#define KT 128          // keys per LDS tile
#define KSTR 40         // K tile row stride (elements), 80 B: 16B-aligned frags, 2-way banks
#define VSTR 136        // V^T row stride (elements), 272 B: 16B-aligned, 2-way banks
#define PSTR 136        // P row stride

typedef __attribute__((ext_vector_type(8))) short short8;
typedef __attribute__((ext_vector_type(4))) float f32x4;

static __device__ __forceinline__ float ln_eps2() { return 1.4210854715202004e-14f; }

static __device__ __forceinline__ ushort f2bf(float f) {
    union { float f; unsigned u; } c; c.f = f;
    unsigned r = c.u + 0x7FFFu + ((c.u >> 16) & 1u);   // RNE
    return (ushort)(r >> 16);
}
static __device__ __forceinline__ float bf2f(ushort h) {
    union { unsigned u; float f; } c; c.u = ((unsigned)h) << 16;
    return c.f;
}

static __device__ __forceinline__ float block_sum256(float val, float* red4) {
#pragma unroll
    for (int m = 32; m >= 1; m >>= 1) val += __shfl_xor(val, m);
    const int wid = threadIdx.x >> 6;
    __syncthreads();                       // protect red4 from previous use
    if ((threadIdx.x & 63) == 0) red4[wid] = val;
    __syncthreads();
    return red4[0] + red4[1] + red4[2] + red4[3];
}

// ---------------- Kernel 1: QKV projection, RB rows per block ----------------
__global__ __launch_bounds__(256) void qkv_kernel(
    const float* __restrict__ x,
    const float* __restrict__ Wq, const float* __restrict__ Wk,
    const float* __restrict__ Wv,
    float* __restrict__ q, float* __restrict__ k, float* __restrict__ v)
{
    __shared__ float xr[RB][DD];
    const int row0 = blockIdx.x * RB;
    const int tid = threadIdx.x;
#pragma unroll
    for (int r = 0; r < RB; ++r) xr[r][tid] = x[(size_t)(row0 + r) * DD + tid];
    __syncthreads();

    const int h  = tid >> 5;
    const int kk = tid & 31;
    const float* wq = Wq + (size_t)(h * DD) * DKK + kk;
    const float* wk = Wk + (size_t)(h * DD) * DKK + kk;
    const float* wv = Wv + (size_t)(h * DD) * DKK + kk;

    float aq[RB], ak[RB], av[RB];
#pragma unroll
    for (int r = 0; r < RB; ++r) { aq[r] = 0.f; ak[r] = 0.f; av[r] = 0.f; }

#pragma unroll 4
    for (int d = 0; d < DD; ++d) {
        const float wqd = wq[d * DKK];
        const float wkd = wk[d * DKK];
        const float wvd = wv[d * DKK];
#pragma unroll
        for (int r = 0; r < RB; ++r) {
            const float xv = xr[r][d];
            aq[r] += xv * wqd; ak[r] += xv * wkd; av[r] += xv * wvd;
        }
    }
    const int b = row0 / SS, s0 = row0 % SS;
#pragma unroll
    for (int r = 0; r < RB; ++r) {
        const size_t off = ((size_t)(b * HH + h) * SS + s0 + r) * DKK + kk;
        q[off] = aq[r]; k[off] = ak[r]; v[off] = av[r];
    }
}

// ---------------- Kernel 2: MFMA flash attention (hi/lo split QK^T) ----------------
// grid = B*H*(S/64); 256 threads = 4 waves, each wave owns 16 queries.
__global__ __launch_bounds__(256) void attn_mfma_kernel(
    const float* __restrict__ q, const float* __restrict__ k,
    const float* __restrict__ v, float* __restrict__ o)
{
    __shared__ ushort KhS[KT * KSTR];        // 10240 B  K tile hi
    __shared__ ushort KlS[KT * KSTR];        // 10240 B  K tile lo
    __shared__ ushort VtS[32 * VSTR];        //  8704 B  transposed V
    __shared__ ushort PlS[4 * 16 * PSTR];    // 17408 B  per-wave P

    const int tid  = threadIdx.x;
    const int wave = tid >> 6;
    const int lane = tid & 63;
    const int c16  = lane & 15;
    const int g    = lane >> 4;

    const int nqb = SS / 64;                 // 32
    const int bh  = blockIdx.x / nqb;
    const int qb  = blockIdx.x % nqb;
    const int qbase = qb * 64 + wave * 16;

    const float* qp = q + (size_t)bh * SS * DKK;
    const float* kp = k + (size_t)bh * SS * DKK;
    const float* vp = v + (size_t)bh * SS * DKK;

    // Q fragments hi/lo: A row = qbase + c16, k-elements g*8..g*8+7
    short8 qhi, qlo;
    {
        const float* qr = qp + (size_t)(qbase + c16) * DKK + g * 8;
#pragma unroll
        for (int j = 0; j < 8; ++j) {
            const ushort h = f2bf(qr[j]);
            qhi[j] = (short)h;
            qlo[j] = (short)f2bf(qr[j] - bf2f(h));
        }
    }

    float m_r[4], l_r[4];
    f32x4 oacc0, oacc1;
#pragma unroll
    for (int r = 0; r < 4; ++r) { m_r[r] = -1e30f; l_r[r] = 0.f; }
    oacc0 = (f32x4)(0.f); oacc1 = (f32x4)(0.f);
    const f32x4 zero = (f32x4)(0.f);

    ushort* Pw = PlS + wave * 16 * PSTR;

    for (int kt = 0; kt < SS; kt += KT) {
        // ---- stage K tile hi/lo (bf16, [128][KSTR]) ----
#pragma unroll
        for (int i = 0; i < 8; ++i) {
            const int p = i * 256 + tid;       // 0..2047 float2-pairs
            const int row = p >> 4;            // 0..127
            const int col2 = (p & 15) * 2;     // 0..30
            const float2 f2 = *(const float2*)(kp + (size_t)(kt + row) * DKK + col2);
            ushort2 uh, ul;
            uh.x = f2bf(f2.x); ul.x = f2bf(f2.x - bf2f(uh.x));
            uh.y = f2bf(f2.y); ul.y = f2bf(f2.y - bf2f(uh.y));
            *(ushort2*)&KhS[row * KSTR + col2] = uh;
            *(ushort2*)&KlS[row * KSTR + col2] = ul;
        }
        // ---- stage V tile transposed (bf16, [32][VSTR]) ----
#pragma unroll
        for (int i = 0; i < 8; ++i) {
            const int p = i * 256 + tid;       // 0..2047
            const int col = p & 31;            // dv
            const int s2 = (p >> 5) * 2;       // 0..126
            const float a = vp[(size_t)(kt + s2) * DVV + col];
            const float b = vp[(size_t)(kt + s2 + 1) * DVV + col];
            ushort2 u; u.x = f2bf(a); u.y = f2bf(b);
            *(ushort2*)&VtS[col * VSTR + s2] = u;
        }
        __syncthreads();

        // ---- QK^T: 16 queries x 128 keys, fp32-quality via hi/lo split ----
        f32x4 sc[8];
#pragma unroll
        for (int t = 0; t < 8; ++t) {
            const short8 khi = *(const short8*)&KhS[(t * 16 + c16) * KSTR + g * 8];
            const short8 klo = *(const short8*)&KlS[(t * 16 + c16) * KSTR + g * 8];
            f32x4 s = __builtin_amdgcn_mfma_f32_16x16x32_bf16(qlo, khi, zero, 0, 0, 0);
            s = __builtin_amdgcn_mfma_f32_16x16x32_bf16(qhi, klo, s, 0, 0, 0);
            s = __builtin_amdgcn_mfma_f32_16x16x32_bf16(qhi, khi, s, 0, 0, 0);
            sc[t] = s;
        }

        // ---- online softmax (D layout: col=key=c16, row=query=4g+r) ----
#pragma unroll
        for (int r = 0; r < 4; ++r) {
            float tm = sc[0][r];
#pragma unroll
            for (int t = 1; t < 8; ++t) tm = fmaxf(tm, sc[t][r]);
            tm = fmaxf(tm, __shfl_xor(tm, 1));
            tm = fmaxf(tm, __shfl_xor(tm, 2));
            tm = fmaxf(tm, __shfl_xor(tm, 4));
            tm = fmaxf(tm, __shfl_xor(tm, 8));
            const float nm = fmaxf(m_r[r], tm);
            const float scale = __expf(m_r[r] - nm);
            m_r[r] = nm;
            float psum = 0.f;
#pragma unroll
            for (int t = 0; t < 8; ++t) {
                const float p = __expf(sc[t][r] - nm);
                sc[t][r] = p;
                psum += p;
            }
            psum += __shfl_xor(psum, 1);
            psum += __shfl_xor(psum, 2);
            psum += __shfl_xor(psum, 4);
            psum += __shfl_xor(psum, 8);
            l_r[r] = l_r[r] * scale + psum;
            oacc0[r] *= scale;
            oacc1[r] *= scale;
        }

        // ---- write P to per-wave LDS in A-operand layout ----
#pragma unroll
        for (int t = 0; t < 8; ++t)
#pragma unroll
            for (int r = 0; r < 4; ++r)
                Pw[(g * 4 + r) * PSTR + t * 16 + c16] = f2bf(sc[t][r]);

        // ---- PV: 4 s-slices x 2 dv-halves ----
#pragma unroll
        for (int s4 = 0; s4 < 4; ++s4) {
            const short8 pfrag  = *(const short8*)&Pw[c16 * PSTR + s4 * 32 + g * 8];
            const short8 vfrag0 = *(const short8*)&VtS[c16 * VSTR + s4 * 32 + g * 8];
            const short8 vfrag1 = *(const short8*)&VtS[(16 + c16) * VSTR + s4 * 32 + g * 8];
            oacc0 = __builtin_amdgcn_mfma_f32_16x16x32_bf16(pfrag, vfrag0, oacc0, 0, 0, 0);
            oacc1 = __builtin_amdgcn_mfma_f32_16x16x32_bf16(pfrag, vfrag1, oacc1, 0, 0, 0);
        }
        __syncthreads();   // all waves done reading tiles before restage
    }

    // ---- epilogue ----
#pragma unroll
    for (int r = 0; r < 4; ++r) {
        const float invl = 1.0f / l_r[r];
        const int qrow = qbase + g * 4 + r;
        float* op = o + ((size_t)bh * SS + qrow) * DVV;
        op[c16]      = oacc0[r] * invl;
        op[16 + c16] = oacc1[r] * invl;
    }
}

// ---------------- Kernel 3: concat @ Wo + residual + LN, RB rows ----------------
__global__ __launch_bounds__(256) void proj_ln_kernel(
    const float* __restrict__ xin, const float* __restrict__ o,
    const float* __restrict__ Wo, const float* __restrict__ gamma,
    const float* __restrict__ beta, float* __restrict__ xout)
{
    __shared__ float cr[RB][DD];
    __shared__ float red4[4];
    const int row0 = blockIdx.x * RB;
    const int tid = threadIdx.x;
    const int b = row0 / SS, s0 = row0 % SS;
    const int h = tid >> 5, dv = tid & 31;
#pragma unroll
    for (int r = 0; r < RB; ++r)
        cr[r][tid] = o[((size_t)(b * HH + h) * SS + s0 + r) * DVV + dv];
    __syncthreads();

    float acc[RB];
#pragma unroll
    for (int r = 0; r < RB; ++r) acc[r] = 0.f;
#pragma unroll 4
    for (int c = 0; c < DD; ++c) {
        const float w = Wo[(size_t)c * DD + tid];
#pragma unroll
        for (int r = 0; r < RB; ++r) acc[r] += cr[r][c] * w;
    }
    const float g0 = gamma[0], b0 = beta[0];
#pragma unroll
    for (int r = 0; r < RB; ++r) {
        const float y = xin[(size_t)(row0 + r) * DD + tid] + acc[r];
        const float mean = block_sum256(y, red4) * (1.0f / DD);
        const float dy = y - mean;
        const float var = block_sum256(dy * dy, red4) * (1.0f / DD);
        const float rr = 1.0f / sqrtf(var + ln_eps2());
        xout[(size_t)(row0 + r) * DD + tid] = dy * rr * g0 + b0;
    }
}

// ---------------- Kernel 4: FFN + residual + LN, RB rows ----------------
__global__ __launch_bounds__(256) void ffn_ln_kernel(
    const float* __restrict__ xin, const float* __restrict__ W1,
    const float* __restrict__ b1, const float* __restrict__ W2,
    const float* __restrict__ b2, const float* __restrict__ gamma,
    const float* __restrict__ beta, float* __restrict__ xout)
{
    __shared__ float xr[RB][DD];
    __shared__ float hid[RB][DFF];
    __shared__ float red4[4];
    const int row0 = blockIdx.x * RB;
    const int tid = threadIdx.x;
#pragma unroll
    for (int r = 0; r < RB; ++r) xr[r][tid] = xin[(size_t)(row0 + r) * DD + tid];
    __syncthreads();

    float a0[RB], a1[RB];
    const float bb0 = b1[tid], bb1 = b1[tid + 256];
#pragma unroll
    for (int r = 0; r < RB; ++r) { a0[r] = bb0; a1[r] = bb1; }
#pragma unroll 4
    for (int d = 0; d < DD; ++d) {
        const float w0 = W1[(size_t)d * DFF + tid];
        const float w1w = W1[(size_t)d * DFF + tid + 256];
#pragma unroll
        for (int r = 0; r < RB; ++r) {
            const float xv = xr[r][d];
            a0[r] += xv * w0; a1[r] += xv * w1w;
        }
    }
#pragma unroll
    for (int r = 0; r < RB; ++r) {
        hid[r][tid]       = fmaxf(a0[r], 0.f);
        hid[r][tid + 256] = fmaxf(a1[r], 0.f);
    }
    __syncthreads();

    float acc[RB];
    const float bb2 = b2[tid];
#pragma unroll
    for (int r = 0; r < RB; ++r) acc[r] = bb2;
#pragma unroll 4
    for (int f = 0; f < DFF; ++f) {
        const float w = W2[(size_t)f * DD + tid];
#pragma unroll
        for (int r = 0; r < RB; ++r) acc[r] += hid[r][f] * w;
    }
    const float g0 = gamma[0], b0 = beta[0];
#pragma unroll
    for (int r = 0; r < RB; ++r) {
        const float y = xr[r][tid] + acc[r];
        const float mean = block_sum256(y, red4) * (1.0f / DD);
        const float dy = y - mean;
        const float var = block_sum256(dy * dy, red4) * (1.0f / DD);
        const float rr = 1.0f / sqrtf(var + ln_eps2());
        xout[(size_t)(row0 + r) * DD + tid] = dy * rr * g0 + b0;
    }
}

// ---------------- host launch ----------------
extern "C" void kernel_launch(void* const* d_in, const int* in_sizes, int n_in,
                              void* d_out, int out_size, void* d_ws, size_t ws_size,
                              hipStream_t stream) {
    const float* x     = (const float*)d_in[0];
    const float* Wq    = (const float*)d_in[1];
    const float* Wk    = (const float*)d_in[2];
    const float* Wv    = (const float*)d_in[3];
    const float* Wo    = (const float*)d_in[4];
    const float* W1    = (const float*)d_in[5];
    const float* b1    = (const float*)d_in[6];
    const float* W2    = (const float*)d_in[7];
    const float* b2    = (const float*)d_in[8];
    const float* gamma = (const float*)d_in[9];
    const float* beta  = (const float*)d_in[10];
    float* out = (float*)d_out;
    float* ws  = (float*)d_ws;

    const size_t NTOK = (size_t)BB * SS * DD;
    float* q  = ws;
    float* k  = ws + NTOK;
    float* v  = ws + 2 * NTOK;
    float* o  = ws + 3 * NTOK;
    float* xa = ws + 4 * NTOK;
    float* xb = ws + 5 * NTOK;

    const float* cur = x;
    for (int l = 0; l < NL; ++l) {
        const float* wq = Wq + (size_t)l * HH * DD * DKK;
        const float* wk = Wk + (size_t)l * HH * DD * DKK;
        const float* wv = Wv + (size_t)l * HH * DD * DKK;
        const float* wo = Wo + (size_t)l * (HH * DVV) * DD;
        const float* w1 = W1 + (size_t)l * DD * DFF;
        const float* w2 = W2 + (size_t)l * DFF * DD;

        qkv_kernel<<<BB * SS / RB, 256, 0, stream>>>(cur, wq, wk, wv, q, k, v);
        attn_mfma_kernel<<<BB * HH * (SS / 64), 256, 0, stream>>>(q, k, v, o);
        proj_ln_kernel<<<BB * SS / RB, 256, 0, stream>>>(cur, o, wo,
                                                         gamma + 2 * l, beta + 2 * l, xa);
        float* nxt = (l == NL - 1) ? out : xb;
        ffn_ln_kernel<<<BB * SS / RB, 256, 0, stream>>>(xa, w1, b1 + (size_t)l * DFF, w2,
                                                        b2 + (size_t)l * DD,
                                                        gamma + 2 * l + 1, beta + 2 * l + 1, nxt);
        cur = nxt;
    }
}

// Round 5
// 391.956 us; speedup vs baseline: 4.2274x; 1.1568x over previous
//
#include <hip/hip_runtime.h>
#include <math.h>

#define BB 2
#define SS 2048
#define DD 256
#define HH 8
#define DKK 32
#define DVV 32
#define DFF 512
#define NL 2
#define RB 4

// attention tiling
#define KT 128          // keys per LDS tile
#define KSTR 40         // K tile row stride (elements), 80 B: 16B-aligned frags, 2-way banks
#define VSTR 136        // V^T row stride (elements), 272 B: 16B-aligned, 2-way banks
#define PSTR 136        // P row stride

typedef __attribute__((ext_vector_type(8))) short short8;
typedef __attribute__((ext_vector_type(4))) float f32x4;

static __device__ __forceinline__ float ln_eps2() { return 1.4210854715202004e-14f; }

static __device__ __forceinline__ ushort f2bf(float f) {
    union { float f; unsigned u; } c; c.f = f;
    unsigned r = c.u + 0x7FFFu + ((c.u >> 16) & 1u);   // RNE
    return (ushort)(r >> 16);
}
static __device__ __forceinline__ float bf2f(ushort h) {
    union { unsigned u; float f; } c; c.u = ((unsigned)h) << 16;
    return c.f;
}

static __device__ __forceinline__ float block_sum256(float val, float* red4) {
#pragma unroll
    for (int m = 32; m >= 1; m >>= 1) val += __shfl_xor(val, m);
    const int wid = threadIdx.x >> 6;
    __syncthreads();                       // protect red4 from previous use
    if ((threadIdx.x & 63) == 0) red4[wid] = val;
    __syncthreads();
    return red4[0] + red4[1] + red4[2] + red4[3];
}

// ---------------- Kernel 1: QKV projection, RB rows per block ----------------
// Emits q fp32, K as bf16 hi/lo, V as bf16 (row-major) — conversions done ONCE.
__global__ __launch_bounds__(256) void qkv_kernel(
    const float* __restrict__ x,
    const float* __restrict__ Wq, const float* __restrict__ Wk,
    const float* __restrict__ Wv,
    float* __restrict__ q, ushort* __restrict__ khi, ushort* __restrict__ klo,
    ushort* __restrict__ vb)
{
    __shared__ float xr[RB][DD];
    const int row0 = blockIdx.x * RB;
    const int tid = threadIdx.x;
#pragma unroll
    for (int r = 0; r < RB; ++r) xr[r][tid] = x[(size_t)(row0 + r) * DD + tid];
    __syncthreads();

    const int h  = tid >> 5;
    const int kk = tid & 31;
    const float* wq = Wq + (size_t)(h * DD) * DKK + kk;
    const float* wk = Wk + (size_t)(h * DD) * DKK + kk;
    const float* wv = Wv + (size_t)(h * DD) * DKK + kk;

    float aq[RB], ak[RB], av[RB];
#pragma unroll
    for (int r = 0; r < RB; ++r) { aq[r] = 0.f; ak[r] = 0.f; av[r] = 0.f; }

#pragma unroll 4
    for (int d = 0; d < DD; ++d) {
        const float wqd = wq[d * DKK];
        const float wkd = wk[d * DKK];
        const float wvd = wv[d * DKK];
#pragma unroll
        for (int r = 0; r < RB; ++r) {
            const float xv = xr[r][d];
            aq[r] += xv * wqd; ak[r] += xv * wkd; av[r] += xv * wvd;
        }
    }
    const int b = row0 / SS, s0 = row0 % SS;
#pragma unroll
    for (int r = 0; r < RB; ++r) {
        const size_t off = ((size_t)(b * HH + h) * SS + s0 + r) * DKK + kk;
        q[off] = aq[r];
        const ushort kh = f2bf(ak[r]);
        khi[off] = kh;
        klo[off] = f2bf(ak[r] - bf2f(kh));
        vb[off]  = f2bf(av[r]);
    }
}

// ---------------- Kernel 1b: V transpose (bf16): vb[bh][s][32] -> vt[bh][32][S] ----
__global__ __launch_bounds__(256) void vtrans_kernel(
    const ushort* __restrict__ vb, ushort* __restrict__ vt)
{
    __shared__ ushort T[32 * 72];            // stride 72 elems (144 B, 16B-aligned rows)
    const int blk = blockIdx.x;              // bh*32 + s-tile
    const int bh = blk >> 5, st = (blk & 31) * 64;
    const ushort* src = vb + ((size_t)bh * SS + st) * DVV;
    ushort* dst = vt + (size_t)bh * DVV * SS + st;
    const int tid = threadIdx.x;
#pragma unroll
    for (int i = 0; i < 4; ++i) {            // 64 rows x 16 uint-chunks
        const int p = i * 256 + tid;         // 0..1023
        const int s_loc = p >> 4, dv2 = (p & 15) * 2;
        const uint u = *(const uint*)(src + s_loc * DVV + dv2);
        T[dv2 * 72 + s_loc]       = (ushort)(u & 0xffffu);
        T[(dv2 + 1) * 72 + s_loc] = (ushort)(u >> 16);
    }
    __syncthreads();
#pragma unroll
    for (int i = 0; i < 2; ++i) {            // 32 dv x 16 uint2-chunks
        const int p = i * 256 + tid;         // 0..511
        const int dv = p >> 4, s8 = (p & 15) * 4;
        *(uint2*)(dst + (size_t)dv * SS + s8) = *(const uint2*)&T[dv * 72 + s8];
    }
}

// ---------------- Kernel 2: MFMA flash attention (precomputed bf16 K/V) ----------------
// grid = B*H*(S/64); 256 threads = 4 waves, each wave owns 16 queries.
__global__ __launch_bounds__(256) void attn_mfma_kernel(
    const float* __restrict__ q, const ushort* __restrict__ khi,
    const ushort* __restrict__ klo, const ushort* __restrict__ vt,
    float* __restrict__ o)
{
    __shared__ ushort KhS[KT * KSTR];        // 10240 B  K tile hi
    __shared__ ushort KlS[KT * KSTR];        // 10240 B  K tile lo
    __shared__ ushort VtS[32 * VSTR];        //  8704 B  transposed V
    __shared__ ushort PlS[4 * 16 * PSTR];    // 17408 B  per-wave P

    const int tid  = threadIdx.x;
    const int wave = tid >> 6;
    const int lane = tid & 63;
    const int c16  = lane & 15;
    const int g    = lane >> 4;

    const int nqb = SS / 64;                 // 32
    const int bh  = blockIdx.x / nqb;
    const int qb  = blockIdx.x % nqb;
    const int qbase = qb * 64 + wave * 16;

    const float*  qp  = q   + (size_t)bh * SS * DKK;
    const ushort* khp = khi + (size_t)bh * SS * DKK;
    const ushort* klp = klo + (size_t)bh * SS * DKK;
    const ushort* vtp = vt  + (size_t)bh * DVV * SS;

    // Q fragments hi/lo: A row = qbase + c16, k-elements g*8..g*8+7
    short8 qhi, qlo;
    {
        const float* qr = qp + (size_t)(qbase + c16) * DKK + g * 8;
#pragma unroll
        for (int j = 0; j < 8; ++j) {
            const ushort h = f2bf(qr[j]);
            qhi[j] = (short)h;
            qlo[j] = (short)f2bf(qr[j] - bf2f(h));
        }
    }

    float m_r[4], l_r[4];
    f32x4 oacc0, oacc1;
#pragma unroll
    for (int r = 0; r < 4; ++r) { m_r[r] = -1e30f; l_r[r] = 0.f; }
    oacc0 = (f32x4)(0.f); oacc1 = (f32x4)(0.f);
    const f32x4 zero = (f32x4)(0.f);

    ushort* Pw = PlS + wave * 16 * PSTR;

    for (int kt = 0; kt < SS; kt += KT) {
        // ---- stage K tile hi/lo: pure 8B copies ([128][32] -> [128][KSTR]) ----
#pragma unroll
        for (int i = 0; i < 4; ++i) {
            const int p = i * 256 + tid;       // 0..1023
            const int row = p >> 3;            // 0..127
            const int col4 = (p & 7) * 4;      // 0,4..28
            const uint2 h8 = *(const uint2*)(khp + (size_t)(kt + row) * DKK + col4);
            const uint2 l8 = *(const uint2*)(klp + (size_t)(kt + row) * DKK + col4);
            *(uint2*)&KhS[row * KSTR + col4] = h8;
            *(uint2*)&KlS[row * KSTR + col4] = l8;
        }
        // ---- stage V^T tile: pure 8B copies ([32][S] -> [32][VSTR]) ----
#pragma unroll
        for (int i = 0; i < 4; ++i) {
            const int p = i * 256 + tid;       // 0..1023
            const int dv = p >> 5;             // 0..31
            const int s8 = (p & 31) * 4;       // 0..124 step 4
            const uint2 v8 = *(const uint2*)(vtp + (size_t)dv * SS + kt + s8);
            *(uint2*)&VtS[dv * VSTR + s8] = v8;
        }
        __syncthreads();

        // ---- QK^T: 16 queries x 128 keys, fp32-quality via hi/lo split ----
        f32x4 sc[8];
#pragma unroll
        for (int t = 0; t < 8; ++t) {
            const short8 khf = *(const short8*)&KhS[(t * 16 + c16) * KSTR + g * 8];
            const short8 klf = *(const short8*)&KlS[(t * 16 + c16) * KSTR + g * 8];
            f32x4 s = __builtin_amdgcn_mfma_f32_16x16x32_bf16(qlo, khf, zero, 0, 0, 0);
            s = __builtin_amdgcn_mfma_f32_16x16x32_bf16(qhi, klf, s, 0, 0, 0);
            s = __builtin_amdgcn_mfma_f32_16x16x32_bf16(qhi, khf, s, 0, 0, 0);
            sc[t] = s;
        }

        // ---- online softmax (D layout: col=key=c16, row=query=4g+r) ----
#pragma unroll
        for (int r = 0; r < 4; ++r) {
            float tm = sc[0][r];
#pragma unroll
            for (int t = 1; t < 8; ++t) tm = fmaxf(tm, sc[t][r]);
            tm = fmaxf(tm, __shfl_xor(tm, 1));
            tm = fmaxf(tm, __shfl_xor(tm, 2));
            tm = fmaxf(tm, __shfl_xor(tm, 4));
            tm = fmaxf(tm, __shfl_xor(tm, 8));
            const float nm = fmaxf(m_r[r], tm);
            const float scale = __expf(m_r[r] - nm);
            m_r[r] = nm;
            float psum = 0.f;
#pragma unroll
            for (int t = 0; t < 8; ++t) {
                const float p = __expf(sc[t][r] - nm);
                sc[t][r] = p;
                psum += p;
            }
            psum += __shfl_xor(psum, 1);
            psum += __shfl_xor(psum, 2);
            psum += __shfl_xor(psum, 4);
            psum += __shfl_xor(psum, 8);
            l_r[r] = l_r[r] * scale + psum;
            oacc0[r] *= scale;
            oacc1[r] *= scale;
        }

        // ---- write P to per-wave LDS in A-operand layout ----
#pragma unroll
        for (int t = 0; t < 8; ++t)
#pragma unroll
            for (int r = 0; r < 4; ++r)
                Pw[(g * 4 + r) * PSTR + t * 16 + c16] = f2bf(sc[t][r]);

        // ---- PV: 4 s-slices x 2 dv-halves ----
#pragma unroll
        for (int s4 = 0; s4 < 4; ++s4) {
            const short8 pfrag  = *(const short8*)&Pw[c16 * PSTR + s4 * 32 + g * 8];
            const short8 vfrag0 = *(const short8*)&VtS[c16 * VSTR + s4 * 32 + g * 8];
            const short8 vfrag1 = *(const short8*)&VtS[(16 + c16) * VSTR + s4 * 32 + g * 8];
            oacc0 = __builtin_amdgcn_mfma_f32_16x16x32_bf16(pfrag, vfrag0, oacc0, 0, 0, 0);
            oacc1 = __builtin_amdgcn_mfma_f32_16x16x32_bf16(pfrag, vfrag1, oacc1, 0, 0, 0);
        }
        __syncthreads();   // all waves done reading tiles before restage
    }

    // ---- epilogue ----
#pragma unroll
    for (int r = 0; r < 4; ++r) {
        const float invl = 1.0f / l_r[r];
        const int qrow = qbase + g * 4 + r;
        float* op = o + ((size_t)bh * SS + qrow) * DVV;
        op[c16]      = oacc0[r] * invl;
        op[16 + c16] = oacc1[r] * invl;
    }
}

// ---------------- Kernel 3: concat @ Wo + residual + LN, RB rows ----------------
__global__ __launch_bounds__(256) void proj_ln_kernel(
    const float* __restrict__ xin, const float* __restrict__ o,
    const float* __restrict__ Wo, const float* __restrict__ gamma,
    const float* __restrict__ beta, float* __restrict__ xout)
{
    __shared__ float cr[RB][DD];
    __shared__ float red4[4];
    const int row0 = blockIdx.x * RB;
    const int tid = threadIdx.x;
    const int b = row0 / SS, s0 = row0 % SS;
    const int h = tid >> 5, dv = tid & 31;
#pragma unroll
    for (int r = 0; r < RB; ++r)
        cr[r][tid] = o[((size_t)(b * HH + h) * SS + s0 + r) * DVV + dv];
    __syncthreads();

    float acc[RB];
#pragma unroll
    for (int r = 0; r < RB; ++r) acc[r] = 0.f;
#pragma unroll 4
    for (int c = 0; c < DD; ++c) {
        const float w = Wo[(size_t)c * DD + tid];
#pragma unroll
        for (int r = 0; r < RB; ++r) acc[r] += cr[r][c] * w;
    }
    const float g0 = gamma[0], b0 = beta[0];
#pragma unroll
    for (int r = 0; r < RB; ++r) {
        const float y = xin[(size_t)(row0 + r) * DD + tid] + acc[r];
        const float mean = block_sum256(y, red4) * (1.0f / DD);
        const float dy = y - mean;
        const float var = block_sum256(dy * dy, red4) * (1.0f / DD);
        const float rr = 1.0f / sqrtf(var + ln_eps2());
        xout[(size_t)(row0 + r) * DD + tid] = dy * rr * g0 + b0;
    }
}

// ---------------- Kernel 4: FFN + residual + LN, RB rows ----------------
__global__ __launch_bounds__(256) void ffn_ln_kernel(
    const float* __restrict__ xin, const float* __restrict__ W1,
    const float* __restrict__ b1, const float* __restrict__ W2,
    const float* __restrict__ b2, const float* __restrict__ gamma,
    const float* __restrict__ beta, float* __restrict__ xout)
{
    __shared__ float xr[RB][DD];
    __shared__ float hid[RB][DFF];
    __shared__ float red4[4];
    const int row0 = blockIdx.x * RB;
    const int tid = threadIdx.x;
#pragma unroll
    for (int r = 0; r < RB; ++r) xr[r][tid] = xin[(size_t)(row0 + r) * DD + tid];
    __syncthreads();

    float a0[RB], a1[RB];
    const float bb0 = b1[tid], bb1 = b1[tid + 256];
#pragma unroll
    for (int r = 0; r < RB; ++r) { a0[r] = bb0; a1[r] = bb1; }
#pragma unroll 4
    for (int d = 0; d < DD; ++d) {
        const float w0 = W1[(size_t)d * DFF + tid];
        const float w1w = W1[(size_t)d * DFF + tid + 256];
#pragma unroll
        for (int r = 0; r < RB; ++r) {
            const float xv = xr[r][d];
            a0[r] += xv * w0; a1[r] += xv * w1w;
        }
    }
#pragma unroll
    for (int r = 0; r < RB; ++r) {
        hid[r][tid]       = fmaxf(a0[r], 0.f);
        hid[r][tid + 256] = fmaxf(a1[r], 0.f);
    }
    __syncthreads();

    float acc[RB];
    const float bb2 = b2[tid];
#pragma unroll
    for (int r = 0; r < RB; ++r) acc[r] = bb2;
#pragma unroll 4
    for (int f = 0; f < DFF; ++f) {
        const float w = W2[(size_t)f * DD + tid];
#pragma unroll
        for (int r = 0; r < RB; ++r) acc[r] += hid[r][f] * w;
    }
    const float g0 = gamma[0], b0 = beta[0];
#pragma unroll
    for (int r = 0; r < RB; ++r) {
        const float y = xr[r][tid] + acc[r];
        const float mean = block_sum256(y, red4) * (1.0f / DD);
        const float dy = y - mean;
        const float var = block_sum256(dy * dy, red4) * (1.0f / DD);
        const float rr = 1.0f / sqrtf(var + ln_eps2());
        xout[(size_t)(row0 + r) * DD + tid] = dy * rr * g0 + b0;
    }
}

// ---------------- host launch ----------------
extern "C" void kernel_launch(void* const* d_in, const int* in_sizes, int n_in,
                              void* d_out, int out_size, void* d_ws, size_t ws_size,
                              hipStream_t stream) {
    const float* x     = (const float*)d_in[0];
    const float* Wq    = (const float*)d_in[1];
    const float* Wk    = (const float*)d_in[2];
    const float* Wv    = (const float*)d_in[3];
    const float* Wo    = (const float*)d_in[4];
    const float* W1    = (const float*)d_in[5];
    const float* b1    = (const float*)d_in[6];
    const float* W2    = (const float*)d_in[7];
    const float* b2    = (const float*)d_in[8];
    const float* gamma = (const float*)d_in[9];
    const float* beta  = (const float*)d_in[10];
    float* out = (float*)d_out;

    const size_t NTOK = (size_t)BB * SS * DD;   // 1,048,576 elements
    float*  q   = (float*)d_ws;                 // NTOK f32
    ushort* khi = (ushort*)(q + NTOK);          // NTOK bf16
    ushort* klo = khi + NTOK;                   // NTOK bf16
    ushort* vb  = klo + NTOK;                   // NTOK bf16
    ushort* vt  = vb + NTOK;                    // NTOK bf16 (transposed)
    float*  o   = (float*)(vt + NTOK);          // NTOK f32
    float*  xa  = o + NTOK;                     // NTOK f32
    float*  xb  = xa + NTOK;                    // NTOK f32

    const float* cur = x;
    for (int l = 0; l < NL; ++l) {
        const float* wq = Wq + (size_t)l * HH * DD * DKK;
        const float* wk = Wk + (size_t)l * HH * DD * DKK;
        const float* wv = Wv + (size_t)l * HH * DD * DKK;
        const float* wo = Wo + (size_t)l * (HH * DVV) * DD;
        const float* w1 = W1 + (size_t)l * DD * DFF;
        const float* w2 = W2 + (size_t)l * DFF * DD;

        qkv_kernel<<<BB * SS / RB, 256, 0, stream>>>(cur, wq, wk, wv, q, khi, klo, vb);
        vtrans_kernel<<<BB * HH * (SS / 64), 256, 0, stream>>>(vb, vt);
        attn_mfma_kernel<<<BB * HH * (SS / 64), 256, 0, stream>>>(q, khi, klo, vt, o);
        proj_ln_kernel<<<BB * SS / RB, 256, 0, stream>>>(cur, o, wo,
                                                         gamma + 2 * l, beta + 2 * l, xa);
        float* nxt = (l == NL - 1) ? out : xb;
        ffn_ln_kernel<<<BB * SS / RB, 256, 0, stream>>>(xa, w1, b1 + (size_t)l * DFF, w2,
                                                        b2 + (size_t)l * DD,
                                                        gamma + 2 * l + 1, beta + 2 * l + 1, nxt);
        cur = nxt;
    }
}

// Round 7
// 348.328 us; speedup vs baseline: 4.7568x; 1.1252x over previous
//
#include <hip/hip_runtime.h>
#include <math.h>

#define BB 2
#define SS 2048
#define DD 256
#define HH 8
#define DKK 32
#define DVV 32
#define DFF 512
#define NL 2
#define RB 4

// attention tiling
#define KT 128
#define KSTR 40
#define VSTR 136
#define PSTR 136

// ffn tiling
#define XSTR 264     // 16-row X tile stride (ushort), 16B-aligned, bank-floor reads
#define HSTR 520     // 16-row H tile stride (ushort)
#define YSTR 260     // Y tile stride (float)

typedef __attribute__((ext_vector_type(8))) short short8;
typedef __attribute__((ext_vector_type(4))) float f32x4;

static __device__ __forceinline__ float ln_eps2() { return 1.4210854715202004e-14f; }

static __device__ __forceinline__ ushort f2bf(float f) {
    union { float f; unsigned u; } c; c.f = f;
    unsigned r = c.u + 0x7FFFu + ((c.u >> 16) & 1u);   // RNE
    return (ushort)(r >> 16);
}
static __device__ __forceinline__ float bf2f(ushort h) {
    union { unsigned u; float f; } c; c.u = ((unsigned)h) << 16;
    return c.f;
}

static __device__ __forceinline__ float block_sum256(float val, float* red4) {
#pragma unroll
    for (int m = 32; m >= 1; m >>= 1) val += __shfl_xor(val, m);
    const int wid = threadIdx.x >> 6;
    __syncthreads();
    if ((threadIdx.x & 63) == 0) red4[wid] = val;
    __syncthreads();
    return red4[0] + red4[1] + red4[2] + red4[3];
}

// ---------------- Kernel 0: weight convert+transpose (once per launch) ----------------
// W1 [l][256][512] -> w1t hi/lo [l][512][256]; W2 [l][512][256] -> w2t hi/lo [l][256][512]
__global__ __launch_bounds__(256) void wtrans_kernel(
    const float* __restrict__ W1, const float* __restrict__ W2,
    ushort* __restrict__ w1t_hi, ushort* __restrict__ w1t_lo,
    ushort* __restrict__ w2t_hi, ushort* __restrict__ w2t_lo)
{
    __shared__ ushort Th[64][72];
    __shared__ ushort Tl[64][72];
    const int bid = blockIdx.x;              // 0..127
    const float* src; ushort *dh, *dl; int R, C, tile;
    if (bid < 64) {                          // W1: 2 layers x 32 tiles
        const int l = bid >> 5; tile = bid & 31;
        src = W1 + (size_t)l * DD * DFF;
        dh = w1t_hi + (size_t)l * DFF * DD; dl = w1t_lo + (size_t)l * DFF * DD;
        R = DD; C = DFF;
    } else {                                 // W2
        const int l = (bid - 64) >> 5; tile = (bid - 64) & 31;
        src = W2 + (size_t)l * DFF * DD;
        dh = w2t_hi + (size_t)l * DD * DFF; dl = w2t_lo + (size_t)l * DD * DFF;
        R = DFF; C = DD;
    }
    const int tilesC = C / 64;
    const int br = (tile / tilesC) * 64, bc = (tile % tilesC) * 64;
    const int tid = threadIdx.x;
#pragma unroll
    for (int i = 0; i < 16; ++i) {
        const int p = i * 256 + tid;         // 4096 = 64x64
        const int r = p >> 6, c = p & 63;
        const float f = src[(size_t)(br + r) * C + bc + c];
        const ushort h = f2bf(f);
        Th[c][r] = h; Tl[c][r] = f2bf(f - bf2f(h));
    }
    __syncthreads();
#pragma unroll
    for (int i = 0; i < 16; ++i) {
        const int p = i * 256 + tid;
        const int r = p >> 6, c = p & 63;
        dh[(size_t)(bc + r) * R + br + c] = Th[r][c];
        dl[(size_t)(bc + r) * R + br + c] = Tl[r][c];
    }
}

// ---------------- Kernel 1: QKV projection, RB rows per block ----------------
__global__ __launch_bounds__(256) void qkv_kernel(
    const float* __restrict__ x,
    const float* __restrict__ Wq, const float* __restrict__ Wk,
    const float* __restrict__ Wv,
    float* __restrict__ q, ushort* __restrict__ khi, ushort* __restrict__ klo,
    ushort* __restrict__ vb)
{
    __shared__ float xr[RB][DD];
    const int row0 = blockIdx.x * RB;
    const int tid = threadIdx.x;
#pragma unroll
    for (int r = 0; r < RB; ++r) xr[r][tid] = x[(size_t)(row0 + r) * DD + tid];
    __syncthreads();

    const int h  = tid >> 5;
    const int kk = tid & 31;
    const float* wq = Wq + (size_t)(h * DD) * DKK + kk;
    const float* wk = Wk + (size_t)(h * DD) * DKK + kk;
    const float* wv = Wv + (size_t)(h * DD) * DKK + kk;

    float aq[RB], ak[RB], av[RB];
#pragma unroll
    for (int r = 0; r < RB; ++r) { aq[r] = 0.f; ak[r] = 0.f; av[r] = 0.f; }

#pragma unroll 4
    for (int d = 0; d < DD; ++d) {
        const float wqd = wq[d * DKK];
        const float wkd = wk[d * DKK];
        const float wvd = wv[d * DKK];
#pragma unroll
        for (int r = 0; r < RB; ++r) {
            const float xv = xr[r][d];
            aq[r] += xv * wqd; ak[r] += xv * wkd; av[r] += xv * wvd;
        }
    }
    const int b = row0 / SS, s0 = row0 % SS;
#pragma unroll
    for (int r = 0; r < RB; ++r) {
        const size_t off = ((size_t)(b * HH + h) * SS + s0 + r) * DKK + kk;
        q[off] = aq[r];
        const ushort kh = f2bf(ak[r]);
        khi[off] = kh;
        klo[off] = f2bf(ak[r] - bf2f(kh));
        vb[off]  = f2bf(av[r]);
    }
}

// ---------------- Kernel 1b: V transpose (bf16) ----------------
__global__ __launch_bounds__(256) void vtrans_kernel(
    const ushort* __restrict__ vb, ushort* __restrict__ vt)
{
    __shared__ ushort T[32 * 72];
    const int blk = blockIdx.x;
    const int bh = blk >> 5, st = (blk & 31) * 64;
    const ushort* src = vb + ((size_t)bh * SS + st) * DVV;
    ushort* dst = vt + (size_t)bh * DVV * SS + st;
    const int tid = threadIdx.x;
#pragma unroll
    for (int i = 0; i < 4; ++i) {
        const int p = i * 256 + tid;
        const int s_loc = p >> 4, dv2 = (p & 15) * 2;
        const uint u = *(const uint*)(src + s_loc * DVV + dv2);
        T[dv2 * 72 + s_loc]       = (ushort)(u & 0xffffu);
        T[(dv2 + 1) * 72 + s_loc] = (ushort)(u >> 16);
    }
    __syncthreads();
#pragma unroll
    for (int i = 0; i < 2; ++i) {
        const int p = i * 256 + tid;
        const int dv = p >> 4, s8 = (p & 15) * 4;
        *(uint2*)(dst + (size_t)dv * SS + s8) = *(const uint2*)&T[dv * 72 + s8];
    }
}

// ---------------- Kernel 2: MFMA flash attention ----------------
__global__ __launch_bounds__(256) void attn_mfma_kernel(
    const float* __restrict__ q, const ushort* __restrict__ khi,
    const ushort* __restrict__ klo, const ushort* __restrict__ vt,
    float* __restrict__ o)
{
    __shared__ ushort KhS[KT * KSTR];
    __shared__ ushort KlS[KT * KSTR];
    __shared__ ushort VtS[32 * VSTR];
    __shared__ ushort PlS[4 * 16 * PSTR];

    const int tid  = threadIdx.x;
    const int wave = tid >> 6;
    const int lane = tid & 63;
    const int c16  = lane & 15;
    const int g    = lane >> 4;

    const int nqb = SS / 64;
    const int bh  = blockIdx.x / nqb;
    const int qb  = blockIdx.x % nqb;
    const int qbase = qb * 64 + wave * 16;

    const float*  qp  = q   + (size_t)bh * SS * DKK;
    const ushort* khp = khi + (size_t)bh * SS * DKK;
    const ushort* klp = klo + (size_t)bh * SS * DKK;
    const ushort* vtp = vt  + (size_t)bh * DVV * SS;

    short8 qhi, qlo;
    {
        const float* qr = qp + (size_t)(qbase + c16) * DKK + g * 8;
#pragma unroll
        for (int j = 0; j < 8; ++j) {
            const ushort h = f2bf(qr[j]);
            qhi[j] = (short)h;
            qlo[j] = (short)f2bf(qr[j] - bf2f(h));
        }
    }

    float m_r[4], l_r[4];
    f32x4 oacc0, oacc1;
#pragma unroll
    for (int r = 0; r < 4; ++r) { m_r[r] = -1e30f; l_r[r] = 0.f; }
    oacc0 = (f32x4)(0.f); oacc1 = (f32x4)(0.f);
    const f32x4 zero = (f32x4)(0.f);

    ushort* Pw = PlS + wave * 16 * PSTR;

    for (int kt = 0; kt < SS; kt += KT) {
#pragma unroll
        for (int i = 0; i < 4; ++i) {
            const int p = i * 256 + tid;
            const int row = p >> 3;
            const int col4 = (p & 7) * 4;
            const uint2 h8 = *(const uint2*)(khp + (size_t)(kt + row) * DKK + col4);
            const uint2 l8 = *(const uint2*)(klp + (size_t)(kt + row) * DKK + col4);
            *(uint2*)&KhS[row * KSTR + col4] = h8;
            *(uint2*)&KlS[row * KSTR + col4] = l8;
        }
#pragma unroll
        for (int i = 0; i < 4; ++i) {
            const int p = i * 256 + tid;
            const int dv = p >> 5;
            const int s8 = (p & 31) * 4;
            const uint2 v8 = *(const uint2*)(vtp + (size_t)dv * SS + kt + s8);
            *(uint2*)&VtS[dv * VSTR + s8] = v8;
        }
        __syncthreads();

        f32x4 sc[8];
#pragma unroll
        for (int t = 0; t < 8; ++t) {
            const short8 khf = *(const short8*)&KhS[(t * 16 + c16) * KSTR + g * 8];
            const short8 klf = *(const short8*)&KlS[(t * 16 + c16) * KSTR + g * 8];
            f32x4 s = __builtin_amdgcn_mfma_f32_16x16x32_bf16(qlo, khf, zero, 0, 0, 0);
            s = __builtin_amdgcn_mfma_f32_16x16x32_bf16(qhi, klf, s, 0, 0, 0);
            s = __builtin_amdgcn_mfma_f32_16x16x32_bf16(qhi, khf, s, 0, 0, 0);
            sc[t] = s;
        }

#pragma unroll
        for (int r = 0; r < 4; ++r) {
            float tm = sc[0][r];
#pragma unroll
            for (int t = 1; t < 8; ++t) tm = fmaxf(tm, sc[t][r]);
            tm = fmaxf(tm, __shfl_xor(tm, 1));
            tm = fmaxf(tm, __shfl_xor(tm, 2));
            tm = fmaxf(tm, __shfl_xor(tm, 4));
            tm = fmaxf(tm, __shfl_xor(tm, 8));
            const float nm = fmaxf(m_r[r], tm);
            const float scale = __expf(m_r[r] - nm);
            m_r[r] = nm;
            float psum = 0.f;
#pragma unroll
            for (int t = 0; t < 8; ++t) {
                const float p = __expf(sc[t][r] - nm);
                sc[t][r] = p;
                psum += p;
            }
            psum += __shfl_xor(psum, 1);
            psum += __shfl_xor(psum, 2);
            psum += __shfl_xor(psum, 4);
            psum += __shfl_xor(psum, 8);
            l_r[r] = l_r[r] * scale + psum;
            oacc0[r] *= scale;
            oacc1[r] *= scale;
        }

#pragma unroll
        for (int t = 0; t < 8; ++t)
#pragma unroll
            for (int r = 0; r < 4; ++r)
                Pw[(g * 4 + r) * PSTR + t * 16 + c16] = f2bf(sc[t][r]);

#pragma unroll
        for (int s4 = 0; s4 < 4; ++s4) {
            const short8 pfrag  = *(const short8*)&Pw[c16 * PSTR + s4 * 32 + g * 8];
            const short8 vfrag0 = *(const short8*)&VtS[c16 * VSTR + s4 * 32 + g * 8];
            const short8 vfrag1 = *(const short8*)&VtS[(16 + c16) * VSTR + s4 * 32 + g * 8];
            oacc0 = __builtin_amdgcn_mfma_f32_16x16x32_bf16(pfrag, vfrag0, oacc0, 0, 0, 0);
            oacc1 = __builtin_amdgcn_mfma_f32_16x16x32_bf16(pfrag, vfrag1, oacc1, 0, 0, 0);
        }
        __syncthreads();
    }

#pragma unroll
    for (int r = 0; r < 4; ++r) {
        const float invl = 1.0f / l_r[r];
        const int qrow = qbase + g * 4 + r;
        float* op = o + ((size_t)bh * SS + qrow) * DVV;
        op[c16]      = oacc0[r] * invl;
        op[16 + c16] = oacc1[r] * invl;
    }
}

// ---------------- Kernel 3: concat @ Wo + residual + LN, RB rows ----------------
__global__ __launch_bounds__(256) void proj_ln_kernel(
    const float* __restrict__ xin, const float* __restrict__ o,
    const float* __restrict__ Wo, const float* __restrict__ gamma,
    const float* __restrict__ beta, float* __restrict__ xout)
{
    __shared__ float cr[RB][DD];
    __shared__ float red4[4];
    const int row0 = blockIdx.x * RB;
    const int tid = threadIdx.x;
    const int b = row0 / SS, s0 = row0 % SS;
    const int h = tid >> 5, dv = tid & 31;
#pragma unroll
    for (int r = 0; r < RB; ++r)
        cr[r][tid] = o[((size_t)(b * HH + h) * SS + s0 + r) * DVV + dv];
    __syncthreads();

    float acc[RB];
#pragma unroll
    for (int r = 0; r < RB; ++r) acc[r] = 0.f;
#pragma unroll 4
    for (int c = 0; c < DD; ++c) {
        const float w = Wo[(size_t)c * DD + tid];
#pragma unroll
        for (int r = 0; r < RB; ++r) acc[r] += cr[r][c] * w;
    }
    const float g0 = gamma[0], b0 = beta[0];
#pragma unroll
    for (int r = 0; r < RB; ++r) {
        const float y = xin[(size_t)(row0 + r) * DD + tid] + acc[r];
        const float mean = block_sum256(y, red4) * (1.0f / DD);
        const float dy = y - mean;
        const float var = block_sum256(dy * dy, red4) * (1.0f / DD);
        const float rr = 1.0f / sqrtf(var + ln_eps2());
        xout[(size_t)(row0 + r) * DD + tid] = dy * rr * g0 + b0;
    }
}

// ---------------- Kernel 4: FFN via MFMA + residual + LN ----------------
// grid = 256 blocks x 16 rows; 4 waves: GEMM1 wave-cols 128, GEMM2 wave-cols 64.
__global__ __launch_bounds__(256) void ffn_mfma_kernel(
    const float* __restrict__ xin,
    const ushort* __restrict__ w1th, const ushort* __restrict__ w1tl,
    const ushort* __restrict__ w2th, const ushort* __restrict__ w2tl,
    const float* __restrict__ b1, const float* __restrict__ b2,
    const float* __restrict__ gamma, const float* __restrict__ beta,
    float* __restrict__ xout)
{
    __shared__ __align__(16) char smem[(2 * 16 * XSTR + 2 * 16 * HSTR) * 2];
    ushort* Xh = (ushort*)smem;                  // 16*XSTR
    ushort* Xl = Xh + 16 * XSTR;
    ushort* Hh = Xl + 16 * XSTR;
    ushort* Hl = Hh + 16 * HSTR;
    float*  Y  = (float*)smem;                   // aliases Xh/Xl after phase1

    const int tid  = threadIdx.x;
    const int wave = tid >> 6;
    const int lane = tid & 63;
    const int c16  = lane & 15;
    const int g    = lane >> 4;
    const int row0 = blockIdx.x * 16;

    // stage X hi/lo
#pragma unroll
    for (int i = 0; i < 16; ++i) {
        const int p = i * 256 + tid;
        const int r = p >> 8, c = p & 255;
        const float f = xin[(size_t)(row0 + r) * DD + c];
        const ushort h = f2bf(f);
        Xh[r * XSTR + c] = h;
        Xl[r * XSTR + c] = f2bf(f - bf2f(h));
    }
    __syncthreads();

    // X fragments (rows = c16, k = kk*32 + g*8)
    short8 xf_h[8], xf_l[8];
#pragma unroll
    for (int kk = 0; kk < 8; ++kk) {
        xf_h[kk] = *(const short8*)&Xh[c16 * XSTR + kk * 32 + g * 8];
        xf_l[kk] = *(const short8*)&Xl[c16 * XSTR + kk * 32 + g * 8];
    }

    // phase 1: H = relu(X @ W1 + b1), wave covers DFF cols [wave*128, +128)
    const int wbase = wave * 128;
#pragma unroll 2
    for (int t = 0; t < 8; ++t) {
        const int ncol = wbase + t * 16 + c16;
        const ushort* wh = w1th + (size_t)ncol * DD;
        const ushort* wl = w1tl + (size_t)ncol * DD;
        f32x4 acc = (f32x4)(0.f);
#pragma unroll
        for (int kk = 0; kk < 8; ++kk) {
            const short8 bh = *(const short8*)(wh + kk * 32 + g * 8);
            const short8 bl = *(const short8*)(wl + kk * 32 + g * 8);
            acc = __builtin_amdgcn_mfma_f32_16x16x32_bf16(xf_h[kk], bh, acc, 0, 0, 0);
            acc = __builtin_amdgcn_mfma_f32_16x16x32_bf16(xf_l[kk], bh, acc, 0, 0, 0);
            acc = __builtin_amdgcn_mfma_f32_16x16x32_bf16(xf_h[kk], bl, acc, 0, 0, 0);
        }
        const float bias = b1[ncol];
#pragma unroll
        for (int r = 0; r < 4; ++r) {
            const int m = 4 * g + r;
            const float hv = fmaxf(acc[r] + bias, 0.f);
            const ushort hh = f2bf(hv);
            Hh[m * HSTR + ncol] = hh;
            Hl[m * HSTR + ncol] = f2bf(hv - bf2f(hh));
        }
    }
    __syncthreads();

    // phase 2: Y = H @ W2, wave covers DD cols [wave*64, +64)
    const int obase = wave * 64;
    f32x4 acc2[4];
#pragma unroll
    for (int t = 0; t < 4; ++t) acc2[t] = (f32x4)(0.f);
#pragma unroll 2
    for (int kk = 0; kk < 16; ++kk) {
        const short8 ah = *(const short8*)&Hh[c16 * HSTR + kk * 32 + g * 8];
        const short8 al = *(const short8*)&Hl[c16 * HSTR + kk * 32 + g * 8];
#pragma unroll
        for (int t = 0; t < 4; ++t) {
            const int ncol = obase + t * 16 + c16;
            const short8 bh = *(const short8*)(w2th + (size_t)ncol * DFF + kk * 32 + g * 8);
            const short8 bl = *(const short8*)(w2tl + (size_t)ncol * DFF + kk * 32 + g * 8);
            acc2[t] = __builtin_amdgcn_mfma_f32_16x16x32_bf16(ah, bh, acc2[t], 0, 0, 0);
            acc2[t] = __builtin_amdgcn_mfma_f32_16x16x32_bf16(al, bh, acc2[t], 0, 0, 0);
            acc2[t] = __builtin_amdgcn_mfma_f32_16x16x32_bf16(ah, bl, acc2[t], 0, 0, 0);
        }
    }

    // write Y (aliases X region; X regs already consumed, H untouched)
#pragma unroll
    for (int t = 0; t < 4; ++t) {
        const int ncol = obase + t * 16 + c16;
#pragma unroll
        for (int r = 0; r < 4; ++r)
            Y[(4 * g + r) * YSTR + ncol] = acc2[t][r];
    }
    __syncthreads();

    // LN epilogue: wave w handles rows 4w..4w+3
    const float g0 = gamma[0], b0 = beta[0];
#pragma unroll
    for (int rr = 0; rr < 4; ++rr) {
        const int row = wave * 4 + rr;
        float v[4];
        float sum = 0.f;
#pragma unroll
        for (int j = 0; j < 4; ++j) {
            const int c = lane + 64 * j;
            v[j] = Y[row * YSTR + c] + b2[c] + xin[(size_t)(row0 + row) * DD + c];
            sum += v[j];
        }
#pragma unroll
        for (int m = 32; m >= 1; m >>= 1) sum += __shfl_xor(sum, m);
        const float mean = sum * (1.0f / DD);
        float var = 0.f;
#pragma unroll
        for (int j = 0; j < 4; ++j) { v[j] -= mean; var += v[j] * v[j]; }
#pragma unroll
        for (int m = 32; m >= 1; m >>= 1) var += __shfl_xor(var, m);
        var *= (1.0f / DD);
        const float rstd = 1.0f / sqrtf(var + ln_eps2());
#pragma unroll
        for (int j = 0; j < 4; ++j)
            xout[(size_t)(row0 + row) * DD + lane + 64 * j] = v[j] * rstd * g0 + b0;
    }
}

// ---------------- host launch ----------------
extern "C" void kernel_launch(void* const* d_in, const int* in_sizes, int n_in,
                              void* d_out, int out_size, void* d_ws, size_t ws_size,
                              hipStream_t stream) {
    const float* x     = (const float*)d_in[0];
    const float* Wq    = (const float*)d_in[1];
    const float* Wk    = (const float*)d_in[2];
    const float* Wv    = (const float*)d_in[3];
    const float* Wo    = (const float*)d_in[4];
    const float* W1    = (const float*)d_in[5];
    const float* b1    = (const float*)d_in[6];
    const float* W2    = (const float*)d_in[7];
    const float* b2    = (const float*)d_in[8];
    const float* gamma = (const float*)d_in[9];
    const float* beta  = (const float*)d_in[10];
    float* out = (float*)d_out;

    const size_t NTOK = (size_t)BB * SS * DD;       // 1,048,576
    const size_t WFF  = (size_t)NL * DFF * DD;      // 262,144
    float*  q    = (float*)d_ws;
    ushort* khi  = (ushort*)(q + NTOK);
    ushort* klo  = khi + NTOK;
    ushort* vb   = klo + NTOK;
    ushort* vt   = vb + NTOK;
    float*  o    = (float*)(vt + NTOK);
    float*  xa   = o + NTOK;
    float*  xb   = xa + NTOK;
    ushort* w1th = (ushort*)(xb + NTOK);
    ushort* w1tl = w1th + WFF;
    ushort* w2th = w1tl + WFF;
    ushort* w2tl = w2th + WFF;

    wtrans_kernel<<<128, 256, 0, stream>>>(W1, W2, w1th, w1tl, w2th, w2tl);

    const float* cur = x;
    for (int l = 0; l < NL; ++l) {
        const float* wq = Wq + (size_t)l * HH * DD * DKK;
        const float* wk = Wk + (size_t)l * HH * DD * DKK;
        const float* wv = Wv + (size_t)l * HH * DD * DKK;
        const float* wo = Wo + (size_t)l * (HH * DVV) * DD;

        qkv_kernel<<<BB * SS / RB, 256, 0, stream>>>(cur, wq, wk, wv, q, khi, klo, vb);
        vtrans_kernel<<<BB * HH * (SS / 64), 256, 0, stream>>>(vb, vt);
        attn_mfma_kernel<<<BB * HH * (SS / 64), 256, 0, stream>>>(q, khi, klo, vt, o);
        proj_ln_kernel<<<BB * SS / RB, 256, 0, stream>>>(cur, o, wo,
                                                         gamma + 2 * l, beta + 2 * l, xa);
        float* nxt = (l == NL - 1) ? out : xb;
        ffn_mfma_kernel<<<BB * SS / 16, 256, 0, stream>>>(
            xa, w1th + (size_t)l * DFF * DD, w1tl + (size_t)l * DFF * DD,
            w2th + (size_t)l * DD * DFF, w2tl + (size_t)l * DD * DFF,
            b1 + (size_t)l * DFF, b2 + (size_t)l * DD,
            gamma + 2 * l + 1, beta + 2 * l + 1, nxt);
        cur = nxt;
    }
}

// Round 11
// 347.899 us; speedup vs baseline: 4.7627x; 1.0012x over previous
//
#include <hip/hip_runtime.h>
#include <math.h>

#define BB 2
#define SS 2048
#define DD 256
#define HH 8
#define DKK 32
#define DVV 32
#define DFF 512
#define NL 2
#define RB 4

// attention tiling
#define KT 128
#define KSTR 40
#define VSTR 136
#define PSTR 136

// gemm tiling
#define XSTR 264     // 16-row X tile stride (ushort)
#define HSTR 520     // 16-row H tile stride (ushort)
#define YSTR 260     // Y tile stride (float)

typedef __attribute__((ext_vector_type(8))) short short8;
typedef __attribute__((ext_vector_type(4))) float f32x4;

static __device__ __forceinline__ float ln_eps2() { return 1.4210854715202004e-14f; }

static __device__ __forceinline__ ushort f2bf(float f) {
    union { float f; unsigned u; } c; c.f = f;
    unsigned r = c.u + 0x7FFFu + ((c.u >> 16) & 1u);   // RNE
    return (ushort)(r >> 16);
}
static __device__ __forceinline__ float bf2f(ushort h) {
    union { unsigned u; float f; } c; c.u = ((unsigned)h) << 16;
    return c.f;
}

static __device__ __forceinline__ float block_sum256(float val, float* red4) {
#pragma unroll
    for (int m = 32; m >= 1; m >>= 1) val += __shfl_xor(val, m);
    const int wid = threadIdx.x >> 6;
    __syncthreads();
    if ((threadIdx.x & 63) == 0) red4[wid] = val;
    __syncthreads();
    return red4[0] + red4[1] + red4[2] + red4[3];
}

// ---------------- Kernel 0a: W1/W2/Wo convert+transpose (once) ----------------
__global__ __launch_bounds__(256) void wtrans_kernel(
    const float* __restrict__ W1, const float* __restrict__ W2,
    const float* __restrict__ Wo,
    ushort* __restrict__ w1t_hi, ushort* __restrict__ w1t_lo,
    ushort* __restrict__ w2t_hi, ushort* __restrict__ w2t_lo,
    ushort* __restrict__ wot_hi, ushort* __restrict__ wot_lo)
{
    __shared__ ushort Th[64][72];
    __shared__ ushort Tl[64][72];
    const int bid = blockIdx.x;              // 0..159
    const float* src; ushort *dh, *dl; int R, C, tile;
    if (bid < 64) {                          // W1
        const int l = bid >> 5; tile = bid & 31;
        src = W1 + (size_t)l * DD * DFF;
        dh = w1t_hi + (size_t)l * DFF * DD; dl = w1t_lo + (size_t)l * DFF * DD;
        R = DD; C = DFF;
    } else if (bid < 128) {                  // W2
        const int l = (bid - 64) >> 5; tile = (bid - 64) & 31;
        src = W2 + (size_t)l * DFF * DD;
        dh = w2t_hi + (size_t)l * DD * DFF; dl = w2t_lo + (size_t)l * DD * DFF;
        R = DFF; C = DD;
    } else {                                 // Wo
        const int l = (bid - 128) >> 4; tile = (bid - 128) & 15;
        src = Wo + (size_t)l * DD * DD;
        dh = wot_hi + (size_t)l * DD * DD; dl = wot_lo + (size_t)l * DD * DD;
        R = DD; C = DD;
    }
    const int tilesC = C / 64;
    const int br = (tile / tilesC) * 64, bc = (tile % tilesC) * 64;
    const int tid = threadIdx.x;
#pragma unroll
    for (int i = 0; i < 16; ++i) {
        const int p = i * 256 + tid;
        const int r = p >> 6, c = p & 63;
        const float f = src[(size_t)(br + r) * C + bc + c];
        const ushort h = f2bf(f);
        Th[c][r] = h; Tl[c][r] = f2bf(f - bf2f(h));
    }
    __syncthreads();
#pragma unroll
    for (int i = 0; i < 16; ++i) {
        const int p = i * 256 + tid;
        const int r = p >> 6, c = p & 63;
        dh[(size_t)(bc + r) * R + br + c] = Th[r][c];
        dl[(size_t)(bc + r) * R + br + c] = Tl[r][c];
    }
}

// ---------------- Kernel 1: scalar QKV (round-7 proven), V written transposed ----------------
__global__ __launch_bounds__(256) void qkv_kernel(
    const float* __restrict__ x,
    const float* __restrict__ Wq, const float* __restrict__ Wk,
    const float* __restrict__ Wv,
    float* __restrict__ q, ushort* __restrict__ khi, ushort* __restrict__ klo,
    ushort* __restrict__ vt)
{
    __shared__ float xr[RB][DD];
    const int row0 = blockIdx.x * RB;
    const int tid = threadIdx.x;
#pragma unroll
    for (int r = 0; r < RB; ++r) xr[r][tid] = x[(size_t)(row0 + r) * DD + tid];
    __syncthreads();

    const int h  = tid >> 5;
    const int kk = tid & 31;
    const float* wq = Wq + (size_t)(h * DD) * DKK + kk;
    const float* wk = Wk + (size_t)(h * DD) * DKK + kk;
    const float* wv = Wv + (size_t)(h * DD) * DKK + kk;

    float aq[RB], ak[RB], av[RB];
#pragma unroll
    for (int r = 0; r < RB; ++r) { aq[r] = 0.f; ak[r] = 0.f; av[r] = 0.f; }

#pragma unroll 4
    for (int d = 0; d < DD; ++d) {
        const float wqd = wq[d * DKK];
        const float wkd = wk[d * DKK];
        const float wvd = wv[d * DKK];
#pragma unroll
        for (int r = 0; r < RB; ++r) {
            const float xv = xr[r][d];
            aq[r] += xv * wqd; ak[r] += xv * wkd; av[r] += xv * wvd;
        }
    }
    const int b = row0 / SS, s0 = row0 % SS;
#pragma unroll
    for (int r = 0; r < RB; ++r) {
        const size_t off = ((size_t)(b * HH + h) * SS + s0 + r) * DKK + kk;
        q[off] = aq[r];
        const ushort kh = f2bf(ak[r]);
        khi[off] = kh;
        klo[off] = f2bf(ak[r] - bf2f(kh));
        // V direct transpose: vt[bh][dv][s]
        vt[((size_t)(b * HH + h) * DVV + kk) * SS + s0 + r] = f2bf(av[r]);
    }
}

// ---------------- Kernel 2: MFMA flash attention ----------------
__global__ __launch_bounds__(256) void attn_mfma_kernel(
    const float* __restrict__ q, const ushort* __restrict__ khi,
    const ushort* __restrict__ klo, const ushort* __restrict__ vt,
    float* __restrict__ o)
{
    __shared__ ushort KhS[KT * KSTR];
    __shared__ ushort KlS[KT * KSTR];
    __shared__ ushort VtS[32 * VSTR];
    __shared__ ushort PlS[4 * 16 * PSTR];

    const int tid  = threadIdx.x;
    const int wave = tid >> 6;
    const int lane = tid & 63;
    const int c16  = lane & 15;
    const int g    = lane >> 4;

    const int nqb = SS / 64;
    const int bh  = blockIdx.x / nqb;
    const int qb  = blockIdx.x % nqb;
    const int qbase = qb * 64 + wave * 16;

    const float*  qp  = q   + (size_t)bh * SS * DKK;
    const ushort* khp = khi + (size_t)bh * SS * DKK;
    const ushort* klp = klo + (size_t)bh * SS * DKK;
    const ushort* vtp = vt  + (size_t)bh * DVV * SS;

    short8 qhi, qlo;
    {
        const float* qr = qp + (size_t)(qbase + c16) * DKK + g * 8;
#pragma unroll
        for (int j = 0; j < 8; ++j) {
            const ushort h = f2bf(qr[j]);
            qhi[j] = (short)h;
            qlo[j] = (short)f2bf(qr[j] - bf2f(h));
        }
    }

    float m_r[4], l_r[4];
    f32x4 oacc0, oacc1;
#pragma unroll
    for (int r = 0; r < 4; ++r) { m_r[r] = -1e30f; l_r[r] = 0.f; }
    oacc0 = (f32x4)(0.f); oacc1 = (f32x4)(0.f);
    const f32x4 zero = (f32x4)(0.f);

    ushort* Pw = PlS + wave * 16 * PSTR;

    for (int kt = 0; kt < SS; kt += KT) {
#pragma unroll
        for (int i = 0; i < 4; ++i) {
            const int p = i * 256 + tid;
            const int row = p >> 3;
            const int col4 = (p & 7) * 4;
            const uint2 h8 = *(const uint2*)(khp + (size_t)(kt + row) * DKK + col4);
            const uint2 l8 = *(const uint2*)(klp + (size_t)(kt + row) * DKK + col4);
            *(uint2*)&KhS[row * KSTR + col4] = h8;
            *(uint2*)&KlS[row * KSTR + col4] = l8;
        }
#pragma unroll
        for (int i = 0; i < 4; ++i) {
            const int p = i * 256 + tid;
            const int dv = p >> 5;
            const int s8 = (p & 31) * 4;
            const uint2 v8 = *(const uint2*)(vtp + (size_t)dv * SS + kt + s8);
            *(uint2*)&VtS[dv * VSTR + s8] = v8;
        }
        __syncthreads();

        f32x4 sc[8];
#pragma unroll
        for (int t = 0; t < 8; ++t) {
            const short8 khf = *(const short8*)&KhS[(t * 16 + c16) * KSTR + g * 8];
            const short8 klf = *(const short8*)&KlS[(t * 16 + c16) * KSTR + g * 8];
            f32x4 s = __builtin_amdgcn_mfma_f32_16x16x32_bf16(qlo, khf, zero, 0, 0, 0);
            s = __builtin_amdgcn_mfma_f32_16x16x32_bf16(qhi, klf, s, 0, 0, 0);
            s = __builtin_amdgcn_mfma_f32_16x16x32_bf16(qhi, khf, s, 0, 0, 0);
            sc[t] = s;
        }

#pragma unroll
        for (int r = 0; r < 4; ++r) {
            float tm = sc[0][r];
#pragma unroll
            for (int t = 1; t < 8; ++t) tm = fmaxf(tm, sc[t][r]);
            tm = fmaxf(tm, __shfl_xor(tm, 1));
            tm = fmaxf(tm, __shfl_xor(tm, 2));
            tm = fmaxf(tm, __shfl_xor(tm, 4));
            tm = fmaxf(tm, __shfl_xor(tm, 8));
            const float nm = fmaxf(m_r[r], tm);
            const float scale = __expf(m_r[r] - nm);
            m_r[r] = nm;
            float psum = 0.f;
#pragma unroll
            for (int t = 0; t < 8; ++t) {
                const float p = __expf(sc[t][r] - nm);
                sc[t][r] = p;
                psum += p;
            }
            psum += __shfl_xor(psum, 1);
            psum += __shfl_xor(psum, 2);
            psum += __shfl_xor(psum, 4);
            psum += __shfl_xor(psum, 8);
            l_r[r] = l_r[r] * scale + psum;
            oacc0[r] *= scale;
            oacc1[r] *= scale;
        }

#pragma unroll
        for (int t = 0; t < 8; ++t)
#pragma unroll
            for (int r = 0; r < 4; ++r)
                Pw[(g * 4 + r) * PSTR + t * 16 + c16] = f2bf(sc[t][r]);

#pragma unroll
        for (int s4 = 0; s4 < 4; ++s4) {
            const short8 pfrag  = *(const short8*)&Pw[c16 * PSTR + s4 * 32 + g * 8];
            const short8 vfrag0 = *(const short8*)&VtS[c16 * VSTR + s4 * 32 + g * 8];
            const short8 vfrag1 = *(const short8*)&VtS[(16 + c16) * VSTR + s4 * 32 + g * 8];
            oacc0 = __builtin_amdgcn_mfma_f32_16x16x32_bf16(pfrag, vfrag0, oacc0, 0, 0, 0);
            oacc1 = __builtin_amdgcn_mfma_f32_16x16x32_bf16(pfrag, vfrag1, oacc1, 0, 0, 0);
        }
        __syncthreads();
    }

    // epilogue: write o in concat layout [b*S + s][h*32 + dv]
    const int b = bh >> 3, h = bh & 7;
#pragma unroll
    for (int r = 0; r < 4; ++r) {
        const float invl = 1.0f / l_r[r];
        const int qrow = qbase + g * 4 + r;
        float* op = o + ((size_t)(b * SS + qrow)) * (HH * DVV) + h * DVV;
        op[c16]      = oacc0[r] * invl;
        op[16 + c16] = oacc1[r] * invl;
    }
}

// ---------------- Kernel 3: scalar proj (round-7 proven) reading concat layout ----------------
__global__ __launch_bounds__(256) void projc_ln_kernel(
    const float* __restrict__ xin, const float* __restrict__ conc,
    const float* __restrict__ Wo, const float* __restrict__ gamma,
    const float* __restrict__ beta, float* __restrict__ xout)
{
    __shared__ float cr[RB][DD];
    __shared__ float red4[4];
    const int row0 = blockIdx.x * RB;
    const int tid = threadIdx.x;
#pragma unroll
    for (int r = 0; r < RB; ++r)
        cr[r][tid] = conc[(size_t)(row0 + r) * DD + tid];
    __syncthreads();

    float acc[RB];
#pragma unroll
    for (int r = 0; r < RB; ++r) acc[r] = 0.f;
#pragma unroll 4
    for (int c = 0; c < DD; ++c) {
        const float w = Wo[(size_t)c * DD + tid];
#pragma unroll
        for (int r = 0; r < RB; ++r) acc[r] += cr[r][c] * w;
    }
    const float g0 = gamma[0], b0 = beta[0];
#pragma unroll
    for (int r = 0; r < RB; ++r) {
        const float y = xin[(size_t)(row0 + r) * DD + tid] + acc[r];
        const float mean = block_sum256(y, red4) * (1.0f / DD);
        const float dy = y - mean;
        const float var = block_sum256(dy * dy, red4) * (1.0f / DD);
        const float rr = 1.0f / sqrtf(var + ln_eps2());
        xout[(size_t)(row0 + r) * DD + tid] = dy * rr * g0 + b0;
    }
}

// ---------------- Kernel 4: FFN via MFMA + residual + LN ----------------
__global__ __launch_bounds__(256) void ffn_mfma_kernel(
    const float* __restrict__ xin,
    const ushort* __restrict__ w1th, const ushort* __restrict__ w1tl,
    const ushort* __restrict__ w2th, const ushort* __restrict__ w2tl,
    const float* __restrict__ b1, const float* __restrict__ b2,
    const float* __restrict__ gamma, const float* __restrict__ beta,
    float* __restrict__ xout)
{
    __shared__ __align__(16) char smem[(2 * 16 * XSTR + 2 * 16 * HSTR) * 2];
    ushort* Xh = (ushort*)smem;
    ushort* Xl = Xh + 16 * XSTR;
    ushort* Hh = Xl + 16 * XSTR;
    ushort* Hl = Hh + 16 * HSTR;
    float*  Y  = (float*)smem;

    const int tid  = threadIdx.x;
    const int wave = tid >> 6;
    const int lane = tid & 63;
    const int c16  = lane & 15;
    const int g    = lane >> 4;
    const int row0 = blockIdx.x * 16;

#pragma unroll
    for (int i = 0; i < 16; ++i) {
        const int p = i * 256 + tid;
        const int r = p >> 8, c = p & 255;
        const float f = xin[(size_t)(row0 + r) * DD + c];
        const ushort h = f2bf(f);
        Xh[r * XSTR + c] = h;
        Xl[r * XSTR + c] = f2bf(f - bf2f(h));
    }
    __syncthreads();

    short8 xf_h[8], xf_l[8];
#pragma unroll
    for (int kk = 0; kk < 8; ++kk) {
        xf_h[kk] = *(const short8*)&Xh[c16 * XSTR + kk * 32 + g * 8];
        xf_l[kk] = *(const short8*)&Xl[c16 * XSTR + kk * 32 + g * 8];
    }

    const int wbase = wave * 128;
#pragma unroll 2
    for (int t = 0; t < 8; ++t) {
        const int ncol = wbase + t * 16 + c16;
        const ushort* wh = w1th + (size_t)ncol * DD;
        const ushort* wl = w1tl + (size_t)ncol * DD;
        f32x4 acc = (f32x4)(0.f);
#pragma unroll
        for (int kk = 0; kk < 8; ++kk) {
            const short8 bh = *(const short8*)(wh + kk * 32 + g * 8);
            const short8 bl = *(const short8*)(wl + kk * 32 + g * 8);
            acc = __builtin_amdgcn_mfma_f32_16x16x32_bf16(xf_h[kk], bh, acc, 0, 0, 0);
            acc = __builtin_amdgcn_mfma_f32_16x16x32_bf16(xf_l[kk], bh, acc, 0, 0, 0);
            acc = __builtin_amdgcn_mfma_f32_16x16x32_bf16(xf_h[kk], bl, acc, 0, 0, 0);
        }
        const float bias = b1[ncol];
#pragma unroll
        for (int r = 0; r < 4; ++r) {
            const int m = 4 * g + r;
            const float hv = fmaxf(acc[r] + bias, 0.f);
            const ushort hh = f2bf(hv);
            Hh[m * HSTR + ncol] = hh;
            Hl[m * HSTR + ncol] = f2bf(hv - bf2f(hh));
        }
    }
    __syncthreads();

    const int obase = wave * 64;
    f32x4 acc2[4];
#pragma unroll
    for (int t = 0; t < 4; ++t) acc2[t] = (f32x4)(0.f);
#pragma unroll 2
    for (int kk = 0; kk < 16; ++kk) {
        const short8 ah = *(const short8*)&Hh[c16 * HSTR + kk * 32 + g * 8];
        const short8 al = *(const short8*)&Hl[c16 * HSTR + kk * 32 + g * 8];
#pragma unroll
        for (int t = 0; t < 4; ++t) {
            const int ncol = obase + t * 16 + c16;
            const short8 bh = *(const short8*)(w2th + (size_t)ncol * DFF + kk * 32 + g * 8);
            const short8 bl = *(const short8*)(w2tl + (size_t)ncol * DFF + kk * 32 + g * 8);
            acc2[t] = __builtin_amdgcn_mfma_f32_16x16x32_bf16(ah, bh, acc2[t], 0, 0, 0);
            acc2[t] = __builtin_amdgcn_mfma_f32_16x16x32_bf16(al, bh, acc2[t], 0, 0, 0);
            acc2[t] = __builtin_amdgcn_mfma_f32_16x16x32_bf16(ah, bl, acc2[t], 0, 0, 0);
        }
    }

#pragma unroll
    for (int t = 0; t < 4; ++t) {
        const int ncol = obase + t * 16 + c16;
#pragma unroll
        for (int r = 0; r < 4; ++r)
            Y[(4 * g + r) * YSTR + ncol] = acc2[t][r];
    }
    __syncthreads();

    const float g0 = gamma[0], b0 = beta[0];
#pragma unroll
    for (int rr = 0; rr < 4; ++rr) {
        const int row = wave * 4 + rr;
        float v[4];
        float sum = 0.f;
#pragma unroll
        for (int j = 0; j < 4; ++j) {
            const int c = lane + 64 * j;
            v[j] = Y[row * YSTR + c] + b2[c] + xin[(size_t)(row0 + row) * DD + c];
            sum += v[j];
        }
#pragma unroll
        for (int m = 32; m >= 1; m >>= 1) sum += __shfl_xor(sum, m);
        const float mean = sum * (1.0f / DD);
        float var = 0.f;
#pragma unroll
        for (int j = 0; j < 4; ++j) { v[j] -= mean; var += v[j] * v[j]; }
#pragma unroll
        for (int m = 32; m >= 1; m >>= 1) var += __shfl_xor(var, m);
        var *= (1.0f / DD);
        const float rstd = 1.0f / sqrtf(var + ln_eps2());
#pragma unroll
        for (int j = 0; j < 4; ++j)
            xout[(size_t)(row0 + row) * DD + lane + 64 * j] = v[j] * rstd * g0 + b0;
    }
}

// ---------------- host launch ----------------
extern "C" void kernel_launch(void* const* d_in, const int* in_sizes, int n_in,
                              void* d_out, int out_size, void* d_ws, size_t ws_size,
                              hipStream_t stream) {
    const float* x     = (const float*)d_in[0];
    const float* Wq    = (const float*)d_in[1];
    const float* Wk    = (const float*)d_in[2];
    const float* Wv    = (const float*)d_in[3];
    const float* Wo    = (const float*)d_in[4];
    const float* W1    = (const float*)d_in[5];
    const float* b1    = (const float*)d_in[6];
    const float* W2    = (const float*)d_in[7];
    const float* b2    = (const float*)d_in[8];
    const float* gamma = (const float*)d_in[9];
    const float* beta  = (const float*)d_in[10];
    float* out = (float*)d_out;

    const size_t NTOK = (size_t)BB * SS * DD;       // 1,048,576
    const size_t WFF  = (size_t)NL * DFF * DD;      // 262,144
    const size_t WOO  = (size_t)NL * DD * DD;       // 131,072
    float*  q    = (float*)d_ws;
    ushort* khi  = (ushort*)(q + NTOK);
    ushort* klo  = khi + NTOK;
    ushort* vt   = klo + NTOK;
    float*  o    = (float*)(vt + NTOK);
    float*  xa   = o + NTOK;
    float*  xb   = xa + NTOK;
    ushort* w1th = (ushort*)(xb + NTOK);
    ushort* w1tl = w1th + WFF;
    ushort* w2th = w1tl + WFF;
    ushort* w2tl = w2th + WFF;
    ushort* woth = w2tl + WFF;
    ushort* wotl = woth + WOO;

    wtrans_kernel<<<160, 256, 0, stream>>>(W1, W2, Wo, w1th, w1tl, w2th, w2tl,
                                           woth, wotl);

    const float* cur = x;
    for (int l = 0; l < NL; ++l) {
        const float* wq = Wq + (size_t)l * HH * DD * DKK;
        const float* wk = Wk + (size_t)l * HH * DD * DKK;
        const float* wv = Wv + (size_t)l * HH * DD * DKK;
        const float* wo = Wo + (size_t)l * DD * DD;

        qkv_kernel<<<BB * SS / RB, 256, 0, stream>>>(cur, wq, wk, wv, q, khi, klo, vt);
        attn_mfma_kernel<<<BB * HH * (SS / 64), 256, 0, stream>>>(q, khi, klo, vt, o);
        projc_ln_kernel<<<BB * SS / RB, 256, 0, stream>>>(
            cur, o, wo, gamma + 2 * l, beta + 2 * l, xa);
        float* nxt = (l == NL - 1) ? out : xb;
        ffn_mfma_kernel<<<BB * SS / 16, 256, 0, stream>>>(
            xa, w1th + (size_t)l * DFF * DD, w1tl + (size_t)l * DFF * DD,
            w2th + (size_t)l * DD * DFF, w2tl + (size_t)l * DD * DFF,
            b1 + (size_t)l * DFF, b2 + (size_t)l * DD,
            gamma + 2 * l + 1, beta + 2 * l + 1, nxt);
        cur = nxt;
    }
}

// Round 12
// 329.672 us; speedup vs baseline: 5.0260x; 1.0553x over previous
//
#include <hip/hip_runtime.h>
#include <math.h>

#define BB 2
#define SS 2048
#define DD 256
#define HH 8
#define DKK 32
#define DVV 32
#define DFF 512
#define NL 2
#define RB 4

// attention tiling
#define KT 128
#define KSTR 40
#define VSTR 136
#define PSTR 136

// gemm tiling
#define XSTR 264     // 16-row X tile stride (ushort)
#define HSTR 520     // 16-row H tile stride (ushort)
#define YSTR 260     // Y tile stride (float)

typedef __attribute__((ext_vector_type(8))) short short8;
typedef __attribute__((ext_vector_type(4))) float f32x4;

static __device__ __forceinline__ float ln_eps2() { return 1.4210854715202004e-14f; }

static __device__ __forceinline__ ushort f2bf(float f) {
    union { float f; unsigned u; } c; c.f = f;
    unsigned r = c.u + 0x7FFFu + ((c.u >> 16) & 1u);   // RNE
    return (ushort)(r >> 16);
}
static __device__ __forceinline__ float bf2f(ushort h) {
    union { unsigned u; float f; } c; c.u = ((unsigned)h) << 16;
    return c.f;
}

// ---------------- Kernel 0a: W1/W2 convert+transpose (round-7 proven form) ----------------
__global__ __launch_bounds__(256) void wtrans_kernel(
    const float* __restrict__ W1, const float* __restrict__ W2,
    ushort* __restrict__ w1t_hi, ushort* __restrict__ w1t_lo,
    ushort* __restrict__ w2t_hi, ushort* __restrict__ w2t_lo)
{
    __shared__ ushort Th[64][72];
    __shared__ ushort Tl[64][72];
    const int bid = blockIdx.x;              // 0..127
    const float* src; ushort *dh, *dl; int R, C, tile;
    if (bid < 64) {                          // W1
        const int l = bid >> 5; tile = bid & 31;
        src = W1 + (size_t)l * DD * DFF;
        dh = w1t_hi + (size_t)l * DFF * DD; dl = w1t_lo + (size_t)l * DFF * DD;
        R = DD; C = DFF;
    } else {                                 // W2
        const int l = (bid - 64) >> 5; tile = (bid - 64) & 31;
        src = W2 + (size_t)l * DFF * DD;
        dh = w2t_hi + (size_t)l * DD * DFF; dl = w2t_lo + (size_t)l * DD * DFF;
        R = DFF; C = DD;
    }
    const int tilesC = C / 64;
    const int br = (tile / tilesC) * 64, bc = (tile % tilesC) * 64;
    const int tid = threadIdx.x;
#pragma unroll
    for (int i = 0; i < 16; ++i) {
        const int p = i * 256 + tid;
        const int r = p >> 6, c = p & 63;
        const float f = src[(size_t)(br + r) * C + bc + c];
        const ushort h = f2bf(f);
        Th[c][r] = h; Tl[c][r] = f2bf(f - bf2f(h));
    }
    __syncthreads();
#pragma unroll
    for (int i = 0; i < 16; ++i) {
        const int p = i * 256 + tid;
        const int r = p >> 6, c = p & 63;
        dh[(size_t)(bc + r) * R + br + c] = Th[r][c];
        dl[(size_t)(bc + r) * R + br + c] = Tl[r][c];
    }
}

// ---------------- Kernel 0b: Wo -> woT hi/lo [l][256][256], simple & verified ----------------
// wh[n][k] = Wo[k][n]. grid = NL*16 (64x64 tiles), fp32 LDS tile [64][65].
__global__ __launch_bounds__(256) void wotrans_kernel(
    const float* __restrict__ Wo,
    ushort* __restrict__ wh, ushort* __restrict__ wl)
{
    __shared__ float T[64][65];
    const int l = blockIdx.x >> 4, tile = blockIdx.x & 15;
    const int tr = (tile >> 2) * 64;         // k-tile base (source row)
    const int tc = (tile & 3) * 64;          // n-tile base (source col)
    const float* src = Wo + (size_t)l * DD * DD;
    ushort* dh = wh + (size_t)l * DD * DD;
    ushort* dl = wl + (size_t)l * DD * DD;
    const int tid = threadIdx.x;
#pragma unroll
    for (int i = 0; i < 16; ++i) {
        const int p = i * 256 + tid;
        const int r = p >> 6, c = p & 63;
        T[r][c] = src[(size_t)(tr + r) * DD + tc + c];
    }
    __syncthreads();
#pragma unroll
    for (int i = 0; i < 16; ++i) {
        const int p = i * 256 + tid;
        const int r = p >> 6, c = p & 63;
        const float f = T[c][r];             // = Wo[tr+c][tc+r]
        const size_t off = (size_t)(tc + r) * DD + tr + c;   // [n][k]
        const ushort h = f2bf(f);
        dh[off] = h;
        dl[off] = f2bf(f - bf2f(h));
    }
}

// ---------------- Kernel 1: scalar QKV (proven), V written transposed ----------------
__global__ __launch_bounds__(256) void qkv_kernel(
    const float* __restrict__ x,
    const float* __restrict__ Wq, const float* __restrict__ Wk,
    const float* __restrict__ Wv,
    float* __restrict__ q, ushort* __restrict__ khi, ushort* __restrict__ klo,
    ushort* __restrict__ vt)
{
    __shared__ float xr[RB][DD];
    const int row0 = blockIdx.x * RB;
    const int tid = threadIdx.x;
#pragma unroll
    for (int r = 0; r < RB; ++r) xr[r][tid] = x[(size_t)(row0 + r) * DD + tid];
    __syncthreads();

    const int h  = tid >> 5;
    const int kk = tid & 31;
    const float* wq = Wq + (size_t)(h * DD) * DKK + kk;
    const float* wk = Wk + (size_t)(h * DD) * DKK + kk;
    const float* wv = Wv + (size_t)(h * DD) * DKK + kk;

    float aq[RB], ak[RB], av[RB];
#pragma unroll
    for (int r = 0; r < RB; ++r) { aq[r] = 0.f; ak[r] = 0.f; av[r] = 0.f; }

#pragma unroll 4
    for (int d = 0; d < DD; ++d) {
        const float wqd = wq[d * DKK];
        const float wkd = wk[d * DKK];
        const float wvd = wv[d * DKK];
#pragma unroll
        for (int r = 0; r < RB; ++r) {
            const float xv = xr[r][d];
            aq[r] += xv * wqd; ak[r] += xv * wkd; av[r] += xv * wvd;
        }
    }
    const int b = row0 / SS, s0 = row0 % SS;
#pragma unroll
    for (int r = 0; r < RB; ++r) {
        const size_t off = ((size_t)(b * HH + h) * SS + s0 + r) * DKK + kk;
        q[off] = aq[r];
        const ushort kh = f2bf(ak[r]);
        khi[off] = kh;
        klo[off] = f2bf(ak[r] - bf2f(kh));
        // V direct transpose: vt[bh][dv][s]
        vt[((size_t)(b * HH + h) * DVV + kk) * SS + s0 + r] = f2bf(av[r]);
    }
}

// ---------------- Kernel 2: MFMA flash attention ----------------
__global__ __launch_bounds__(256) void attn_mfma_kernel(
    const float* __restrict__ q, const ushort* __restrict__ khi,
    const ushort* __restrict__ klo, const ushort* __restrict__ vt,
    float* __restrict__ o)
{
    __shared__ ushort KhS[KT * KSTR];
    __shared__ ushort KlS[KT * KSTR];
    __shared__ ushort VtS[32 * VSTR];
    __shared__ ushort PlS[4 * 16 * PSTR];

    const int tid  = threadIdx.x;
    const int wave = tid >> 6;
    const int lane = tid & 63;
    const int c16  = lane & 15;
    const int g    = lane >> 4;

    const int nqb = SS / 64;
    const int bh  = blockIdx.x / nqb;
    const int qb  = blockIdx.x % nqb;
    const int qbase = qb * 64 + wave * 16;

    const float*  qp  = q   + (size_t)bh * SS * DKK;
    const ushort* khp = khi + (size_t)bh * SS * DKK;
    const ushort* klp = klo + (size_t)bh * SS * DKK;
    const ushort* vtp = vt  + (size_t)bh * DVV * SS;

    short8 qhi, qlo;
    {
        const float* qr = qp + (size_t)(qbase + c16) * DKK + g * 8;
#pragma unroll
        for (int j = 0; j < 8; ++j) {
            const ushort h = f2bf(qr[j]);
            qhi[j] = (short)h;
            qlo[j] = (short)f2bf(qr[j] - bf2f(h));
        }
    }

    float m_r[4], l_r[4];
    f32x4 oacc0, oacc1;
#pragma unroll
    for (int r = 0; r < 4; ++r) { m_r[r] = -1e30f; l_r[r] = 0.f; }
    oacc0 = (f32x4)(0.f); oacc1 = (f32x4)(0.f);
    const f32x4 zero = (f32x4)(0.f);

    ushort* Pw = PlS + wave * 16 * PSTR;

    for (int kt = 0; kt < SS; kt += KT) {
#pragma unroll
        for (int i = 0; i < 4; ++i) {
            const int p = i * 256 + tid;
            const int row = p >> 3;
            const int col4 = (p & 7) * 4;
            const uint2 h8 = *(const uint2*)(khp + (size_t)(kt + row) * DKK + col4);
            const uint2 l8 = *(const uint2*)(klp + (size_t)(kt + row) * DKK + col4);
            *(uint2*)&KhS[row * KSTR + col4] = h8;
            *(uint2*)&KlS[row * KSTR + col4] = l8;
        }
#pragma unroll
        for (int i = 0; i < 4; ++i) {
            const int p = i * 256 + tid;
            const int dv = p >> 5;
            const int s8 = (p & 31) * 4;
            const uint2 v8 = *(const uint2*)(vtp + (size_t)dv * SS + kt + s8);
            *(uint2*)&VtS[dv * VSTR + s8] = v8;
        }
        __syncthreads();

        f32x4 sc[8];
#pragma unroll
        for (int t = 0; t < 8; ++t) {
            const short8 khf = *(const short8*)&KhS[(t * 16 + c16) * KSTR + g * 8];
            const short8 klf = *(const short8*)&KlS[(t * 16 + c16) * KSTR + g * 8];
            f32x4 s = __builtin_amdgcn_mfma_f32_16x16x32_bf16(qlo, khf, zero, 0, 0, 0);
            s = __builtin_amdgcn_mfma_f32_16x16x32_bf16(qhi, klf, s, 0, 0, 0);
            s = __builtin_amdgcn_mfma_f32_16x16x32_bf16(qhi, khf, s, 0, 0, 0);
            sc[t] = s;
        }

#pragma unroll
        for (int r = 0; r < 4; ++r) {
            float tm = sc[0][r];
#pragma unroll
            for (int t = 1; t < 8; ++t) tm = fmaxf(tm, sc[t][r]);
            tm = fmaxf(tm, __shfl_xor(tm, 1));
            tm = fmaxf(tm, __shfl_xor(tm, 2));
            tm = fmaxf(tm, __shfl_xor(tm, 4));
            tm = fmaxf(tm, __shfl_xor(tm, 8));
            const float nm = fmaxf(m_r[r], tm);
            const float scale = __expf(m_r[r] - nm);
            m_r[r] = nm;
            float psum = 0.f;
#pragma unroll
            for (int t = 0; t < 8; ++t) {
                const float p = __expf(sc[t][r] - nm);
                sc[t][r] = p;
                psum += p;
            }
            psum += __shfl_xor(psum, 1);
            psum += __shfl_xor(psum, 2);
            psum += __shfl_xor(psum, 4);
            psum += __shfl_xor(psum, 8);
            l_r[r] = l_r[r] * scale + psum;
            oacc0[r] *= scale;
            oacc1[r] *= scale;
        }

#pragma unroll
        for (int t = 0; t < 8; ++t)
#pragma unroll
            for (int r = 0; r < 4; ++r)
                Pw[(g * 4 + r) * PSTR + t * 16 + c16] = f2bf(sc[t][r]);

#pragma unroll
        for (int s4 = 0; s4 < 4; ++s4) {
            const short8 pfrag  = *(const short8*)&Pw[c16 * PSTR + s4 * 32 + g * 8];
            const short8 vfrag0 = *(const short8*)&VtS[c16 * VSTR + s4 * 32 + g * 8];
            const short8 vfrag1 = *(const short8*)&VtS[(16 + c16) * VSTR + s4 * 32 + g * 8];
            oacc0 = __builtin_amdgcn_mfma_f32_16x16x32_bf16(pfrag, vfrag0, oacc0, 0, 0, 0);
            oacc1 = __builtin_amdgcn_mfma_f32_16x16x32_bf16(pfrag, vfrag1, oacc1, 0, 0, 0);
        }
        __syncthreads();
    }

    // epilogue: write o in concat layout [b*S + s][h*32 + dv]
    const int b = bh >> 3, h = bh & 7;
#pragma unroll
    for (int r = 0; r < 4; ++r) {
        const float invl = 1.0f / l_r[r];
        const int qrow = qbase + g * 4 + r;
        float* op = o + ((size_t)(b * SS + qrow)) * (HH * DVV) + h * DVV;
        op[c16]      = oacc0[r] * invl;
        op[16 + c16] = oacc1[r] * invl;
    }
}

// ---------------- Kernel 3: proj via MFMA (ffn-phase-1 proven structure) ----------------
// grid = B*S/16; 4 waves x 4 col-tiles (N=256); dedicated Y buffer (no aliasing).
__global__ __launch_bounds__(256) void proj_mfma_kernel(
    const float* __restrict__ conc, const float* __restrict__ xres,
    const ushort* __restrict__ wth, const ushort* __restrict__ wtl,
    const float* __restrict__ gamma, const float* __restrict__ beta,
    float* __restrict__ xout)
{
    __shared__ __align__(16) ushort Xh[16 * XSTR];
    __shared__ __align__(16) ushort Xl[16 * XSTR];
    __shared__ float Y[16 * YSTR];

    const int tid = threadIdx.x, wave = tid >> 6, lane = tid & 63;
    const int c16 = lane & 15, g = lane >> 4;
    const int row0 = blockIdx.x * 16;

#pragma unroll
    for (int i = 0; i < 16; ++i) {
        const int p = i * 256 + tid;
        const int r = p >> 8, c = p & 255;
        const float f = conc[(size_t)(row0 + r) * DD + c];
        const ushort h = f2bf(f);
        Xh[r * XSTR + c] = h;
        Xl[r * XSTR + c] = f2bf(f - bf2f(h));
    }
    __syncthreads();

    short8 xf_h[8], xf_l[8];
#pragma unroll
    for (int kk = 0; kk < 8; ++kk) {
        xf_h[kk] = *(const short8*)&Xh[c16 * XSTR + kk * 32 + g * 8];
        xf_l[kk] = *(const short8*)&Xl[c16 * XSTR + kk * 32 + g * 8];
    }

    const int wbase = wave * 64;
#pragma unroll 2
    for (int t = 0; t < 4; ++t) {
        const int ncol = wbase + t * 16 + c16;
        const ushort* wh = wth + (size_t)ncol * DD;
        const ushort* wl = wtl + (size_t)ncol * DD;
        f32x4 acc = (f32x4)(0.f);
#pragma unroll
        for (int kk = 0; kk < 8; ++kk) {
            const short8 bh = *(const short8*)(wh + kk * 32 + g * 8);
            const short8 bl = *(const short8*)(wl + kk * 32 + g * 8);
            acc = __builtin_amdgcn_mfma_f32_16x16x32_bf16(xf_h[kk], bh, acc, 0, 0, 0);
            acc = __builtin_amdgcn_mfma_f32_16x16x32_bf16(xf_l[kk], bh, acc, 0, 0, 0);
            acc = __builtin_amdgcn_mfma_f32_16x16x32_bf16(xf_h[kk], bl, acc, 0, 0, 0);
        }
#pragma unroll
        for (int r = 0; r < 4; ++r)
            Y[(4 * g + r) * YSTR + ncol] = acc[r];
    }
    __syncthreads();

    const float g0 = gamma[0], b0 = beta[0];
#pragma unroll
    for (int rr = 0; rr < 4; ++rr) {
        const int row = wave * 4 + rr;
        float v[4];
        float sum = 0.f;
#pragma unroll
        for (int j = 0; j < 4; ++j) {
            const int c = lane + 64 * j;
            v[j] = Y[row * YSTR + c] + xres[(size_t)(row0 + row) * DD + c];
            sum += v[j];
        }
#pragma unroll
        for (int m = 32; m >= 1; m >>= 1) sum += __shfl_xor(sum, m);
        const float mean = sum * (1.0f / DD);
        float var = 0.f;
#pragma unroll
        for (int j = 0; j < 4; ++j) { v[j] -= mean; var += v[j] * v[j]; }
#pragma unroll
        for (int m = 32; m >= 1; m >>= 1) var += __shfl_xor(var, m);
        var *= (1.0f / DD);
        const float rstd = 1.0f / sqrtf(var + ln_eps2());
#pragma unroll
        for (int j = 0; j < 4; ++j)
            xout[(size_t)(row0 + row) * DD + lane + 64 * j] = v[j] * rstd * g0 + b0;
    }
}

// ---------------- Kernel 4: FFN via MFMA + residual + LN ----------------
__global__ __launch_bounds__(256) void ffn_mfma_kernel(
    const float* __restrict__ xin,
    const ushort* __restrict__ w1th, const ushort* __restrict__ w1tl,
    const ushort* __restrict__ w2th, const ushort* __restrict__ w2tl,
    const float* __restrict__ b1, const float* __restrict__ b2,
    const float* __restrict__ gamma, const float* __restrict__ beta,
    float* __restrict__ xout)
{
    __shared__ __align__(16) char smem[(2 * 16 * XSTR + 2 * 16 * HSTR) * 2];
    ushort* Xh = (ushort*)smem;
    ushort* Xl = Xh + 16 * XSTR;
    ushort* Hh = Xl + 16 * XSTR;
    ushort* Hl = Hh + 16 * HSTR;
    float*  Y  = (float*)smem;

    const int tid  = threadIdx.x;
    const int wave = tid >> 6;
    const int lane = tid & 63;
    const int c16  = lane & 15;
    const int g    = lane >> 4;
    const int row0 = blockIdx.x * 16;

#pragma unroll
    for (int i = 0; i < 16; ++i) {
        const int p = i * 256 + tid;
        const int r = p >> 8, c = p & 255;
        const float f = xin[(size_t)(row0 + r) * DD + c];
        const ushort h = f2bf(f);
        Xh[r * XSTR + c] = h;
        Xl[r * XSTR + c] = f2bf(f - bf2f(h));
    }
    __syncthreads();

    short8 xf_h[8], xf_l[8];
#pragma unroll
    for (int kk = 0; kk < 8; ++kk) {
        xf_h[kk] = *(const short8*)&Xh[c16 * XSTR + kk * 32 + g * 8];
        xf_l[kk] = *(const short8*)&Xl[c16 * XSTR + kk * 32 + g * 8];
    }

    const int wbase = wave * 128;
#pragma unroll 2
    for (int t = 0; t < 8; ++t) {
        const int ncol = wbase + t * 16 + c16;
        const ushort* wh = w1th + (size_t)ncol * DD;
        const ushort* wl = w1tl + (size_t)ncol * DD;
        f32x4 acc = (f32x4)(0.f);
#pragma unroll
        for (int kk = 0; kk < 8; ++kk) {
            const short8 bh = *(const short8*)(wh + kk * 32 + g * 8);
            const short8 bl = *(const short8*)(wl + kk * 32 + g * 8);
            acc = __builtin_amdgcn_mfma_f32_16x16x32_bf16(xf_h[kk], bh, acc, 0, 0, 0);
            acc = __builtin_amdgcn_mfma_f32_16x16x32_bf16(xf_l[kk], bh, acc, 0, 0, 0);
            acc = __builtin_amdgcn_mfma_f32_16x16x32_bf16(xf_h[kk], bl, acc, 0, 0, 0);
        }
        const float bias = b1[ncol];
#pragma unroll
        for (int r = 0; r < 4; ++r) {
            const int m = 4 * g + r;
            const float hv = fmaxf(acc[r] + bias, 0.f);
            const ushort hh = f2bf(hv);
            Hh[m * HSTR + ncol] = hh;
            Hl[m * HSTR + ncol] = f2bf(hv - bf2f(hh));
        }
    }
    __syncthreads();

    const int obase = wave * 64;
    f32x4 acc2[4];
#pragma unroll
    for (int t = 0; t < 4; ++t) acc2[t] = (f32x4)(0.f);
#pragma unroll 2
    for (int kk = 0; kk < 16; ++kk) {
        const short8 ah = *(const short8*)&Hh[c16 * HSTR + kk * 32 + g * 8];
        const short8 al = *(const short8*)&Hl[c16 * HSTR + kk * 32 + g * 8];
#pragma unroll
        for (int t = 0; t < 4; ++t) {
            const int ncol = obase + t * 16 + c16;
            const short8 bh = *(const short8*)(w2th + (size_t)ncol * DFF + kk * 32 + g * 8);
            const short8 bl = *(const short8*)(w2tl + (size_t)ncol * DFF + kk * 32 + g * 8);
            acc2[t] = __builtin_amdgcn_mfma_f32_16x16x32_bf16(ah, bh, acc2[t], 0, 0, 0);
            acc2[t] = __builtin_amdgcn_mfma_f32_16x16x32_bf16(al, bh, acc2[t], 0, 0, 0);
            acc2[t] = __builtin_amdgcn_mfma_f32_16x16x32_bf16(ah, bl, acc2[t], 0, 0, 0);
        }
    }

#pragma unroll
    for (int t = 0; t < 4; ++t) {
        const int ncol = obase + t * 16 + c16;
#pragma unroll
        for (int r = 0; r < 4; ++r)
            Y[(4 * g + r) * YSTR + ncol] = acc2[t][r];
    }
    __syncthreads();

    const float g0 = gamma[0], b0 = beta[0];
#pragma unroll
    for (int rr = 0; rr < 4; ++rr) {
        const int row = wave * 4 + rr;
        float v[4];
        float sum = 0.f;
#pragma unroll
        for (int j = 0; j < 4; ++j) {
            const int c = lane + 64 * j;
            v[j] = Y[row * YSTR + c] + b2[c] + xin[(size_t)(row0 + row) * DD + c];
            sum += v[j];
        }
#pragma unroll
        for (int m = 32; m >= 1; m >>= 1) sum += __shfl_xor(sum, m);
        const float mean = sum * (1.0f / DD);
        float var = 0.f;
#pragma unroll
        for (int j = 0; j < 4; ++j) { v[j] -= mean; var += v[j] * v[j]; }
#pragma unroll
        for (int m = 32; m >= 1; m >>= 1) var += __shfl_xor(var, m);
        var *= (1.0f / DD);
        const float rstd = 1.0f / sqrtf(var + ln_eps2());
#pragma unroll
        for (int j = 0; j < 4; ++j)
            xout[(size_t)(row0 + row) * DD + lane + 64 * j] = v[j] * rstd * g0 + b0;
    }
}

// ---------------- host launch ----------------
extern "C" void kernel_launch(void* const* d_in, const int* in_sizes, int n_in,
                              void* d_out, int out_size, void* d_ws, size_t ws_size,
                              hipStream_t stream) {
    const float* x     = (const float*)d_in[0];
    const float* Wq    = (const float*)d_in[1];
    const float* Wk    = (const float*)d_in[2];
    const float* Wv    = (const float*)d_in[3];
    const float* Wo    = (const float*)d_in[4];
    const float* W1    = (const float*)d_in[5];
    const float* b1    = (const float*)d_in[6];
    const float* W2    = (const float*)d_in[7];
    const float* b2    = (const float*)d_in[8];
    const float* gamma = (const float*)d_in[9];
    const float* beta  = (const float*)d_in[10];
    float* out = (float*)d_out;

    const size_t NTOK = (size_t)BB * SS * DD;       // 1,048,576
    const size_t WFF  = (size_t)NL * DFF * DD;      // 262,144
    const size_t WOO  = (size_t)NL * DD * DD;       // 131,072
    float*  q    = (float*)d_ws;
    ushort* khi  = (ushort*)(q + NTOK);
    ushort* klo  = khi + NTOK;
    ushort* vt   = klo + NTOK;
    float*  o    = (float*)(vt + NTOK);
    float*  xa   = o + NTOK;
    float*  xb   = xa + NTOK;
    ushort* w1th = (ushort*)(xb + NTOK);
    ushort* w1tl = w1th + WFF;
    ushort* w2th = w1tl + WFF;
    ushort* w2tl = w2th + WFF;
    ushort* woth = w2tl + WFF;
    ushort* wotl = woth + WOO;

    wtrans_kernel<<<128, 256, 0, stream>>>(W1, W2, w1th, w1tl, w2th, w2tl);
    wotrans_kernel<<<NL * 16, 256, 0, stream>>>(Wo, woth, wotl);

    const float* cur = x;
    for (int l = 0; l < NL; ++l) {
        const float* wq = Wq + (size_t)l * HH * DD * DKK;
        const float* wk = Wk + (size_t)l * HH * DD * DKK;
        const float* wv = Wv + (size_t)l * HH * DD * DKK;

        qkv_kernel<<<BB * SS / RB, 256, 0, stream>>>(cur, wq, wk, wv, q, khi, klo, vt);
        attn_mfma_kernel<<<BB * HH * (SS / 64), 256, 0, stream>>>(q, khi, klo, vt, o);
        proj_mfma_kernel<<<BB * SS / 16, 256, 0, stream>>>(
            o, cur, woth + (size_t)l * DD * DD, wotl + (size_t)l * DD * DD,
            gamma + 2 * l, beta + 2 * l, xa);
        float* nxt = (l == NL - 1) ? out : xb;
        ffn_mfma_kernel<<<BB * SS / 16, 256, 0, stream>>>(
            xa, w1th + (size_t)l * DFF * DD, w1tl + (size_t)l * DFF * DD,
            w2th + (size_t)l * DD * DFF, w2tl + (size_t)l * DD * DFF,
            b1 + (size_t)l * DFF, b2 + (size_t)l * DD,
            gamma + 2 * l + 1, beta + 2 * l + 1, nxt);
        cur = nxt;
    }
}

// Round 13
// 327.612 us; speedup vs baseline: 5.0576x; 1.0063x over previous
//
#include <hip/hip_runtime.h>
#include <math.h>

#define BB 2
#define SS 2048
#define DD 256
#define HH 8
#define DKK 32
#define DVV 32
#define DFF 512
#define NL 2

// attention tiling
#define KT 128
#define KSTR 40
#define VSTR 136
#define PSTR 136

// gemm tiling
#define XSTR 264     // 16-row X tile stride (ushort)
#define HSTR 520     // 16-row H tile stride (ushort)
#define YSTR 260     // Y tile stride (float)

typedef __attribute__((ext_vector_type(8))) short short8;
typedef __attribute__((ext_vector_type(4))) float f32x4;

static __device__ __forceinline__ float ln_eps2() { return 1.4210854715202004e-14f; }

static __device__ __forceinline__ ushort f2bf(float f) {
    union { float f; unsigned u; } c; c.f = f;
    unsigned r = c.u + 0x7FFFu + ((c.u >> 16) & 1u);   // RNE
    return (ushort)(r >> 16);
}
static __device__ __forceinline__ float bf2f(ushort h) {
    union { unsigned u; float f; } c; c.u = ((unsigned)h) << 16;
    return c.f;
}

// ---------------- Kernel 0a: W1/W2 convert+transpose (proven) ----------------
__global__ __launch_bounds__(256) void wtrans_kernel(
    const float* __restrict__ W1, const float* __restrict__ W2,
    ushort* __restrict__ w1t_hi, ushort* __restrict__ w1t_lo,
    ushort* __restrict__ w2t_hi, ushort* __restrict__ w2t_lo)
{
    __shared__ ushort Th[64][72];
    __shared__ ushort Tl[64][72];
    const int bid = blockIdx.x;              // 0..127
    const float* src; ushort *dh, *dl; int R, C, tile;
    if (bid < 64) {                          // W1
        const int l = bid >> 5; tile = bid & 31;
        src = W1 + (size_t)l * DD * DFF;
        dh = w1t_hi + (size_t)l * DFF * DD; dl = w1t_lo + (size_t)l * DFF * DD;
        R = DD; C = DFF;
    } else {                                 // W2
        const int l = (bid - 64) >> 5; tile = (bid - 64) & 31;
        src = W2 + (size_t)l * DFF * DD;
        dh = w2t_hi + (size_t)l * DD * DFF; dl = w2t_lo + (size_t)l * DD * DFF;
        R = DFF; C = DD;
    }
    const int tilesC = C / 64;
    const int br = (tile / tilesC) * 64, bc = (tile % tilesC) * 64;
    const int tid = threadIdx.x;
#pragma unroll
    for (int i = 0; i < 16; ++i) {
        const int p = i * 256 + tid;
        const int r = p >> 6, c = p & 63;
        const float f = src[(size_t)(br + r) * C + bc + c];
        const ushort h = f2bf(f);
        Th[c][r] = h; Tl[c][r] = f2bf(f - bf2f(h));
    }
    __syncthreads();
#pragma unroll
    for (int i = 0; i < 16; ++i) {
        const int p = i * 256 + tid;
        const int r = p >> 6, c = p & 63;
        dh[(size_t)(bc + r) * R + br + c] = Th[r][c];
        dl[(size_t)(bc + r) * R + br + c] = Tl[r][c];
    }
}

// ---------------- Kernel 0b: Wo -> woT hi/lo [l][256][256] (proven) ----------------
__global__ __launch_bounds__(256) void wotrans_kernel(
    const float* __restrict__ Wo,
    ushort* __restrict__ wh, ushort* __restrict__ wl)
{
    __shared__ float T[64][65];
    const int l = blockIdx.x >> 4, tile = blockIdx.x & 15;
    const int tr = (tile >> 2) * 64;
    const int tc = (tile & 3) * 64;
    const float* src = Wo + (size_t)l * DD * DD;
    ushort* dh = wh + (size_t)l * DD * DD;
    ushort* dl = wl + (size_t)l * DD * DD;
    const int tid = threadIdx.x;
#pragma unroll
    for (int i = 0; i < 16; ++i) {
        const int p = i * 256 + tid;
        const int r = p >> 6, c = p & 63;
        T[r][c] = src[(size_t)(tr + r) * DD + tc + c];
    }
    __syncthreads();
#pragma unroll
    for (int i = 0; i < 16; ++i) {
        const int p = i * 256 + tid;
        const int r = p >> 6, c = p & 63;
        const float f = T[c][r];
        const size_t off = (size_t)(tc + r) * DD + tr + c;
        const ushort h = f2bf(f);
        dh[off] = h;
        dl[off] = f2bf(f - bf2f(h));
    }
}

// ---------------- Kernel 0c: Wq/Wk/Wv -> wqkvT hi/lo [l][768][256] (once) ----------------
// dst row = src*256 + h*32 + dk, col = d; value = W[d][dk].
__global__ __launch_bounds__(256) void wqkv_trans_kernel(
    const float* __restrict__ Wq, const float* __restrict__ Wk,
    const float* __restrict__ Wv,
    ushort* __restrict__ qkvT_hi, ushort* __restrict__ qkvT_lo)
{
    __shared__ float T[DKK][DD + 1];
    const int bid = blockIdx.x;              // l*24 + src*8 + h
    const int l = bid / 24, rem = bid % 24, src = rem >> 3, h = rem & 7;
    const float* W = (src == 0 ? Wq : src == 1 ? Wk : Wv)
                     + ((size_t)l * HH + h) * DD * DKK;
    ushort* dh = qkvT_hi + ((size_t)l * 768 + src * 256 + h * 32) * DD;
    ushort* dl = qkvT_lo + ((size_t)l * 768 + src * 256 + h * 32) * DD;
    const int tid = threadIdx.x;
#pragma unroll
    for (int i = 0; i < 32; ++i) {           // W[d][dk] -> T[dk][d]
        const int p = i * 256 + tid;
        T[p & 31][p >> 5] = W[p];
    }
    __syncthreads();
#pragma unroll
    for (int i = 0; i < 32; ++i) {
        const int p = i * 256 + tid;
        const int dk = p >> 8, d = p & 255;
        const float f = T[dk][d];
        const ushort hh = f2bf(f);
        dh[dk * DD + d] = hh;
        dl[dk * DD + d] = f2bf(f - bf2f(hh));
    }
}

// ---------------- Kernel 1: QKV via MFMA (round-12 proj template clone) ----------------
// grid = B*S/16; 16 rows x 768 cols; 4 waves x 12 col-tiles.
__global__ __launch_bounds__(256) void qkv_mfma_kernel(
    const float* __restrict__ xin,
    const ushort* __restrict__ wth, const ushort* __restrict__ wtl,
    float* __restrict__ q, ushort* __restrict__ khi, ushort* __restrict__ klo,
    ushort* __restrict__ vt)
{
    __shared__ __align__(16) ushort Xh[16 * XSTR];
    __shared__ __align__(16) ushort Xl[16 * XSTR];

    const int tid = threadIdx.x, wave = tid >> 6, lane = tid & 63;
    const int c16 = lane & 15, g = lane >> 4;
    const int row0 = blockIdx.x * 16;

#pragma unroll
    for (int i = 0; i < 16; ++i) {
        const int p = i * 256 + tid;
        const int r = p >> 8, c = p & 255;
        const float f = xin[(size_t)(row0 + r) * DD + c];
        const ushort h = f2bf(f);
        Xh[r * XSTR + c] = h;
        Xl[r * XSTR + c] = f2bf(f - bf2f(h));
    }
    __syncthreads();

    short8 xf_h[8], xf_l[8];
#pragma unroll
    for (int kk = 0; kk < 8; ++kk) {
        xf_h[kk] = *(const short8*)&Xh[c16 * XSTR + kk * 32 + g * 8];
        xf_l[kk] = *(const short8*)&Xl[c16 * XSTR + kk * 32 + g * 8];
    }

    const int b = row0 / SS, s0 = row0 % SS;
    const int wbase = wave * 192;            // 4 waves x 192 = 768
#pragma unroll 2
    for (int t = 0; t < 12; ++t) {
        const int ncol = wbase + t * 16 + c16;
        const ushort* wh = wth + (size_t)ncol * DD;
        const ushort* wl = wtl + (size_t)ncol * DD;
        f32x4 acc = (f32x4)(0.f);
#pragma unroll
        for (int kk = 0; kk < 8; ++kk) {
            const short8 bh = *(const short8*)(wh + kk * 32 + g * 8);
            const short8 bl = *(const short8*)(wl + kk * 32 + g * 8);
            acc = __builtin_amdgcn_mfma_f32_16x16x32_bf16(xf_h[kk], bh, acc, 0, 0, 0);
            acc = __builtin_amdgcn_mfma_f32_16x16x32_bf16(xf_l[kk], bh, acc, 0, 0, 0);
            acc = __builtin_amdgcn_mfma_f32_16x16x32_bf16(xf_h[kk], bl, acc, 0, 0, 0);
        }
        const int src = ncol >> 8, h = (ncol >> 5) & 7, dk = ncol & 31;
        const size_t base = ((size_t)(b * HH + h) * SS + s0) * DKK + dk;
#pragma unroll
        for (int r = 0; r < 4; ++r) {
            if (src == 0) {
                q[base + (size_t)(4 * g + r) * DKK] = acc[r];
            } else if (src == 1) {
                const size_t off = base + (size_t)(4 * g + r) * DKK;
                const ushort hh = f2bf(acc[r]);
                khi[off] = hh;
                klo[off] = f2bf(acc[r] - bf2f(hh));
            } else {
                // V direct transpose: vt[bh][dv][s]
                vt[((size_t)(b * HH + h) * DVV + dk) * SS + s0 + 4 * g + r] = f2bf(acc[r]);
            }
        }
    }
}

// ---------------- Kernel 2: MFMA flash attention (unchanged) ----------------
__global__ __launch_bounds__(256) void attn_mfma_kernel(
    const float* __restrict__ q, const ushort* __restrict__ khi,
    const ushort* __restrict__ klo, const ushort* __restrict__ vt,
    float* __restrict__ o)
{
    __shared__ ushort KhS[KT * KSTR];
    __shared__ ushort KlS[KT * KSTR];
    __shared__ ushort VtS[32 * VSTR];
    __shared__ ushort PlS[4 * 16 * PSTR];

    const int tid  = threadIdx.x;
    const int wave = tid >> 6;
    const int lane = tid & 63;
    const int c16  = lane & 15;
    const int g    = lane >> 4;

    const int nqb = SS / 64;
    const int bh  = blockIdx.x / nqb;
    const int qb  = blockIdx.x % nqb;
    const int qbase = qb * 64 + wave * 16;

    const float*  qp  = q   + (size_t)bh * SS * DKK;
    const ushort* khp = khi + (size_t)bh * SS * DKK;
    const ushort* klp = klo + (size_t)bh * SS * DKK;
    const ushort* vtp = vt  + (size_t)bh * DVV * SS;

    short8 qhi, qlo;
    {
        const float* qr = qp + (size_t)(qbase + c16) * DKK + g * 8;
#pragma unroll
        for (int j = 0; j < 8; ++j) {
            const ushort h = f2bf(qr[j]);
            qhi[j] = (short)h;
            qlo[j] = (short)f2bf(qr[j] - bf2f(h));
        }
    }

    float m_r[4], l_r[4];
    f32x4 oacc0, oacc1;
#pragma unroll
    for (int r = 0; r < 4; ++r) { m_r[r] = -1e30f; l_r[r] = 0.f; }
    oacc0 = (f32x4)(0.f); oacc1 = (f32x4)(0.f);
    const f32x4 zero = (f32x4)(0.f);

    ushort* Pw = PlS + wave * 16 * PSTR;

    for (int kt = 0; kt < SS; kt += KT) {
#pragma unroll
        for (int i = 0; i < 4; ++i) {
            const int p = i * 256 + tid;
            const int row = p >> 3;
            const int col4 = (p & 7) * 4;
            const uint2 h8 = *(const uint2*)(khp + (size_t)(kt + row) * DKK + col4);
            const uint2 l8 = *(const uint2*)(klp + (size_t)(kt + row) * DKK + col4);
            *(uint2*)&KhS[row * KSTR + col4] = h8;
            *(uint2*)&KlS[row * KSTR + col4] = l8;
        }
#pragma unroll
        for (int i = 0; i < 4; ++i) {
            const int p = i * 256 + tid;
            const int dv = p >> 5;
            const int s8 = (p & 31) * 4;
            const uint2 v8 = *(const uint2*)(vtp + (size_t)dv * SS + kt + s8);
            *(uint2*)&VtS[dv * VSTR + s8] = v8;
        }
        __syncthreads();

        f32x4 sc[8];
#pragma unroll
        for (int t = 0; t < 8; ++t) {
            const short8 khf = *(const short8*)&KhS[(t * 16 + c16) * KSTR + g * 8];
            const short8 klf = *(const short8*)&KlS[(t * 16 + c16) * KSTR + g * 8];
            f32x4 s = __builtin_amdgcn_mfma_f32_16x16x32_bf16(qlo, khf, zero, 0, 0, 0);
            s = __builtin_amdgcn_mfma_f32_16x16x32_bf16(qhi, klf, s, 0, 0, 0);
            s = __builtin_amdgcn_mfma_f32_16x16x32_bf16(qhi, khf, s, 0, 0, 0);
            sc[t] = s;
        }

#pragma unroll
        for (int r = 0; r < 4; ++r) {
            float tm = sc[0][r];
#pragma unroll
            for (int t = 1; t < 8; ++t) tm = fmaxf(tm, sc[t][r]);
            tm = fmaxf(tm, __shfl_xor(tm, 1));
            tm = fmaxf(tm, __shfl_xor(tm, 2));
            tm = fmaxf(tm, __shfl_xor(tm, 4));
            tm = fmaxf(tm, __shfl_xor(tm, 8));
            const float nm = fmaxf(m_r[r], tm);
            const float scale = __expf(m_r[r] - nm);
            m_r[r] = nm;
            float psum = 0.f;
#pragma unroll
            for (int t = 0; t < 8; ++t) {
                const float p = __expf(sc[t][r] - nm);
                sc[t][r] = p;
                psum += p;
            }
            psum += __shfl_xor(psum, 1);
            psum += __shfl_xor(psum, 2);
            psum += __shfl_xor(psum, 4);
            psum += __shfl_xor(psum, 8);
            l_r[r] = l_r[r] * scale + psum;
            oacc0[r] *= scale;
            oacc1[r] *= scale;
        }

#pragma unroll
        for (int t = 0; t < 8; ++t)
#pragma unroll
            for (int r = 0; r < 4; ++r)
                Pw[(g * 4 + r) * PSTR + t * 16 + c16] = f2bf(sc[t][r]);

#pragma unroll
        for (int s4 = 0; s4 < 4; ++s4) {
            const short8 pfrag  = *(const short8*)&Pw[c16 * PSTR + s4 * 32 + g * 8];
            const short8 vfrag0 = *(const short8*)&VtS[c16 * VSTR + s4 * 32 + g * 8];
            const short8 vfrag1 = *(const short8*)&VtS[(16 + c16) * VSTR + s4 * 32 + g * 8];
            oacc0 = __builtin_amdgcn_mfma_f32_16x16x32_bf16(pfrag, vfrag0, oacc0, 0, 0, 0);
            oacc1 = __builtin_amdgcn_mfma_f32_16x16x32_bf16(pfrag, vfrag1, oacc1, 0, 0, 0);
        }
        __syncthreads();
    }

    // epilogue: write o in concat layout [b*S + s][h*32 + dv]
    const int b = bh >> 3, h = bh & 7;
#pragma unroll
    for (int r = 0; r < 4; ++r) {
        const float invl = 1.0f / l_r[r];
        const int qrow = qbase + g * 4 + r;
        float* op = o + ((size_t)(b * SS + qrow)) * (HH * DVV) + h * DVV;
        op[c16]      = oacc0[r] * invl;
        op[16 + c16] = oacc1[r] * invl;
    }
}

// ---------------- Kernel 3: proj via MFMA (proven) ----------------
__global__ __launch_bounds__(256) void proj_mfma_kernel(
    const float* __restrict__ conc, const float* __restrict__ xres,
    const ushort* __restrict__ wth, const ushort* __restrict__ wtl,
    const float* __restrict__ gamma, const float* __restrict__ beta,
    float* __restrict__ xout)
{
    __shared__ __align__(16) ushort Xh[16 * XSTR];
    __shared__ __align__(16) ushort Xl[16 * XSTR];
    __shared__ float Y[16 * YSTR];

    const int tid = threadIdx.x, wave = tid >> 6, lane = tid & 63;
    const int c16 = lane & 15, g = lane >> 4;
    const int row0 = blockIdx.x * 16;

#pragma unroll
    for (int i = 0; i < 16; ++i) {
        const int p = i * 256 + tid;
        const int r = p >> 8, c = p & 255;
        const float f = conc[(size_t)(row0 + r) * DD + c];
        const ushort h = f2bf(f);
        Xh[r * XSTR + c] = h;
        Xl[r * XSTR + c] = f2bf(f - bf2f(h));
    }
    __syncthreads();

    short8 xf_h[8], xf_l[8];
#pragma unroll
    for (int kk = 0; kk < 8; ++kk) {
        xf_h[kk] = *(const short8*)&Xh[c16 * XSTR + kk * 32 + g * 8];
        xf_l[kk] = *(const short8*)&Xl[c16 * XSTR + kk * 32 + g * 8];
    }

    const int wbase = wave * 64;
#pragma unroll 2
    for (int t = 0; t < 4; ++t) {
        const int ncol = wbase + t * 16 + c16;
        const ushort* wh = wth + (size_t)ncol * DD;
        const ushort* wl = wtl + (size_t)ncol * DD;
        f32x4 acc = (f32x4)(0.f);
#pragma unroll
        for (int kk = 0; kk < 8; ++kk) {
            const short8 bh = *(const short8*)(wh + kk * 32 + g * 8);
            const short8 bl = *(const short8*)(wl + kk * 32 + g * 8);
            acc = __builtin_amdgcn_mfma_f32_16x16x32_bf16(xf_h[kk], bh, acc, 0, 0, 0);
            acc = __builtin_amdgcn_mfma_f32_16x16x32_bf16(xf_l[kk], bh, acc, 0, 0, 0);
            acc = __builtin_amdgcn_mfma_f32_16x16x32_bf16(xf_h[kk], bl, acc, 0, 0, 0);
        }
#pragma unroll
        for (int r = 0; r < 4; ++r)
            Y[(4 * g + r) * YSTR + ncol] = acc[r];
    }
    __syncthreads();

    const float g0 = gamma[0], b0 = beta[0];
#pragma unroll
    for (int rr = 0; rr < 4; ++rr) {
        const int row = wave * 4 + rr;
        float v[4];
        float sum = 0.f;
#pragma unroll
        for (int j = 0; j < 4; ++j) {
            const int c = lane + 64 * j;
            v[j] = Y[row * YSTR + c] + xres[(size_t)(row0 + row) * DD + c];
            sum += v[j];
        }
#pragma unroll
        for (int m = 32; m >= 1; m >>= 1) sum += __shfl_xor(sum, m);
        const float mean = sum * (1.0f / DD);
        float var = 0.f;
#pragma unroll
        for (int j = 0; j < 4; ++j) { v[j] -= mean; var += v[j] * v[j]; }
#pragma unroll
        for (int m = 32; m >= 1; m >>= 1) var += __shfl_xor(var, m);
        var *= (1.0f / DD);
        const float rstd = 1.0f / sqrtf(var + ln_eps2());
#pragma unroll
        for (int j = 0; j < 4; ++j)
            xout[(size_t)(row0 + row) * DD + lane + 64 * j] = v[j] * rstd * g0 + b0;
    }
}

// ---------------- Kernel 4: FFN via MFMA + residual + LN (proven) ----------------
__global__ __launch_bounds__(256) void ffn_mfma_kernel(
    const float* __restrict__ xin,
    const ushort* __restrict__ w1th, const ushort* __restrict__ w1tl,
    const ushort* __restrict__ w2th, const ushort* __restrict__ w2tl,
    const float* __restrict__ b1, const float* __restrict__ b2,
    const float* __restrict__ gamma, const float* __restrict__ beta,
    float* __restrict__ xout)
{
    __shared__ __align__(16) char smem[(2 * 16 * XSTR + 2 * 16 * HSTR) * 2];
    ushort* Xh = (ushort*)smem;
    ushort* Xl = Xh + 16 * XSTR;
    ushort* Hh = Xl + 16 * XSTR;
    ushort* Hl = Hh + 16 * HSTR;
    float*  Y  = (float*)smem;

    const int tid  = threadIdx.x;
    const int wave = tid >> 6;
    const int lane = tid & 63;
    const int c16  = lane & 15;
    const int g    = lane >> 4;
    const int row0 = blockIdx.x * 16;

#pragma unroll
    for (int i = 0; i < 16; ++i) {
        const int p = i * 256 + tid;
        const int r = p >> 8, c = p & 255;
        const float f = xin[(size_t)(row0 + r) * DD + c];
        const ushort h = f2bf(f);
        Xh[r * XSTR + c] = h;
        Xl[r * XSTR + c] = f2bf(f - bf2f(h));
    }
    __syncthreads();

    short8 xf_h[8], xf_l[8];
#pragma unroll
    for (int kk = 0; kk < 8; ++kk) {
        xf_h[kk] = *(const short8*)&Xh[c16 * XSTR + kk * 32 + g * 8];
        xf_l[kk] = *(const short8*)&Xl[c16 * XSTR + kk * 32 + g * 8];
    }

    const int wbase = wave * 128;
#pragma unroll 2
    for (int t = 0; t < 8; ++t) {
        const int ncol = wbase + t * 16 + c16;
        const ushort* wh = w1th + (size_t)ncol * DD;
        const ushort* wl = w1tl + (size_t)ncol * DD;
        f32x4 acc = (f32x4)(0.f);
#pragma unroll
        for (int kk = 0; kk < 8; ++kk) {
            const short8 bh = *(const short8*)(wh + kk * 32 + g * 8);
            const short8 bl = *(const short8*)(wl + kk * 32 + g * 8);
            acc = __builtin_amdgcn_mfma_f32_16x16x32_bf16(xf_h[kk], bh, acc, 0, 0, 0);
            acc = __builtin_amdgcn_mfma_f32_16x16x32_bf16(xf_l[kk], bh, acc, 0, 0, 0);
            acc = __builtin_amdgcn_mfma_f32_16x16x32_bf16(xf_h[kk], bl, acc, 0, 0, 0);
        }
        const float bias = b1[ncol];
#pragma unroll
        for (int r = 0; r < 4; ++r) {
            const int m = 4 * g + r;
            const float hv = fmaxf(acc[r] + bias, 0.f);
            const ushort hh = f2bf(hv);
            Hh[m * HSTR + ncol] = hh;
            Hl[m * HSTR + ncol] = f2bf(hv - bf2f(hh));
        }
    }
    __syncthreads();

    const int obase = wave * 64;
    f32x4 acc2[4];
#pragma unroll
    for (int t = 0; t < 4; ++t) acc2[t] = (f32x4)(0.f);
#pragma unroll 2
    for (int kk = 0; kk < 16; ++kk) {
        const short8 ah = *(const short8*)&Hh[c16 * HSTR + kk * 32 + g * 8];
        const short8 al = *(const short8*)&Hl[c16 * HSTR + kk * 32 + g * 8];
#pragma unroll
        for (int t = 0; t < 4; ++t) {
            const int ncol = obase + t * 16 + c16;
            const short8 bh = *(const short8*)(w2th + (size_t)ncol * DFF + kk * 32 + g * 8);
            const short8 bl = *(const short8*)(w2tl + (size_t)ncol * DFF + kk * 32 + g * 8);
            acc2[t] = __builtin_amdgcn_mfma_f32_16x16x32_bf16(ah, bh, acc2[t], 0, 0, 0);
            acc2[t] = __builtin_amdgcn_mfma_f32_16x16x32_bf16(al, bh, acc2[t], 0, 0, 0);
            acc2[t] = __builtin_amdgcn_mfma_f32_16x16x32_bf16(ah, bl, acc2[t], 0, 0, 0);
        }
    }

#pragma unroll
    for (int t = 0; t < 4; ++t) {
        const int ncol = obase + t * 16 + c16;
#pragma unroll
        for (int r = 0; r < 4; ++r)
            Y[(4 * g + r) * YSTR + ncol] = acc2[t][r];
    }
    __syncthreads();

    const float g0 = gamma[0], b0 = beta[0];
#pragma unroll
    for (int rr = 0; rr < 4; ++rr) {
        const int row = wave * 4 + rr;
        float v[4];
        float sum = 0.f;
#pragma unroll
        for (int j = 0; j < 4; ++j) {
            const int c = lane + 64 * j;
            v[j] = Y[row * YSTR + c] + b2[c] + xin[(size_t)(row0 + row) * DD + c];
            sum += v[j];
        }
#pragma unroll
        for (int m = 32; m >= 1; m >>= 1) sum += __shfl_xor(sum, m);
        const float mean = sum * (1.0f / DD);
        float var = 0.f;
#pragma unroll
        for (int j = 0; j < 4; ++j) { v[j] -= mean; var += v[j] * v[j]; }
#pragma unroll
        for (int m = 32; m >= 1; m >>= 1) var += __shfl_xor(var, m);
        var *= (1.0f / DD);
        const float rstd = 1.0f / sqrtf(var + ln_eps2());
#pragma unroll
        for (int j = 0; j < 4; ++j)
            xout[(size_t)(row0 + row) * DD + lane + 64 * j] = v[j] * rstd * g0 + b0;
    }
}

// ---------------- host launch ----------------
extern "C" void kernel_launch(void* const* d_in, const int* in_sizes, int n_in,
                              void* d_out, int out_size, void* d_ws, size_t ws_size,
                              hipStream_t stream) {
    const float* x     = (const float*)d_in[0];
    const float* Wq    = (const float*)d_in[1];
    const float* Wk    = (const float*)d_in[2];
    const float* Wv    = (const float*)d_in[3];
    const float* Wo    = (const float*)d_in[4];
    const float* W1    = (const float*)d_in[5];
    const float* b1    = (const float*)d_in[6];
    const float* W2    = (const float*)d_in[7];
    const float* b2    = (const float*)d_in[8];
    const float* gamma = (const float*)d_in[9];
    const float* beta  = (const float*)d_in[10];
    float* out = (float*)d_out;

    const size_t NTOK = (size_t)BB * SS * DD;       // 1,048,576
    const size_t WFF  = (size_t)NL * DFF * DD;      // 262,144
    const size_t WOO  = (size_t)NL * DD * DD;       // 131,072
    const size_t WQKV = (size_t)NL * 768 * DD;      // 393,216
    float*  q    = (float*)d_ws;
    ushort* khi  = (ushort*)(q + NTOK);
    ushort* klo  = khi + NTOK;
    ushort* vt   = klo + NTOK;
    float*  o    = (float*)(vt + NTOK);
    float*  xa   = o + NTOK;
    float*  xb   = xa + NTOK;
    ushort* w1th = (ushort*)(xb + NTOK);
    ushort* w1tl = w1th + WFF;
    ushort* w2th = w1tl + WFF;
    ushort* w2tl = w2th + WFF;
    ushort* woth = w2tl + WFF;
    ushort* wotl = woth + WOO;
    ushort* wqth = wotl + WOO;
    ushort* wqtl = wqth + WQKV;

    wtrans_kernel<<<128, 256, 0, stream>>>(W1, W2, w1th, w1tl, w2th, w2tl);
    wotrans_kernel<<<NL * 16, 256, 0, stream>>>(Wo, woth, wotl);
    wqkv_trans_kernel<<<48, 256, 0, stream>>>(Wq, Wk, Wv, wqth, wqtl);

    const float* cur = x;
    for (int l = 0; l < NL; ++l) {
        qkv_mfma_kernel<<<BB * SS / 16, 256, 0, stream>>>(
            cur, wqth + (size_t)l * 768 * DD, wqtl + (size_t)l * 768 * DD,
            q, khi, klo, vt);
        attn_mfma_kernel<<<BB * HH * (SS / 64), 256, 0, stream>>>(q, khi, klo, vt, o);
        proj_mfma_kernel<<<BB * SS / 16, 256, 0, stream>>>(
            o, cur, woth + (size_t)l * DD * DD, wotl + (size_t)l * DD * DD,
            gamma + 2 * l, beta + 2 * l, xa);
        float* nxt = (l == NL - 1) ? out : xb;
        ffn_mfma_kernel<<<BB * SS / 16, 256, 0, stream>>>(
            xa, w1th + (size_t)l * DFF * DD, w1tl + (size_t)l * DFF * DD,
            w2th + (size_t)l * DD * DFF, w2tl + (size_t)l * DD * DFF,
            b1 + (size_t)l * DFF, b2 + (size_t)l * DD,
            gamma + 2 * l + 1, beta + 2 * l + 1, nxt);
        cur = nxt;
    }
}

// Round 15
// 317.361 us; speedup vs baseline: 5.2210x; 1.0323x over previous
//
#include <hip/hip_runtime.h>
#include <math.h>

#define BB 2
#define SS 2048
#define DD 256
#define HH 8
#define DKK 32
#define DVV 32
#define DFF 512
#define NL 2

// attention tiling
#define KT 128
#define KSTR 40
#define VSTR 136
#define PSTR 136
#define NSPLIT 4
#define SCHUNK (SS / NSPLIT)   // 512 keys per block

// gemm tiling
#define XSTR 264     // 16-row X tile stride (ushort)
#define HSTR 520     // 16-row H tile stride (ushort)
#define YSTR 260     // Y tile stride (float)

typedef __attribute__((ext_vector_type(8))) short short8;
typedef __attribute__((ext_vector_type(4))) float f32x4;

static __device__ __forceinline__ float ln_eps2() { return 1.4210854715202004e-14f; }

static __device__ __forceinline__ ushort f2bf(float f) {
    union { float f; unsigned u; } c; c.f = f;
    unsigned r = c.u + 0x7FFFu + ((c.u >> 16) & 1u);   // RNE
    return (ushort)(r >> 16);
}
static __device__ __forceinline__ float bf2f(ushort h) {
    union { unsigned u; float f; } c; c.u = ((unsigned)h) << 16;
    return c.f;
}

// ---------------- Kernel 0a: W1/W2 convert+transpose (proven) ----------------
__global__ __launch_bounds__(256) void wtrans_kernel(
    const float* __restrict__ W1, const float* __restrict__ W2,
    ushort* __restrict__ w1t_hi, ushort* __restrict__ w1t_lo,
    ushort* __restrict__ w2t_hi, ushort* __restrict__ w2t_lo)
{
    __shared__ ushort Th[64][72];
    __shared__ ushort Tl[64][72];
    const int bid = blockIdx.x;              // 0..127
    const float* src; ushort *dh, *dl; int R, C, tile;
    if (bid < 64) {                          // W1
        const int l = bid >> 5; tile = bid & 31;
        src = W1 + (size_t)l * DD * DFF;
        dh = w1t_hi + (size_t)l * DFF * DD; dl = w1t_lo + (size_t)l * DFF * DD;
        R = DD; C = DFF;
    } else {                                 // W2
        const int l = (bid - 64) >> 5; tile = (bid - 64) & 31;
        src = W2 + (size_t)l * DFF * DD;
        dh = w2t_hi + (size_t)l * DD * DFF; dl = w2t_lo + (size_t)l * DD * DFF;
        R = DFF; C = DD;
    }
    const int tilesC = C / 64;
    const int br = (tile / tilesC) * 64, bc = (tile % tilesC) * 64;
    const int tid = threadIdx.x;
#pragma unroll
    for (int i = 0; i < 16; ++i) {
        const int p = i * 256 + tid;
        const int r = p >> 6, c = p & 63;
        const float f = src[(size_t)(br + r) * C + bc + c];
        const ushort h = f2bf(f);
        Th[c][r] = h; Tl[c][r] = f2bf(f - bf2f(h));
    }
    __syncthreads();
#pragma unroll
    for (int i = 0; i < 16; ++i) {
        const int p = i * 256 + tid;
        const int r = p >> 6, c = p & 63;
        dh[(size_t)(bc + r) * R + br + c] = Th[r][c];
        dl[(size_t)(bc + r) * R + br + c] = Tl[r][c];
    }
}

// ---------------- Kernel 0b: Wo -> woT hi/lo [l][256][256] (proven) ----------------
__global__ __launch_bounds__(256) void wotrans_kernel(
    const float* __restrict__ Wo,
    ushort* __restrict__ wh, ushort* __restrict__ wl)
{
    __shared__ float T[64][65];
    const int l = blockIdx.x >> 4, tile = blockIdx.x & 15;
    const int tr = (tile >> 2) * 64;
    const int tc = (tile & 3) * 64;
    const float* src = Wo + (size_t)l * DD * DD;
    ushort* dh = wh + (size_t)l * DD * DD;
    ushort* dl = wl + (size_t)l * DD * DD;
    const int tid = threadIdx.x;
#pragma unroll
    for (int i = 0; i < 16; ++i) {
        const int p = i * 256 + tid;
        const int r = p >> 6, c = p & 63;
        T[r][c] = src[(size_t)(tr + r) * DD + tc + c];
    }
    __syncthreads();
#pragma unroll
    for (int i = 0; i < 16; ++i) {
        const int p = i * 256 + tid;
        const int r = p >> 6, c = p & 63;
        const float f = T[c][r];
        const size_t off = (size_t)(tc + r) * DD + tr + c;
        const ushort h = f2bf(f);
        dh[off] = h;
        dl[off] = f2bf(f - bf2f(h));
    }
}

// ---------------- Kernel 0c: Wq/Wk/Wv -> wqkvT hi/lo [l][768][256] (proven) ----------------
__global__ __launch_bounds__(256) void wqkv_trans_kernel(
    const float* __restrict__ Wq, const float* __restrict__ Wk,
    const float* __restrict__ Wv,
    ushort* __restrict__ qkvT_hi, ushort* __restrict__ qkvT_lo)
{
    __shared__ float T[DKK][DD + 1];
    const int bid = blockIdx.x;              // l*24 + src*8 + h
    const int l = bid / 24, rem = bid % 24, src = rem >> 3, h = rem & 7;
    const float* W = (src == 0 ? Wq : src == 1 ? Wk : Wv)
                     + ((size_t)l * HH + h) * DD * DKK;
    ushort* dh = qkvT_hi + ((size_t)l * 768 + src * 256 + h * 32) * DD;
    ushort* dl = qkvT_lo + ((size_t)l * 768 + src * 256 + h * 32) * DD;
    const int tid = threadIdx.x;
#pragma unroll
    for (int i = 0; i < 32; ++i) {           // W[d][dk] -> T[dk][d]
        const int p = i * 256 + tid;
        T[p & 31][p >> 5] = W[p];
    }
    __syncthreads();
#pragma unroll
    for (int i = 0; i < 32; ++i) {
        const int p = i * 256 + tid;
        const int dk = p >> 8, d = p & 255;
        const float f = T[dk][d];
        const ushort hh = f2bf(f);
        dh[dk * DD + d] = hh;
        dl[dk * DD + d] = f2bf(f - bf2f(hh));
    }
}

// ---------------- Kernel 1: QKV via MFMA (proven round-13) ----------------
__global__ __launch_bounds__(256) void qkv_mfma_kernel(
    const float* __restrict__ xin,
    const ushort* __restrict__ wth, const ushort* __restrict__ wtl,
    float* __restrict__ q, ushort* __restrict__ khi, ushort* __restrict__ klo,
    ushort* __restrict__ vt)
{
    __shared__ __align__(16) ushort Xh[16 * XSTR];
    __shared__ __align__(16) ushort Xl[16 * XSTR];

    const int tid = threadIdx.x, wave = tid >> 6, lane = tid & 63;
    const int c16 = lane & 15, g = lane >> 4;
    const int row0 = blockIdx.x * 16;

#pragma unroll
    for (int i = 0; i < 16; ++i) {
        const int p = i * 256 + tid;
        const int r = p >> 8, c = p & 255;
        const float f = xin[(size_t)(row0 + r) * DD + c];
        const ushort h = f2bf(f);
        Xh[r * XSTR + c] = h;
        Xl[r * XSTR + c] = f2bf(f - bf2f(h));
    }
    __syncthreads();

    short8 xf_h[8], xf_l[8];
#pragma unroll
    for (int kk = 0; kk < 8; ++kk) {
        xf_h[kk] = *(const short8*)&Xh[c16 * XSTR + kk * 32 + g * 8];
        xf_l[kk] = *(const short8*)&Xl[c16 * XSTR + kk * 32 + g * 8];
    }

    const int b = row0 / SS, s0 = row0 % SS;
    const int wbase = wave * 192;            // 4 waves x 192 = 768
#pragma unroll 2
    for (int t = 0; t < 12; ++t) {
        const int ncol = wbase + t * 16 + c16;
        const ushort* wh = wth + (size_t)ncol * DD;
        const ushort* wl = wtl + (size_t)ncol * DD;
        f32x4 acc = (f32x4)(0.f);
#pragma unroll
        for (int kk = 0; kk < 8; ++kk) {
            const short8 bh = *(const short8*)(wh + kk * 32 + g * 8);
            const short8 bl = *(const short8*)(wl + kk * 32 + g * 8);
            acc = __builtin_amdgcn_mfma_f32_16x16x32_bf16(xf_h[kk], bh, acc, 0, 0, 0);
            acc = __builtin_amdgcn_mfma_f32_16x16x32_bf16(xf_l[kk], bh, acc, 0, 0, 0);
            acc = __builtin_amdgcn_mfma_f32_16x16x32_bf16(xf_h[kk], bl, acc, 0, 0, 0);
        }
        const int src = ncol >> 8, h = (ncol >> 5) & 7, dk = ncol & 31;
        const size_t base = ((size_t)(b * HH + h) * SS + s0) * DKK + dk;
#pragma unroll
        for (int r = 0; r < 4; ++r) {
            if (src == 0) {
                q[base + (size_t)(4 * g + r) * DKK] = acc[r];
            } else if (src == 1) {
                const size_t off = base + (size_t)(4 * g + r) * DKK;
                const ushort hh = f2bf(acc[r]);
                khi[off] = hh;
                klo[off] = f2bf(acc[r] - bf2f(hh));
            } else {
                vt[((size_t)(b * HH + h) * DVV + dk) * SS + s0 + 4 * g + r] = f2bf(acc[r]);
            }
        }
    }
}

// ---------------- Kernel 2: MFMA flash attention, split-K ----------------
// grid = B*H*(S/64)*NSPLIT; block = 4 waves x 16 queries, 512-key chunk.
__global__ __launch_bounds__(256) void attn_mfma_kernel(
    const float* __restrict__ q, const ushort* __restrict__ khi,
    const ushort* __restrict__ klo, const ushort* __restrict__ vt,
    float* __restrict__ opart, float* __restrict__ ml)
{
    __shared__ ushort KhS[KT * KSTR];
    __shared__ ushort KlS[KT * KSTR];
    __shared__ ushort VtS[32 * VSTR];
    __shared__ ushort PlS[4 * 16 * PSTR];

    const int tid  = threadIdx.x;
    const int wave = tid >> 6;
    const int lane = tid & 63;
    const int c16  = lane & 15;
    const int g    = lane >> 4;

    const int nqb = SS / 64;                 // 32
    const int bh  = blockIdx.x / (nqb * NSPLIT);
    const int rem = blockIdx.x % (nqb * NSPLIT);
    const int qb  = rem / NSPLIT;
    const int sp  = rem % NSPLIT;
    const int qbase = qb * 64 + wave * 16;

    const float*  qp  = q   + (size_t)bh * SS * DKK;
    const ushort* khp = khi + (size_t)bh * SS * DKK;
    const ushort* klp = klo + (size_t)bh * SS * DKK;
    const ushort* vtp = vt  + (size_t)bh * DVV * SS;

    short8 qhi, qlo;
    {
        const float* qr = qp + (size_t)(qbase + c16) * DKK + g * 8;
#pragma unroll
        for (int j = 0; j < 8; ++j) {
            const ushort h = f2bf(qr[j]);
            qhi[j] = (short)h;
            qlo[j] = (short)f2bf(qr[j] - bf2f(h));
        }
    }

    float m_r[4], l_r[4];
    f32x4 oacc0, oacc1;
#pragma unroll
    for (int r = 0; r < 4; ++r) { m_r[r] = -1e30f; l_r[r] = 0.f; }
    oacc0 = (f32x4)(0.f); oacc1 = (f32x4)(0.f);
    const f32x4 zero = (f32x4)(0.f);

    ushort* Pw = PlS + wave * 16 * PSTR;

    for (int kt = sp * SCHUNK; kt < (sp + 1) * SCHUNK; kt += KT) {
#pragma unroll
        for (int i = 0; i < 4; ++i) {
            const int p = i * 256 + tid;
            const int row = p >> 3;
            const int col4 = (p & 7) * 4;
            const uint2 h8 = *(const uint2*)(khp + (size_t)(kt + row) * DKK + col4);
            const uint2 l8 = *(const uint2*)(klp + (size_t)(kt + row) * DKK + col4);
            *(uint2*)&KhS[row * KSTR + col4] = h8;
            *(uint2*)&KlS[row * KSTR + col4] = l8;
        }
#pragma unroll
        for (int i = 0; i < 4; ++i) {
            const int p = i * 256 + tid;
            const int dv = p >> 5;
            const int s8 = (p & 31) * 4;
            const uint2 v8 = *(const uint2*)(vtp + (size_t)dv * SS + kt + s8);
            *(uint2*)&VtS[dv * VSTR + s8] = v8;
        }
        __syncthreads();

        f32x4 sc[8];
#pragma unroll
        for (int t = 0; t < 8; ++t) {
            const short8 khf = *(const short8*)&KhS[(t * 16 + c16) * KSTR + g * 8];
            const short8 klf = *(const short8*)&KlS[(t * 16 + c16) * KSTR + g * 8];
            f32x4 s = __builtin_amdgcn_mfma_f32_16x16x32_bf16(qlo, khf, zero, 0, 0, 0);
            s = __builtin_amdgcn_mfma_f32_16x16x32_bf16(qhi, klf, s, 0, 0, 0);
            s = __builtin_amdgcn_mfma_f32_16x16x32_bf16(qhi, khf, s, 0, 0, 0);
            sc[t] = s;
        }

#pragma unroll
        for (int r = 0; r < 4; ++r) {
            float tm = sc[0][r];
#pragma unroll
            for (int t = 1; t < 8; ++t) tm = fmaxf(tm, sc[t][r]);
            tm = fmaxf(tm, __shfl_xor(tm, 1));
            tm = fmaxf(tm, __shfl_xor(tm, 2));
            tm = fmaxf(tm, __shfl_xor(tm, 4));
            tm = fmaxf(tm, __shfl_xor(tm, 8));
            const float nm = fmaxf(m_r[r], tm);
            const float scale = __expf(m_r[r] - nm);
            m_r[r] = nm;
            float psum = 0.f;
#pragma unroll
            for (int t = 0; t < 8; ++t) {
                const float p = __expf(sc[t][r] - nm);
                sc[t][r] = p;
                psum += p;
            }
            psum += __shfl_xor(psum, 1);
            psum += __shfl_xor(psum, 2);
            psum += __shfl_xor(psum, 4);
            psum += __shfl_xor(psum, 8);
            l_r[r] = l_r[r] * scale + psum;
            oacc0[r] *= scale;
            oacc1[r] *= scale;
        }

#pragma unroll
        for (int t = 0; t < 8; ++t)
#pragma unroll
            for (int r = 0; r < 4; ++r)
                Pw[(g * 4 + r) * PSTR + t * 16 + c16] = f2bf(sc[t][r]);

#pragma unroll
        for (int s4 = 0; s4 < 4; ++s4) {
            const short8 pfrag  = *(const short8*)&Pw[c16 * PSTR + s4 * 32 + g * 8];
            const short8 vfrag0 = *(const short8*)&VtS[c16 * VSTR + s4 * 32 + g * 8];
            const short8 vfrag1 = *(const short8*)&VtS[(16 + c16) * VSTR + s4 * 32 + g * 8];
            oacc0 = __builtin_amdgcn_mfma_f32_16x16x32_bf16(pfrag, vfrag0, oacc0, 0, 0, 0);
            oacc1 = __builtin_amdgcn_mfma_f32_16x16x32_bf16(pfrag, vfrag1, oacc1, 0, 0, 0);
        }
        __syncthreads();
    }

    // epilogue: unnormalized partials + (m,l) per q-row
    const size_t pbase = (size_t)(sp * BB * HH + bh) * SS;
#pragma unroll
    for (int r = 0; r < 4; ++r) {
        const int qrow = qbase + g * 4 + r;
        float* op = opart + (pbase + qrow) * DVV;
        op[c16]      = oacc0[r];
        op[16 + c16] = oacc1[r];
        if (c16 == 0) {
            ml[(pbase + qrow) * 2]     = m_r[r];
            ml[(pbase + qrow) * 2 + 1] = l_r[r];
        }
    }
}

// ---------------- Kernel 2b: split-K merge -> o in concat layout ----------------
// grid = B*H*(S/128); 256 threads.
__global__ __launch_bounds__(256) void attn_merge_kernel(
    const float* __restrict__ opart, const float* __restrict__ ml,
    float* __restrict__ o)
{
    const int nch = SS / 128;                // 16
    const int bh = blockIdx.x / nch;
    const int chunk = blockIdx.x % nch;
    const int q0 = chunk * 128;
    const int b = bh >> 3, h = bh & 7;
    const int tid = threadIdx.x;

#pragma unroll
    for (int i = 0; i < 16; ++i) {
        const int p = i * 256 + tid;
        const int ql = p >> 5, dv = p & 31;
        const int qr = q0 + ql;
        float ms[NSPLIT], ls[NSPLIT];
#pragma unroll
        for (int s = 0; s < NSPLIT; ++s) {
            const size_t pb = (size_t)(s * BB * HH + bh) * SS + qr;
            ms[s] = ml[pb * 2];
            ls[s] = ml[pb * 2 + 1];
        }
        float M = ms[0];
#pragma unroll
        for (int s = 1; s < NSPLIT; ++s) M = fmaxf(M, ms[s]);
        float L = 0.f, acc = 0.f;
#pragma unroll
        for (int s = 0; s < NSPLIT; ++s) {
            const float w = __expf(ms[s] - M);
            L += w * ls[s];
            acc += w * opart[((size_t)(s * BB * HH + bh) * SS + qr) * DVV + dv];
        }
        o[(size_t)(b * SS + qr) * (HH * DVV) + h * DVV + dv] = acc / L;
    }
}

// ---------------- Kernel 3: proj via MFMA (proven) ----------------
__global__ __launch_bounds__(256) void proj_mfma_kernel(
    const float* __restrict__ conc, const float* __restrict__ xres,
    const ushort* __restrict__ wth, const ushort* __restrict__ wtl,
    const float* __restrict__ gamma, const float* __restrict__ beta,
    float* __restrict__ xout)
{
    __shared__ __align__(16) ushort Xh[16 * XSTR];
    __shared__ __align__(16) ushort Xl[16 * XSTR];
    __shared__ float Y[16 * YSTR];

    const int tid = threadIdx.x, wave = tid >> 6, lane = tid & 63;
    const int c16 = lane & 15, g = lane >> 4;
    const int row0 = blockIdx.x * 16;

#pragma unroll
    for (int i = 0; i < 16; ++i) {
        const int p = i * 256 + tid;
        const int r = p >> 8, c = p & 255;
        const float f = conc[(size_t)(row0 + r) * DD + c];
        const ushort h = f2bf(f);
        Xh[r * XSTR + c] = h;
        Xl[r * XSTR + c] = f2bf(f - bf2f(h));
    }
    __syncthreads();

    short8 xf_h[8], xf_l[8];
#pragma unroll
    for (int kk = 0; kk < 8; ++kk) {
        xf_h[kk] = *(const short8*)&Xh[c16 * XSTR + kk * 32 + g * 8];
        xf_l[kk] = *(const short8*)&Xl[c16 * XSTR + kk * 32 + g * 8];
    }

    const int wbase = wave * 64;
#pragma unroll 2
    for (int t = 0; t < 4; ++t) {
        const int ncol = wbase + t * 16 + c16;
        const ushort* wh = wth + (size_t)ncol * DD;
        const ushort* wl = wtl + (size_t)ncol * DD;
        f32x4 acc = (f32x4)(0.f);
#pragma unroll
        for (int kk = 0; kk < 8; ++kk) {
            const short8 bh = *(const short8*)(wh + kk * 32 + g * 8);
            const short8 bl = *(const short8*)(wl + kk * 32 + g * 8);
            acc = __builtin_amdgcn_mfma_f32_16x16x32_bf16(xf_h[kk], bh, acc, 0, 0, 0);
            acc = __builtin_amdgcn_mfma_f32_16x16x32_bf16(xf_l[kk], bh, acc, 0, 0, 0);
            acc = __builtin_amdgcn_mfma_f32_16x16x32_bf16(xf_h[kk], bl, acc, 0, 0, 0);
        }
#pragma unroll
        for (int r = 0; r < 4; ++r)
            Y[(4 * g + r) * YSTR + ncol] = acc[r];
    }
    __syncthreads();

    const float g0 = gamma[0], b0 = beta[0];
#pragma unroll
    for (int rr = 0; rr < 4; ++rr) {
        const int row = wave * 4 + rr;
        float v[4];
        float sum = 0.f;
#pragma unroll
        for (int j = 0; j < 4; ++j) {
            const int c = lane + 64 * j;
            v[j] = Y[row * YSTR + c] + xres[(size_t)(row0 + row) * DD + c];
            sum += v[j];
        }
#pragma unroll
        for (int m = 32; m >= 1; m >>= 1) sum += __shfl_xor(sum, m);
        const float mean = sum * (1.0f / DD);
        float var = 0.f;
#pragma unroll
        for (int j = 0; j < 4; ++j) { v[j] -= mean; var += v[j] * v[j]; }
#pragma unroll
        for (int m = 32; m >= 1; m >>= 1) var += __shfl_xor(var, m);
        var *= (1.0f / DD);
        const float rstd = 1.0f / sqrtf(var + ln_eps2());
#pragma unroll
        for (int j = 0; j < 4; ++j)
            xout[(size_t)(row0 + row) * DD + lane + 64 * j] = v[j] * rstd * g0 + b0;
    }
}

// ---------------- Kernel 4: FFN via MFMA + residual + LN (proven) ----------------
__global__ __launch_bounds__(256) void ffn_mfma_kernel(
    const float* __restrict__ xin,
    const ushort* __restrict__ w1th, const ushort* __restrict__ w1tl,
    const ushort* __restrict__ w2th, const ushort* __restrict__ w2tl,
    const float* __restrict__ b1, const float* __restrict__ b2,
    const float* __restrict__ gamma, const float* __restrict__ beta,
    float* __restrict__ xout)
{
    __shared__ __align__(16) char smem[(2 * 16 * XSTR + 2 * 16 * HSTR) * 2];
    ushort* Xh = (ushort*)smem;
    ushort* Xl = Xh + 16 * XSTR;
    ushort* Hh = Xl + 16 * XSTR;
    ushort* Hl = Hh + 16 * HSTR;
    float*  Y  = (float*)smem;

    const int tid  = threadIdx.x;
    const int wave = tid >> 6;
    const int lane = tid & 63;
    const int c16  = lane & 15;
    const int g    = lane >> 4;
    const int row0 = blockIdx.x * 16;

#pragma unroll
    for (int i = 0; i < 16; ++i) {
        const int p = i * 256 + tid;
        const int r = p >> 8, c = p & 255;
        const float f = xin[(size_t)(row0 + r) * DD + c];
        const ushort h = f2bf(f);
        Xh[r * XSTR + c] = h;
        Xl[r * XSTR + c] = f2bf(f - bf2f(h));
    }
    __syncthreads();

    short8 xf_h[8], xf_l[8];
#pragma unroll
    for (int kk = 0; kk < 8; ++kk) {
        xf_h[kk] = *(const short8*)&Xh[c16 * XSTR + kk * 32 + g * 8];
        xf_l[kk] = *(const short8*)&Xl[c16 * XSTR + kk * 32 + g * 8];
    }

    const int wbase = wave * 128;
#pragma unroll 2
    for (int t = 0; t < 8; ++t) {
        const int ncol = wbase + t * 16 + c16;
        const ushort* wh = w1th + (size_t)ncol * DD;
        const ushort* wl = w1tl + (size_t)ncol * DD;
        f32x4 acc = (f32x4)(0.f);
#pragma unroll
        for (int kk = 0; kk < 8; ++kk) {
            const short8 bh = *(const short8*)(wh + kk * 32 + g * 8);
            const short8 bl = *(const short8*)(wl + kk * 32 + g * 8);
            acc = __builtin_amdgcn_mfma_f32_16x16x32_bf16(xf_h[kk], bh, acc, 0, 0, 0);
            acc = __builtin_amdgcn_mfma_f32_16x16x32_bf16(xf_l[kk], bh, acc, 0, 0, 0);
            acc = __builtin_amdgcn_mfma_f32_16x16x32_bf16(xf_h[kk], bl, acc, 0, 0, 0);
        }
        const float bias = b1[ncol];
#pragma unroll
        for (int r = 0; r < 4; ++r) {
            const int m = 4 * g + r;
            const float hv = fmaxf(acc[r] + bias, 0.f);
            const ushort hh = f2bf(hv);
            Hh[m * HSTR + ncol] = hh;
            Hl[m * HSTR + ncol] = f2bf(hv - bf2f(hh));
        }
    }
    __syncthreads();

    const int obase = wave * 64;
    f32x4 acc2[4];
#pragma unroll
    for (int t = 0; t < 4; ++t) acc2[t] = (f32x4)(0.f);
#pragma unroll 2
    for (int kk = 0; kk < 16; ++kk) {
        const short8 ah = *(const short8*)&Hh[c16 * HSTR + kk * 32 + g * 8];
        const short8 al = *(const short8*)&Hl[c16 * HSTR + kk * 32 + g * 8];
#pragma unroll
        for (int t = 0; t < 4; ++t) {
            const int ncol = obase + t * 16 + c16;
            const short8 bh = *(const short8*)(w2th + (size_t)ncol * DFF + kk * 32 + g * 8);
            const short8 bl = *(const short8*)(w2tl + (size_t)ncol * DFF + kk * 32 + g * 8);
            acc2[t] = __builtin_amdgcn_mfma_f32_16x16x32_bf16(ah, bh, acc2[t], 0, 0, 0);
            acc2[t] = __builtin_amdgcn_mfma_f32_16x16x32_bf16(al, bh, acc2[t], 0, 0, 0);
            acc2[t] = __builtin_amdgcn_mfma_f32_16x16x32_bf16(ah, bl, acc2[t], 0, 0, 0);
        }
    }

#pragma unroll
    for (int t = 0; t < 4; ++t) {
        const int ncol = obase + t * 16 + c16;
#pragma unroll
        for (int r = 0; r < 4; ++r)
            Y[(4 * g + r) * YSTR + ncol] = acc2[t][r];
    }
    __syncthreads();

    const float g0 = gamma[0], b0 = beta[0];
#pragma unroll
    for (int rr = 0; rr < 4; ++rr) {
        const int row = wave * 4 + rr;
        float v[4];
        float sum = 0.f;
#pragma unroll
        for (int j = 0; j < 4; ++j) {
            const int c = lane + 64 * j;
            v[j] = Y[row * YSTR + c] + b2[c] + xin[(size_t)(row0 + row) * DD + c];
            sum += v[j];
        }
#pragma unroll
        for (int m = 32; m >= 1; m >>= 1) sum += __shfl_xor(sum, m);
        const float mean = sum * (1.0f / DD);
        float var = 0.f;
#pragma unroll
        for (int j = 0; j < 4; ++j) { v[j] -= mean; var += v[j] * v[j]; }
#pragma unroll
        for (int m = 32; m >= 1; m >>= 1) var += __shfl_xor(var, m);
        var *= (1.0f / DD);
        const float rstd = 1.0f / sqrtf(var + ln_eps2());
#pragma unroll
        for (int j = 0; j < 4; ++j)
            xout[(size_t)(row0 + row) * DD + lane + 64 * j] = v[j] * rstd * g0 + b0;
    }
}

// ---------------- host launch ----------------
extern "C" void kernel_launch(void* const* d_in, const int* in_sizes, int n_in,
                              void* d_out, int out_size, void* d_ws, size_t ws_size,
                              hipStream_t stream) {
    const float* x     = (const float*)d_in[0];
    const float* Wq    = (const float*)d_in[1];
    const float* Wk    = (const float*)d_in[2];
    const float* Wv    = (const float*)d_in[3];
    const float* Wo    = (const float*)d_in[4];
    const float* W1    = (const float*)d_in[5];
    const float* b1    = (const float*)d_in[6];
    const float* W2    = (const float*)d_in[7];
    const float* b2    = (const float*)d_in[8];
    const float* gamma = (const float*)d_in[9];
    const float* beta  = (const float*)d_in[10];
    float* out = (float*)d_out;

    const size_t NTOK = (size_t)BB * SS * DD;       // 1,048,576
    const size_t WFF  = (size_t)NL * DFF * DD;      // 262,144
    const size_t WOO  = (size_t)NL * DD * DD;       // 131,072
    const size_t WQKV = (size_t)NL * 768 * DD;      // 393,216
    float*  q    = (float*)d_ws;
    ushort* khi  = (ushort*)(q + NTOK);
    ushort* klo  = khi + NTOK;
    ushort* vt   = klo + NTOK;
    float*  o    = (float*)(vt + NTOK);
    float*  xa   = o + NTOK;
    float*  xb   = xa + NTOK;
    ushort* w1th = (ushort*)(xb + NTOK);
    ushort* w1tl = w1th + WFF;
    ushort* w2th = w1tl + WFF;
    ushort* w2tl = w2th + WFF;
    ushort* woth = w2tl + WFF;
    ushort* wotl = woth + WOO;
    ushort* wqth = wotl + WOO;
    ushort* wqtl = wqth + WQKV;
    float*  opart = (float*)(wqtl + WQKV);          // NSPLIT*B*H*S*DVV f32 = 16 MB
    float*  ml    = opart + (size_t)NSPLIT * BB * HH * SS * DVV;  // 1 MB

    wtrans_kernel<<<128, 256, 0, stream>>>(W1, W2, w1th, w1tl, w2th, w2tl);
    wotrans_kernel<<<NL * 16, 256, 0, stream>>>(Wo, woth, wotl);
    wqkv_trans_kernel<<<48, 256, 0, stream>>>(Wq, Wk, Wv, wqth, wqtl);

    const float* cur = x;
    for (int l = 0; l < NL; ++l) {
        qkv_mfma_kernel<<<BB * SS / 16, 256, 0, stream>>>(
            cur, wqth + (size_t)l * 768 * DD, wqtl + (size_t)l * 768 * DD,
            q, khi, klo, vt);
        attn_mfma_kernel<<<BB * HH * (SS / 64) * NSPLIT, 256, 0, stream>>>(
            q, khi, klo, vt, opart, ml);
        attn_merge_kernel<<<BB * HH * (SS / 128), 256, 0, stream>>>(opart, ml, o);
        proj_mfma_kernel<<<BB * SS / 16, 256, 0, stream>>>(
            o, cur, woth + (size_t)l * DD * DD, wotl + (size_t)l * DD * DD,
            gamma + 2 * l, beta + 2 * l, xa);
        float* nxt = (l == NL - 1) ? out : xb;
        ffn_mfma_kernel<<<BB * SS / 16, 256, 0, stream>>>(
            xa, w1th + (size_t)l * DFF * DD, w1tl + (size_t)l * DFF * DD,
            w2th + (size_t)l * DD * DFF, w2tl + (size_t)l * DD * DFF,
            b1 + (size_t)l * DFF, b2 + (size_t)l * DD,
            gamma + 2 * l + 1, beta + 2 * l + 1, nxt);
        cur = nxt;
    }
}

// Round 16
// 299.280 us; speedup vs baseline: 5.5364x; 1.0604x over previous
//
#include <hip/hip_runtime.h>
#include <math.h>

#define BB 2
#define SS 2048
#define DD 256
#define HH 8
#define DKK 32
#define DVV 32
#define DFF 512
#define NL 2

// attention tiling
#define KT 64
#define KSTR 40
#define VSTR 72
#define PSTR 72
#define NSPLIT 4
#define SCHUNK (SS / NSPLIT)   // 512 keys per block

// gemm tiling
#define XSTR 264     // 16-row X tile stride (ushort)
#define HSTR 520     // 16-row H tile stride (ushort)
#define YSTR 260     // Y tile stride (float)

typedef __attribute__((ext_vector_type(8))) short short8;
typedef __attribute__((ext_vector_type(4))) float f32x4;

static __device__ __forceinline__ float ln_eps2() { return 1.4210854715202004e-14f; }

static __device__ __forceinline__ ushort f2bf(float f) {
    union { float f; unsigned u; } c; c.f = f;
    unsigned r = c.u + 0x7FFFu + ((c.u >> 16) & 1u);   // RNE
    return (ushort)(r >> 16);
}
static __device__ __forceinline__ float bf2f(ushort h) {
    union { unsigned u; float f; } c; c.u = ((unsigned)h) << 16;
    return c.f;
}

// ---------------- Kernel 0a: W1/W2 convert+transpose (proven) ----------------
__global__ __launch_bounds__(256) void wtrans_kernel(
    const float* __restrict__ W1, const float* __restrict__ W2,
    ushort* __restrict__ w1t_hi, ushort* __restrict__ w1t_lo,
    ushort* __restrict__ w2t_hi, ushort* __restrict__ w2t_lo)
{
    __shared__ ushort Th[64][72];
    __shared__ ushort Tl[64][72];
    const int bid = blockIdx.x;              // 0..127
    const float* src; ushort *dh, *dl; int R, C, tile;
    if (bid < 64) {                          // W1
        const int l = bid >> 5; tile = bid & 31;
        src = W1 + (size_t)l * DD * DFF;
        dh = w1t_hi + (size_t)l * DFF * DD; dl = w1t_lo + (size_t)l * DFF * DD;
        R = DD; C = DFF;
    } else {                                 // W2
        const int l = (bid - 64) >> 5; tile = (bid - 64) & 31;
        src = W2 + (size_t)l * DFF * DD;
        dh = w2t_hi + (size_t)l * DD * DFF; dl = w2t_lo + (size_t)l * DD * DFF;
        R = DFF; C = DD;
    }
    const int tilesC = C / 64;
    const int br = (tile / tilesC) * 64, bc = (tile % tilesC) * 64;
    const int tid = threadIdx.x;
#pragma unroll
    for (int i = 0; i < 16; ++i) {
        const int p = i * 256 + tid;
        const int r = p >> 6, c = p & 63;
        const float f = src[(size_t)(br + r) * C + bc + c];
        const ushort h = f2bf(f);
        Th[c][r] = h; Tl[c][r] = f2bf(f - bf2f(h));
    }
    __syncthreads();
#pragma unroll
    for (int i = 0; i < 16; ++i) {
        const int p = i * 256 + tid;
        const int r = p >> 6, c = p & 63;
        dh[(size_t)(bc + r) * R + br + c] = Th[r][c];
        dl[(size_t)(bc + r) * R + br + c] = Tl[r][c];
    }
}

// ---------------- Kernel 0b: Wo -> woT hi/lo [l][256][256] (proven) ----------------
__global__ __launch_bounds__(256) void wotrans_kernel(
    const float* __restrict__ Wo,
    ushort* __restrict__ wh, ushort* __restrict__ wl)
{
    __shared__ float T[64][65];
    const int l = blockIdx.x >> 4, tile = blockIdx.x & 15;
    const int tr = (tile >> 2) * 64;
    const int tc = (tile & 3) * 64;
    const float* src = Wo + (size_t)l * DD * DD;
    ushort* dh = wh + (size_t)l * DD * DD;
    ushort* dl = wl + (size_t)l * DD * DD;
    const int tid = threadIdx.x;
#pragma unroll
    for (int i = 0; i < 16; ++i) {
        const int p = i * 256 + tid;
        const int r = p >> 6, c = p & 63;
        T[r][c] = src[(size_t)(tr + r) * DD + tc + c];
    }
    __syncthreads();
#pragma unroll
    for (int i = 0; i < 16; ++i) {
        const int p = i * 256 + tid;
        const int r = p >> 6, c = p & 63;
        const float f = T[c][r];
        const size_t off = (size_t)(tc + r) * DD + tr + c;
        const ushort h = f2bf(f);
        dh[off] = h;
        dl[off] = f2bf(f - bf2f(h));
    }
}

// ---------------- Kernel 0c: Wq/Wk/Wv -> wqkvT hi/lo [l][768][256] (proven) ----------------
__global__ __launch_bounds__(256) void wqkv_trans_kernel(
    const float* __restrict__ Wq, const float* __restrict__ Wk,
    const float* __restrict__ Wv,
    ushort* __restrict__ qkvT_hi, ushort* __restrict__ qkvT_lo)
{
    __shared__ float T[DKK][DD + 1];
    const int bid = blockIdx.x;              // l*24 + src*8 + h
    const int l = bid / 24, rem = bid % 24, src = rem >> 3, h = rem & 7;
    const float* W = (src == 0 ? Wq : src == 1 ? Wk : Wv)
                     + ((size_t)l * HH + h) * DD * DKK;
    ushort* dh = qkvT_hi + ((size_t)l * 768 + src * 256 + h * 32) * DD;
    ushort* dl = qkvT_lo + ((size_t)l * 768 + src * 256 + h * 32) * DD;
    const int tid = threadIdx.x;
#pragma unroll
    for (int i = 0; i < 32; ++i) {           // W[d][dk] -> T[dk][d]
        const int p = i * 256 + tid;
        T[p & 31][p >> 5] = W[p];
    }
    __syncthreads();
#pragma unroll
    for (int i = 0; i < 32; ++i) {
        const int p = i * 256 + tid;
        const int dk = p >> 8, d = p & 255;
        const float f = T[dk][d];
        const ushort hh = f2bf(f);
        dh[dk * DD + d] = hh;
        dl[dk * DD + d] = f2bf(f - bf2f(hh));
    }
}

// ---------------- Kernel 1: QKV via MFMA, 2-way column split ----------------
// grid = (B*S/16)*2; 16 rows x 384-col half per WG; 4 waves x 6 tiles.
__global__ __launch_bounds__(256) void qkv_mfma_kernel(
    const float* __restrict__ xin,
    const ushort* __restrict__ wth, const ushort* __restrict__ wtl,
    float* __restrict__ q, ushort* __restrict__ khi, ushort* __restrict__ klo,
    ushort* __restrict__ vt)
{
    __shared__ __align__(16) ushort Xh[16 * XSTR];
    __shared__ __align__(16) ushort Xl[16 * XSTR];

    const int tid = threadIdx.x, wave = tid >> 6, lane = tid & 63;
    const int c16 = lane & 15, g = lane >> 4;
    const int row0 = (blockIdx.x >> 1) * 16;
    const int half = blockIdx.x & 1;

#pragma unroll
    for (int i = 0; i < 16; ++i) {
        const int p = i * 256 + tid;
        const int r = p >> 8, c = p & 255;
        const float f = xin[(size_t)(row0 + r) * DD + c];
        const ushort h = f2bf(f);
        Xh[r * XSTR + c] = h;
        Xl[r * XSTR + c] = f2bf(f - bf2f(h));
    }
    __syncthreads();

    short8 xf_h[8], xf_l[8];
#pragma unroll
    for (int kk = 0; kk < 8; ++kk) {
        xf_h[kk] = *(const short8*)&Xh[c16 * XSTR + kk * 32 + g * 8];
        xf_l[kk] = *(const short8*)&Xl[c16 * XSTR + kk * 32 + g * 8];
    }

    const int b = row0 / SS, s0 = row0 % SS;
    const int wbase = half * 384 + wave * 96;   // 2 halves x 4 waves x 96 = 768
#pragma unroll 2
    for (int t = 0; t < 6; ++t) {
        const int ncol = wbase + t * 16 + c16;
        const ushort* wh = wth + (size_t)ncol * DD;
        const ushort* wl = wtl + (size_t)ncol * DD;
        f32x4 acc = (f32x4)(0.f);
#pragma unroll
        for (int kk = 0; kk < 8; ++kk) {
            const short8 bh = *(const short8*)(wh + kk * 32 + g * 8);
            const short8 bl = *(const short8*)(wl + kk * 32 + g * 8);
            acc = __builtin_amdgcn_mfma_f32_16x16x32_bf16(xf_h[kk], bh, acc, 0, 0, 0);
            acc = __builtin_amdgcn_mfma_f32_16x16x32_bf16(xf_l[kk], bh, acc, 0, 0, 0);
            acc = __builtin_amdgcn_mfma_f32_16x16x32_bf16(xf_h[kk], bl, acc, 0, 0, 0);
        }
        const int src = ncol >> 8, h = (ncol >> 5) & 7, dk = ncol & 31;
        const size_t base = ((size_t)(b * HH + h) * SS + s0) * DKK + dk;
#pragma unroll
        for (int r = 0; r < 4; ++r) {
            if (src == 0) {
                q[base + (size_t)(4 * g + r) * DKK] = acc[r];
            } else if (src == 1) {
                const size_t off = base + (size_t)(4 * g + r) * DKK;
                const ushort hh = f2bf(acc[r]);
                khi[off] = hh;
                klo[off] = f2bf(acc[r] - bf2f(hh));
            } else {
                vt[((size_t)(b * HH + h) * DVV + dk) * SS + s0 + 4 * g + r] = f2bf(acc[r]);
            }
        }
    }
}

// ---------------- Kernel 2: MFMA flash attention, split-K, KT=64 ----------------
// grid = B*H*(S/64)*NSPLIT; block = 4 waves x 16 queries, 512-key chunk.
// LDS = 24 KB -> 6 blocks/CU.
__global__ __launch_bounds__(256) void attn_mfma_kernel(
    const float* __restrict__ q, const ushort* __restrict__ khi,
    const ushort* __restrict__ klo, const ushort* __restrict__ vt,
    float* __restrict__ opart, float* __restrict__ ml)
{
    __shared__ ushort KhS[KT * KSTR];        // 5120 B
    __shared__ ushort KlS[KT * KSTR];        // 5120 B
    __shared__ ushort VtS[32 * VSTR];        // 4608 B
    __shared__ ushort PlS[4 * 16 * PSTR];    // 9216 B

    const int tid  = threadIdx.x;
    const int wave = tid >> 6;
    const int lane = tid & 63;
    const int c16  = lane & 15;
    const int g    = lane >> 4;

    const int nqb = SS / 64;                 // 32
    const int bh  = blockIdx.x / (nqb * NSPLIT);
    const int rem = blockIdx.x % (nqb * NSPLIT);
    const int qb  = rem / NSPLIT;
    const int sp  = rem % NSPLIT;
    const int qbase = qb * 64 + wave * 16;

    const float*  qp  = q   + (size_t)bh * SS * DKK;
    const ushort* khp = khi + (size_t)bh * SS * DKK;
    const ushort* klp = klo + (size_t)bh * SS * DKK;
    const ushort* vtp = vt  + (size_t)bh * DVV * SS;

    short8 qhi, qlo;
    {
        const float* qr = qp + (size_t)(qbase + c16) * DKK + g * 8;
#pragma unroll
        for (int j = 0; j < 8; ++j) {
            const ushort h = f2bf(qr[j]);
            qhi[j] = (short)h;
            qlo[j] = (short)f2bf(qr[j] - bf2f(h));
        }
    }

    float m_r[4], l_r[4];
    f32x4 oacc0, oacc1;
#pragma unroll
    for (int r = 0; r < 4; ++r) { m_r[r] = -1e30f; l_r[r] = 0.f; }
    oacc0 = (f32x4)(0.f); oacc1 = (f32x4)(0.f);
    const f32x4 zero = (f32x4)(0.f);

    ushort* Pw = PlS + wave * 16 * PSTR;

    for (int kt = sp * SCHUNK; kt < (sp + 1) * SCHUNK; kt += KT) {
        // ---- stage K tile hi/lo: 64 rows x 32 cols, 8B per thread x 2 ----
#pragma unroll
        for (int i = 0; i < 2; ++i) {
            const int p = i * 256 + tid;       // 0..511
            const int row = p >> 3;            // 0..63
            const int col4 = (p & 7) * 4;      // 0..28
            const uint2 h8 = *(const uint2*)(khp + (size_t)(kt + row) * DKK + col4);
            const uint2 l8 = *(const uint2*)(klp + (size_t)(kt + row) * DKK + col4);
            *(uint2*)&KhS[row * KSTR + col4] = h8;
            *(uint2*)&KlS[row * KSTR + col4] = l8;
        }
        // ---- stage V^T tile: 32 dv x 64 s ----
#pragma unroll
        for (int i = 0; i < 2; ++i) {
            const int p = i * 256 + tid;       // 0..511
            const int dv = p >> 4;             // 0..31
            const int s8 = (p & 15) * 4;       // 0..60
            const uint2 v8 = *(const uint2*)(vtp + (size_t)dv * SS + kt + s8);
            *(uint2*)&VtS[dv * VSTR + s8] = v8;
        }
        __syncthreads();

        // ---- QK^T: 16 queries x 64 keys ----
        f32x4 sc[4];
#pragma unroll
        for (int t = 0; t < 4; ++t) {
            const short8 khf = *(const short8*)&KhS[(t * 16 + c16) * KSTR + g * 8];
            const short8 klf = *(const short8*)&KlS[(t * 16 + c16) * KSTR + g * 8];
            f32x4 s = __builtin_amdgcn_mfma_f32_16x16x32_bf16(qlo, khf, zero, 0, 0, 0);
            s = __builtin_amdgcn_mfma_f32_16x16x32_bf16(qhi, klf, s, 0, 0, 0);
            s = __builtin_amdgcn_mfma_f32_16x16x32_bf16(qhi, khf, s, 0, 0, 0);
            sc[t] = s;
        }

        // ---- online softmax ----
#pragma unroll
        for (int r = 0; r < 4; ++r) {
            float tm = sc[0][r];
#pragma unroll
            for (int t = 1; t < 4; ++t) tm = fmaxf(tm, sc[t][r]);
            tm = fmaxf(tm, __shfl_xor(tm, 1));
            tm = fmaxf(tm, __shfl_xor(tm, 2));
            tm = fmaxf(tm, __shfl_xor(tm, 4));
            tm = fmaxf(tm, __shfl_xor(tm, 8));
            const float nm = fmaxf(m_r[r], tm);
            const float scale = __expf(m_r[r] - nm);
            m_r[r] = nm;
            float psum = 0.f;
#pragma unroll
            for (int t = 0; t < 4; ++t) {
                const float p = __expf(sc[t][r] - nm);
                sc[t][r] = p;
                psum += p;
            }
            psum += __shfl_xor(psum, 1);
            psum += __shfl_xor(psum, 2);
            psum += __shfl_xor(psum, 4);
            psum += __shfl_xor(psum, 8);
            l_r[r] = l_r[r] * scale + psum;
            oacc0[r] *= scale;
            oacc1[r] *= scale;
        }

        // ---- P to per-wave LDS in A layout ----
#pragma unroll
        for (int t = 0; t < 4; ++t)
#pragma unroll
            for (int r = 0; r < 4; ++r)
                Pw[(g * 4 + r) * PSTR + t * 16 + c16] = f2bf(sc[t][r]);

        // ---- PV: 2 s-slices x 2 dv-halves ----
#pragma unroll
        for (int s4 = 0; s4 < 2; ++s4) {
            const short8 pfrag  = *(const short8*)&Pw[c16 * PSTR + s4 * 32 + g * 8];
            const short8 vfrag0 = *(const short8*)&VtS[c16 * VSTR + s4 * 32 + g * 8];
            const short8 vfrag1 = *(const short8*)&VtS[(16 + c16) * VSTR + s4 * 32 + g * 8];
            oacc0 = __builtin_amdgcn_mfma_f32_16x16x32_bf16(pfrag, vfrag0, oacc0, 0, 0, 0);
            oacc1 = __builtin_amdgcn_mfma_f32_16x16x32_bf16(pfrag, vfrag1, oacc1, 0, 0, 0);
        }
        __syncthreads();
    }

    // epilogue: unnormalized partials + (m,l) per q-row
    const size_t pbase = (size_t)(sp * BB * HH + bh) * SS;
#pragma unroll
    for (int r = 0; r < 4; ++r) {
        const int qrow = qbase + g * 4 + r;
        float* op = opart + (pbase + qrow) * DVV;
        op[c16]      = oacc0[r];
        op[16 + c16] = oacc1[r];
        if (c16 == 0) {
            ml[(pbase + qrow) * 2]     = m_r[r];
            ml[(pbase + qrow) * 2 + 1] = l_r[r];
        }
    }
}

// ---------------- Kernel 2b: split-K merge -> o in concat layout ----------------
__global__ __launch_bounds__(256) void attn_merge_kernel(
    const float* __restrict__ opart, const float* __restrict__ ml,
    float* __restrict__ o)
{
    const int nch = SS / 128;                // 16
    const int bh = blockIdx.x / nch;
    const int chunk = blockIdx.x % nch;
    const int q0 = chunk * 128;
    const int b = bh >> 3, h = bh & 7;
    const int tid = threadIdx.x;

#pragma unroll
    for (int i = 0; i < 16; ++i) {
        const int p = i * 256 + tid;
        const int ql = p >> 5, dv = p & 31;
        const int qr = q0 + ql;
        float ms[NSPLIT], ls[NSPLIT];
#pragma unroll
        for (int s = 0; s < NSPLIT; ++s) {
            const size_t pb = (size_t)(s * BB * HH + bh) * SS + qr;
            ms[s] = ml[pb * 2];
            ls[s] = ml[pb * 2 + 1];
        }
        float M = ms[0];
#pragma unroll
        for (int s = 1; s < NSPLIT; ++s) M = fmaxf(M, ms[s]);
        float L = 0.f, acc = 0.f;
#pragma unroll
        for (int s = 0; s < NSPLIT; ++s) {
            const float w = __expf(ms[s] - M);
            L += w * ls[s];
            acc += w * opart[((size_t)(s * BB * HH + bh) * SS + qr) * DVV + dv];
        }
        o[(size_t)(b * SS + qr) * (HH * DVV) + h * DVV + dv] = acc / L;
    }
}

// ---------------- Kernel 3: proj via MFMA (proven) ----------------
__global__ __launch_bounds__(256) void proj_mfma_kernel(
    const float* __restrict__ conc, const float* __restrict__ xres,
    const ushort* __restrict__ wth, const ushort* __restrict__ wtl,
    const float* __restrict__ gamma, const float* __restrict__ beta,
    float* __restrict__ xout)
{
    __shared__ __align__(16) ushort Xh[16 * XSTR];
    __shared__ __align__(16) ushort Xl[16 * XSTR];
    __shared__ float Y[16 * YSTR];

    const int tid = threadIdx.x, wave = tid >> 6, lane = tid & 63;
    const int c16 = lane & 15, g = lane >> 4;
    const int row0 = blockIdx.x * 16;

#pragma unroll
    for (int i = 0; i < 16; ++i) {
        const int p = i * 256 + tid;
        const int r = p >> 8, c = p & 255;
        const float f = conc[(size_t)(row0 + r) * DD + c];
        const ushort h = f2bf(f);
        Xh[r * XSTR + c] = h;
        Xl[r * XSTR + c] = f2bf(f - bf2f(h));
    }
    __syncthreads();

    short8 xf_h[8], xf_l[8];
#pragma unroll
    for (int kk = 0; kk < 8; ++kk) {
        xf_h[kk] = *(const short8*)&Xh[c16 * XSTR + kk * 32 + g * 8];
        xf_l[kk] = *(const short8*)&Xl[c16 * XSTR + kk * 32 + g * 8];
    }

    const int wbase = wave * 64;
#pragma unroll 2
    for (int t = 0; t < 4; ++t) {
        const int ncol = wbase + t * 16 + c16;
        const ushort* wh = wth + (size_t)ncol * DD;
        const ushort* wl = wtl + (size_t)ncol * DD;
        f32x4 acc = (f32x4)(0.f);
#pragma unroll
        for (int kk = 0; kk < 8; ++kk) {
            const short8 bh = *(const short8*)(wh + kk * 32 + g * 8);
            const short8 bl = *(const short8*)(wl + kk * 32 + g * 8);
            acc = __builtin_amdgcn_mfma_f32_16x16x32_bf16(xf_h[kk], bh, acc, 0, 0, 0);
            acc = __builtin_amdgcn_mfma_f32_16x16x32_bf16(xf_l[kk], bh, acc, 0, 0, 0);
            acc = __builtin_amdgcn_mfma_f32_16x16x32_bf16(xf_h[kk], bl, acc, 0, 0, 0);
        }
#pragma unroll
        for (int r = 0; r < 4; ++r)
            Y[(4 * g + r) * YSTR + ncol] = acc[r];
    }
    __syncthreads();

    const float g0 = gamma[0], b0 = beta[0];
#pragma unroll
    for (int rr = 0; rr < 4; ++rr) {
        const int row = wave * 4 + rr;
        float v[4];
        float sum = 0.f;
#pragma unroll
        for (int j = 0; j < 4; ++j) {
            const int c = lane + 64 * j;
            v[j] = Y[row * YSTR + c] + xres[(size_t)(row0 + row) * DD + c];
            sum += v[j];
        }
#pragma unroll
        for (int m = 32; m >= 1; m >>= 1) sum += __shfl_xor(sum, m);
        const float mean = sum * (1.0f / DD);
        float var = 0.f;
#pragma unroll
        for (int j = 0; j < 4; ++j) { v[j] -= mean; var += v[j] * v[j]; }
#pragma unroll
        for (int m = 32; m >= 1; m >>= 1) var += __shfl_xor(var, m);
        var *= (1.0f / DD);
        const float rstd = 1.0f / sqrtf(var + ln_eps2());
#pragma unroll
        for (int j = 0; j < 4; ++j)
            xout[(size_t)(row0 + row) * DD + lane + 64 * j] = v[j] * rstd * g0 + b0;
    }
}

// ---------------- Kernel 4: FFN via MFMA + residual + LN (proven) ----------------
__global__ __launch_bounds__(256) void ffn_mfma_kernel(
    const float* __restrict__ xin,
    const ushort* __restrict__ w1th, const ushort* __restrict__ w1tl,
    const ushort* __restrict__ w2th, const ushort* __restrict__ w2tl,
    const float* __restrict__ b1, const float* __restrict__ b2,
    const float* __restrict__ gamma, const float* __restrict__ beta,
    float* __restrict__ xout)
{
    __shared__ __align__(16) char smem[(2 * 16 * XSTR + 2 * 16 * HSTR) * 2];
    ushort* Xh = (ushort*)smem;
    ushort* Xl = Xh + 16 * XSTR;
    ushort* Hh = Xl + 16 * XSTR;
    ushort* Hl = Hh + 16 * HSTR;
    float*  Y  = (float*)smem;

    const int tid  = threadIdx.x;
    const int wave = tid >> 6;
    const int lane = tid & 63;
    const int c16  = lane & 15;
    const int g    = lane >> 4;
    const int row0 = blockIdx.x * 16;

#pragma unroll
    for (int i = 0; i < 16; ++i) {
        const int p = i * 256 + tid;
        const int r = p >> 8, c = p & 255;
        const float f = xin[(size_t)(row0 + r) * DD + c];
        const ushort h = f2bf(f);
        Xh[r * XSTR + c] = h;
        Xl[r * XSTR + c] = f2bf(f - bf2f(h));
    }
    __syncthreads();

    short8 xf_h[8], xf_l[8];
#pragma unroll
    for (int kk = 0; kk < 8; ++kk) {
        xf_h[kk] = *(const short8*)&Xh[c16 * XSTR + kk * 32 + g * 8];
        xf_l[kk] = *(const short8*)&Xl[c16 * XSTR + kk * 32 + g * 8];
    }

    const int wbase = wave * 128;
#pragma unroll 2
    for (int t = 0; t < 8; ++t) {
        const int ncol = wbase + t * 16 + c16;
        const ushort* wh = w1th + (size_t)ncol * DD;
        const ushort* wl = w1tl + (size_t)ncol * DD;
        f32x4 acc = (f32x4)(0.f);
#pragma unroll
        for (int kk = 0; kk < 8; ++kk) {
            const short8 bh = *(const short8*)(wh + kk * 32 + g * 8);
            const short8 bl = *(const short8*)(wl + kk * 32 + g * 8);
            acc = __builtin_amdgcn_mfma_f32_16x16x32_bf16(xf_h[kk], bh, acc, 0, 0, 0);
            acc = __builtin_amdgcn_mfma_f32_16x16x32_bf16(xf_l[kk], bh, acc, 0, 0, 0);
            acc = __builtin_amdgcn_mfma_f32_16x16x32_bf16(xf_h[kk], bl, acc, 0, 0, 0);
        }
        const float bias = b1[ncol];
#pragma unroll
        for (int r = 0; r < 4; ++r) {
            const int m = 4 * g + r;
            const float hv = fmaxf(acc[r] + bias, 0.f);
            const ushort hh = f2bf(hv);
            Hh[m * HSTR + ncol] = hh;
            Hl[m * HSTR + ncol] = f2bf(hv - bf2f(hh));
        }
    }
    __syncthreads();

    const int obase = wave * 64;
    f32x4 acc2[4];
#pragma unroll
    for (int t = 0; t < 4; ++t) acc2[t] = (f32x4)(0.f);
#pragma unroll 2
    for (int kk = 0; kk < 16; ++kk) {
        const short8 ah = *(const short8*)&Hh[c16 * HSTR + kk * 32 + g * 8];
        const short8 al = *(const short8*)&Hl[c16 * HSTR + kk * 32 + g * 8];
#pragma unroll
        for (int t = 0; t < 4; ++t) {
            const int ncol = obase + t * 16 + c16;
            const short8 bh = *(const short8*)(w2th + (size_t)ncol * DFF + kk * 32 + g * 8);
            const short8 bl = *(const short8*)(w2tl + (size_t)ncol * DFF + kk * 32 + g * 8);
            acc2[t] = __builtin_amdgcn_mfma_f32_16x16x32_bf16(ah, bh, acc2[t], 0, 0, 0);
            acc2[t] = __builtin_amdgcn_mfma_f32_16x16x32_bf16(al, bh, acc2[t], 0, 0, 0);
            acc2[t] = __builtin_amdgcn_mfma_f32_16x16x32_bf16(ah, bl, acc2[t], 0, 0, 0);
        }
    }

#pragma unroll
    for (int t = 0; t < 4; ++t) {
        const int ncol = obase + t * 16 + c16;
#pragma unroll
        for (int r = 0; r < 4; ++r)
            Y[(4 * g + r) * YSTR + ncol] = acc2[t][r];
    }
    __syncthreads();

    const float g0 = gamma[0], b0 = beta[0];
#pragma unroll
    for (int rr = 0; rr < 4; ++rr) {
        const int row = wave * 4 + rr;
        float v[4];
        float sum = 0.f;
#pragma unroll
        for (int j = 0; j < 4; ++j) {
            const int c = lane + 64 * j;
            v[j] = Y[row * YSTR + c] + b2[c] + xin[(size_t)(row0 + row) * DD + c];
            sum += v[j];
        }
#pragma unroll
        for (int m = 32; m >= 1; m >>= 1) sum += __shfl_xor(sum, m);
        const float mean = sum * (1.0f / DD);
        float var = 0.f;
#pragma unroll
        for (int j = 0; j < 4; ++j) { v[j] -= mean; var += v[j] * v[j]; }
#pragma unroll
        for (int m = 32; m >= 1; m >>= 1) var += __shfl_xor(var, m);
        var *= (1.0f / DD);
        const float rstd = 1.0f / sqrtf(var + ln_eps2());
#pragma unroll
        for (int j = 0; j < 4; ++j)
            xout[(size_t)(row0 + row) * DD + lane + 64 * j] = v[j] * rstd * g0 + b0;
    }
}

// ---------------- host launch ----------------
extern "C" void kernel_launch(void* const* d_in, const int* in_sizes, int n_in,
                              void* d_out, int out_size, void* d_ws, size_t ws_size,
                              hipStream_t stream) {
    const float* x     = (const float*)d_in[0];
    const float* Wq    = (const float*)d_in[1];
    const float* Wk    = (const float*)d_in[2];
    const float* Wv    = (const float*)d_in[3];
    const float* Wo    = (const float*)d_in[4];
    const float* W1    = (const float*)d_in[5];
    const float* b1    = (const float*)d_in[6];
    const float* W2    = (const float*)d_in[7];
    const float* b2    = (const float*)d_in[8];
    const float* gamma = (const float*)d_in[9];
    const float* beta  = (const float*)d_in[10];
    float* out = (float*)d_out;

    const size_t NTOK = (size_t)BB * SS * DD;       // 1,048,576
    const size_t WFF  = (size_t)NL * DFF * DD;      // 262,144
    const size_t WOO  = (size_t)NL * DD * DD;       // 131,072
    const size_t WQKV = (size_t)NL * 768 * DD;      // 393,216
    float*  q    = (float*)d_ws;
    ushort* khi  = (ushort*)(q + NTOK);
    ushort* klo  = khi + NTOK;
    ushort* vt   = klo + NTOK;
    float*  o    = (float*)(vt + NTOK);
    float*  xa   = o + NTOK;
    float*  xb   = xa + NTOK;
    ushort* w1th = (ushort*)(xb + NTOK);
    ushort* w1tl = w1th + WFF;
    ushort* w2th = w1tl + WFF;
    ushort* w2tl = w2th + WFF;
    ushort* woth = w2tl + WFF;
    ushort* wotl = woth + WOO;
    ushort* wqth = wotl + WOO;
    ushort* wqtl = wqth + WQKV;
    float*  opart = (float*)(wqtl + WQKV);          // NSPLIT*B*H*S*DVV f32 = 16 MB
    float*  ml    = opart + (size_t)NSPLIT * BB * HH * SS * DVV;  // 1 MB

    wtrans_kernel<<<128, 256, 0, stream>>>(W1, W2, w1th, w1tl, w2th, w2tl);
    wotrans_kernel<<<NL * 16, 256, 0, stream>>>(Wo, woth, wotl);
    wqkv_trans_kernel<<<48, 256, 0, stream>>>(Wq, Wk, Wv, wqth, wqtl);

    const float* cur = x;
    for (int l = 0; l < NL; ++l) {
        qkv_mfma_kernel<<<2 * BB * SS / 16, 256, 0, stream>>>(
            cur, wqth + (size_t)l * 768 * DD, wqtl + (size_t)l * 768 * DD,
            q, khi, klo, vt);
        attn_mfma_kernel<<<BB * HH * (SS / 64) * NSPLIT, 256, 0, stream>>>(
            q, khi, klo, vt, opart, ml);
        attn_merge_kernel<<<BB * HH * (SS / 128), 256, 0, stream>>>(opart, ml, o);
        proj_mfma_kernel<<<BB * SS / 16, 256, 0, stream>>>(
            o, cur, woth + (size_t)l * DD * DD, wotl + (size_t)l * DD * DD,
            gamma + 2 * l, beta + 2 * l, xa);
        float* nxt = (l == NL - 1) ? out : xb;
        ffn_mfma_kernel<<<BB * SS / 16, 256, 0, stream>>>(
            xa, w1th + (size_t)l * DFF * DD, w1tl + (size_t)l * DFF * DD,
            w2th + (size_t)l * DD * DFF, w2tl + (size_t)l * DD * DFF,
            b1 + (size_t)l * DFF, b2 + (size_t)l * DD,
            gamma + 2 * l + 1, beta + 2 * l + 1, nxt);
        cur = nxt;
    }
}

// Round 18
// 244.314 us; speedup vs baseline: 6.7820x; 1.2250x over previous
//
#include <hip/hip_runtime.h>
#include <math.h>

#define BB 2
#define SS 2048
#define DD 256
#define HH 8
#define DKK 32
#define DVV 32
#define DFF 512
#define NL 2

// attention tiling
#define KSTR 40
#define VSTR 72
#define NSPLIT 4
#define SCHUNK (SS / NSPLIT)   // 512 keys per block

// gemm tiling
#define XSTR 264     // 16-row X tile stride (ushort)
#define HSTR 520     // 16-row H tile stride (ushort)
#define YSTR 260     // Y tile stride (float)

typedef __attribute__((ext_vector_type(8))) short short8;
typedef __attribute__((ext_vector_type(4))) float f32x4;
typedef __attribute__((ext_vector_type(16))) float f32x16;

static __device__ __forceinline__ float ln_eps2() { return 1.4210854715202004e-14f; }

static __device__ __forceinline__ ushort f2bf(float f) {
    union { float f; unsigned u; } c; c.f = f;
    unsigned r = c.u + 0x7FFFu + ((c.u >> 16) & 1u);   // RNE
    return (ushort)(r >> 16);
}
static __device__ __forceinline__ float bf2f(ushort h) {
    union { unsigned u; float f; } c; c.u = ((unsigned)h) << 16;
    return c.f;
}
static __device__ __forceinline__ unsigned cvtpk_bf16(float a, float b) {
    unsigned r;
    asm volatile("v_cvt_pk_bf16_f32 %0, %1, %2" : "=v"(r) : "v"(a), "v"(b));
    return r;   // lo = bf16(a), hi = bf16(b)
}

// ---------------- Kernel 0a: W1/W2 convert+transpose (proven) ----------------
__global__ __launch_bounds__(256) void wtrans_kernel(
    const float* __restrict__ W1, const float* __restrict__ W2,
    ushort* __restrict__ w1t_hi, ushort* __restrict__ w1t_lo,
    ushort* __restrict__ w2t_hi, ushort* __restrict__ w2t_lo)
{
    __shared__ ushort Th[64][72];
    __shared__ ushort Tl[64][72];
    const int bid = blockIdx.x;              // 0..127
    const float* src; ushort *dh, *dl; int R, C, tile;
    if (bid < 64) {                          // W1
        const int l = bid >> 5; tile = bid & 31;
        src = W1 + (size_t)l * DD * DFF;
        dh = w1t_hi + (size_t)l * DFF * DD; dl = w1t_lo + (size_t)l * DFF * DD;
        R = DD; C = DFF;
    } else {                                 // W2
        const int l = (bid - 64) >> 5; tile = (bid - 64) & 31;
        src = W2 + (size_t)l * DFF * DD;
        dh = w2t_hi + (size_t)l * DD * DFF; dl = w2t_lo + (size_t)l * DD * DFF;
        R = DFF; C = DD;
    }
    const int tilesC = C / 64;
    const int br = (tile / tilesC) * 64, bc = (tile % tilesC) * 64;
    const int tid = threadIdx.x;
#pragma unroll
    for (int i = 0; i < 16; ++i) {
        const int p = i * 256 + tid;
        const int r = p >> 6, c = p & 63;
        const float f = src[(size_t)(br + r) * C + bc + c];
        const ushort h = f2bf(f);
        Th[c][r] = h; Tl[c][r] = f2bf(f - bf2f(h));
    }
    __syncthreads();
#pragma unroll
    for (int i = 0; i < 16; ++i) {
        const int p = i * 256 + tid;
        const int r = p >> 6, c = p & 63;
        dh[(size_t)(bc + r) * R + br + c] = Th[r][c];
        dl[(size_t)(bc + r) * R + br + c] = Tl[r][c];
    }
}

// ---------------- Kernel 0b: Wo -> woT hi/lo [l][256][256] (proven) ----------------
__global__ __launch_bounds__(256) void wotrans_kernel(
    const float* __restrict__ Wo,
    ushort* __restrict__ wh, ushort* __restrict__ wl)
{
    __shared__ float T[64][65];
    const int l = blockIdx.x >> 4, tile = blockIdx.x & 15;
    const int tr = (tile >> 2) * 64;
    const int tc = (tile & 3) * 64;
    const float* src = Wo + (size_t)l * DD * DD;
    ushort* dh = wh + (size_t)l * DD * DD;
    ushort* dl = wl + (size_t)l * DD * DD;
    const int tid = threadIdx.x;
#pragma unroll
    for (int i = 0; i < 16; ++i) {
        const int p = i * 256 + tid;
        const int r = p >> 6, c = p & 63;
        T[r][c] = src[(size_t)(tr + r) * DD + tc + c];
    }
    __syncthreads();
#pragma unroll
    for (int i = 0; i < 16; ++i) {
        const int p = i * 256 + tid;
        const int r = p >> 6, c = p & 63;
        const float f = T[c][r];
        const size_t off = (size_t)(tc + r) * DD + tr + c;
        const ushort h = f2bf(f);
        dh[off] = h;
        dl[off] = f2bf(f - bf2f(h));
    }
}

// ---------------- Kernel 0c: Wq/Wk/Wv -> wqkvT hi/lo [l][768][256] (proven) ----------------
__global__ __launch_bounds__(256) void wqkv_trans_kernel(
    const float* __restrict__ Wq, const float* __restrict__ Wk,
    const float* __restrict__ Wv,
    ushort* __restrict__ qkvT_hi, ushort* __restrict__ qkvT_lo)
{
    __shared__ float T[DKK][DD + 1];
    const int bid = blockIdx.x;              // l*24 + src*8 + h
    const int l = bid / 24, rem = bid % 24, src = rem >> 3, h = rem & 7;
    const float* W = (src == 0 ? Wq : src == 1 ? Wk : Wv)
                     + ((size_t)l * HH + h) * DD * DKK;
    ushort* dh = qkvT_hi + ((size_t)l * 768 + src * 256 + h * 32) * DD;
    ushort* dl = qkvT_lo + ((size_t)l * 768 + src * 256 + h * 32) * DD;
    const int tid = threadIdx.x;
#pragma unroll
    for (int i = 0; i < 32; ++i) {           // W[d][dk] -> T[dk][d]
        const int p = i * 256 + tid;
        T[p & 31][p >> 5] = W[p];
    }
    __syncthreads();
#pragma unroll
    for (int i = 0; i < 32; ++i) {
        const int p = i * 256 + tid;
        const int dk = p >> 8, d = p & 255;
        const float f = T[dk][d];
        const ushort hh = f2bf(f);
        dh[dk * DD + d] = hh;
        dl[dk * DD + d] = f2bf(f - bf2f(hh));
    }
}

// ---------------- Kernel 1: QKV via MFMA, 2-way column split (proven) ----------------
__global__ __launch_bounds__(256) void qkv_mfma_kernel(
    const float* __restrict__ xin,
    const ushort* __restrict__ wth, const ushort* __restrict__ wtl,
    float* __restrict__ q, ushort* __restrict__ khi, ushort* __restrict__ klo,
    ushort* __restrict__ vt)
{
    __shared__ __align__(16) ushort Xh[16 * XSTR];
    __shared__ __align__(16) ushort Xl[16 * XSTR];

    const int tid = threadIdx.x, wave = tid >> 6, lane = tid & 63;
    const int c16 = lane & 15, g = lane >> 4;
    const int row0 = (blockIdx.x >> 1) * 16;
    const int half = blockIdx.x & 1;

#pragma unroll
    for (int i = 0; i < 16; ++i) {
        const int p = i * 256 + tid;
        const int r = p >> 8, c = p & 255;
        const float f = xin[(size_t)(row0 + r) * DD + c];
        const ushort h = f2bf(f);
        Xh[r * XSTR + c] = h;
        Xl[r * XSTR + c] = f2bf(f - bf2f(h));
    }
    __syncthreads();

    short8 xf_h[8], xf_l[8];
#pragma unroll
    for (int kk = 0; kk < 8; ++kk) {
        xf_h[kk] = *(const short8*)&Xh[c16 * XSTR + kk * 32 + g * 8];
        xf_l[kk] = *(const short8*)&Xl[c16 * XSTR + kk * 32 + g * 8];
    }

    const int b = row0 / SS, s0 = row0 % SS;
    const int wbase = half * 384 + wave * 96;
#pragma unroll 2
    for (int t = 0; t < 6; ++t) {
        const int ncol = wbase + t * 16 + c16;
        const ushort* wh = wth + (size_t)ncol * DD;
        const ushort* wl = wtl + (size_t)ncol * DD;
        f32x4 acc = (f32x4)(0.f);
#pragma unroll
        for (int kk = 0; kk < 8; ++kk) {
            const short8 bh = *(const short8*)(wh + kk * 32 + g * 8);
            const short8 bl = *(const short8*)(wl + kk * 32 + g * 8);
            acc = __builtin_amdgcn_mfma_f32_16x16x32_bf16(xf_h[kk], bh, acc, 0, 0, 0);
            acc = __builtin_amdgcn_mfma_f32_16x16x32_bf16(xf_l[kk], bh, acc, 0, 0, 0);
            acc = __builtin_amdgcn_mfma_f32_16x16x32_bf16(xf_h[kk], bl, acc, 0, 0, 0);
        }
        const int src = ncol >> 8, h = (ncol >> 5) & 7, dk = ncol & 31;
        const size_t base = ((size_t)(b * HH + h) * SS + s0) * DKK + dk;
#pragma unroll
        for (int r = 0; r < 4; ++r) {
            if (src == 0) {
                q[base + (size_t)(4 * g + r) * DKK] = acc[r];
            } else if (src == 1) {
                const size_t off = base + (size_t)(4 * g + r) * DKK;
                const ushort hh = f2bf(acc[r]);
                khi[off] = hh;
                klo[off] = f2bf(acc[r] - bf2f(hh));
            } else {
                vt[((size_t)(b * HH + h) * DVV + dk) * SS + s0 + 4 * g + r] = f2bf(acc[r]);
            }
        }
    }
}

// ---------------- Kernel 2: swapped-operand 32x32 flash attention, split-K ----------------
// grid = B*H*(S/128)*NSPLIT; 4 waves x 32 queries each; 64-key tiles.
// S^T = mfma(K, Q): col = lane&31 = query (one query per thread);
// softmax reductions in-register + one shfl_xor(32); P packed via v_cvt_pk_bf16_f32,
// half-key exchange via 4 pre-selected shfl_xor(32); O^T = mfma(V^T, P).
__global__ __launch_bounds__(256) void attn_mfma_kernel(
    const float* __restrict__ q, const ushort* __restrict__ khi,
    const ushort* __restrict__ klo, const ushort* __restrict__ vt,
    float* __restrict__ opart, float* __restrict__ ml)
{
    __shared__ ushort KhS[64 * KSTR];        // 5120 B
    __shared__ ushort KlS[64 * KSTR];        // 5120 B
    __shared__ ushort VtS[32 * VSTR];        // 4608 B

    const int tid  = threadIdx.x;
    const int wave = tid >> 6;
    const int lane = tid & 63;
    const int c32  = lane & 31;
    const int hi   = lane >> 5;

    const int nqb = SS / 128;                // 16
    const int bh  = blockIdx.x / (nqb * NSPLIT);
    const int rem = blockIdx.x % (nqb * NSPLIT);
    const int qb  = rem / NSPLIT;
    const int sp  = rem % NSPLIT;
    const int qrow = qb * 128 + wave * 32 + c32;

    const float*  qp  = q   + (size_t)bh * SS * DKK;
    const ushort* khp = khi + (size_t)bh * SS * DKK;
    const ushort* klp = klo + (size_t)bh * SS * DKK;
    const ushort* vtp = vt  + (size_t)bh * DVV * SS;

    // Q as B-operand: chunk c holds Q[qrow][c*16 + hi*8 + j], hi/lo split
    short8 qh0, ql0, qh1, ql1;
    {
        const float* qr = qp + (size_t)qrow * DKK + hi * 8;
#pragma unroll
        for (int j = 0; j < 8; ++j) {
            const ushort h = f2bf(qr[j]);
            qh0[j] = (short)h; ql0[j] = (short)f2bf(qr[j] - bf2f(h));
        }
#pragma unroll
        for (int j = 0; j < 8; ++j) {
            const float f = qr[16 + j];
            const ushort h = f2bf(f);
            qh1[j] = (short)h; ql1[j] = (short)f2bf(f - bf2f(h));
        }
    }

    float m = -1e30f, l = 0.f;
    f32x16 oacc = (f32x16)(0.f);
    const f32x16 zero16 = (f32x16)(0.f);

    for (int kt = sp * SCHUNK; kt < (sp + 1) * SCHUNK; kt += 64) {
        // ---- stage K tile hi/lo (64 x 32) and V^T (32 x 64): pure 8B copies ----
#pragma unroll
        for (int i = 0; i < 2; ++i) {
            const int p = i * 256 + tid;       // 0..511
            const int row = p >> 3;            // 0..63
            const int col4 = (p & 7) * 4;      // 0..28
            const uint2 h8 = *(const uint2*)(khp + (size_t)(kt + row) * DKK + col4);
            const uint2 l8 = *(const uint2*)(klp + (size_t)(kt + row) * DKK + col4);
            *(uint2*)&KhS[row * KSTR + col4] = h8;
            *(uint2*)&KlS[row * KSTR + col4] = l8;
        }
#pragma unroll
        for (int i = 0; i < 2; ++i) {
            const int p = i * 256 + tid;       // 0..511
            const int dv = p >> 4;             // 0..31
            const int s8 = (p & 15) * 4;       // 0..60
            const uint2 v8 = *(const uint2*)(vtp + (size_t)dv * SS + kt + s8);
            *(uint2*)&VtS[dv * VSTR + s8] = v8;
        }
        __syncthreads();

        // ---- QK^T swapped: S^T[key][q], 2 key-subtiles of 32 ----
        f32x16 s0, s1;
        {
            const int rb0 = c32 * KSTR + hi * 8;
            const short8 kh0 = *(const short8*)&KhS[rb0];
            const short8 kl0 = *(const short8*)&KlS[rb0];
            const short8 kh1 = *(const short8*)&KhS[rb0 + 16];
            const short8 kl1 = *(const short8*)&KlS[rb0 + 16];
            f32x16 s = __builtin_amdgcn_mfma_f32_32x32x16_bf16(kh0, ql0, zero16, 0, 0, 0);
            s = __builtin_amdgcn_mfma_f32_32x32x16_bf16(kl0, qh0, s, 0, 0, 0);
            s = __builtin_amdgcn_mfma_f32_32x32x16_bf16(kh0, qh0, s, 0, 0, 0);
            s = __builtin_amdgcn_mfma_f32_32x32x16_bf16(kh1, ql1, s, 0, 0, 0);
            s = __builtin_amdgcn_mfma_f32_32x32x16_bf16(kl1, qh1, s, 0, 0, 0);
            s0 = __builtin_amdgcn_mfma_f32_32x32x16_bf16(kh1, qh1, s, 0, 0, 0);
        }
        {
            const int rb1 = (32 + c32) * KSTR + hi * 8;
            const short8 kh0 = *(const short8*)&KhS[rb1];
            const short8 kl0 = *(const short8*)&KlS[rb1];
            const short8 kh1 = *(const short8*)&KhS[rb1 + 16];
            const short8 kl1 = *(const short8*)&KlS[rb1 + 16];
            f32x16 s = __builtin_amdgcn_mfma_f32_32x32x16_bf16(kh0, ql0, zero16, 0, 0, 0);
            s = __builtin_amdgcn_mfma_f32_32x32x16_bf16(kl0, qh0, s, 0, 0, 0);
            s = __builtin_amdgcn_mfma_f32_32x32x16_bf16(kh0, qh0, s, 0, 0, 0);
            s = __builtin_amdgcn_mfma_f32_32x32x16_bf16(kh1, ql1, s, 0, 0, 0);
            s = __builtin_amdgcn_mfma_f32_32x32x16_bf16(kl1, qh1, s, 0, 0, 0);
            s1 = __builtin_amdgcn_mfma_f32_32x32x16_bf16(kh1, qh1, s, 0, 0, 0);
        }

        // ---- online softmax: one query per thread (col=c32) ----
        float tm = s0[0];
#pragma unroll
        for (int j = 1; j < 16; ++j) tm = fmaxf(tm, s0[j]);
#pragma unroll
        for (int j = 0; j < 16; ++j) tm = fmaxf(tm, s1[j]);
        tm = fmaxf(tm, __shfl_xor(tm, 32));
        const float nm = fmaxf(m, tm);
        const float scale = __expf(m - nm);
        m = nm;
        float psum = 0.f;
#pragma unroll
        for (int j = 0; j < 16; ++j) { const float p = __expf(s0[j] - nm); s0[j] = p; psum += p; }
#pragma unroll
        for (int j = 0; j < 16; ++j) { const float p = __expf(s1[j] - nm); s1[j] = p; psum += p; }
        psum += __shfl_xor(psum, 32);
        l = l * scale + psum;
#pragma unroll
        for (int j = 0; j < 16; ++j) oacc[j] *= scale;

        // ---- pack P to bf16 + half-key exchange; build PV B-operands in regs ----
        unsigned w0 = cvtpk_bf16(s0[0],  s0[1]);
        unsigned w1 = cvtpk_bf16(s0[2],  s0[3]);
        unsigned w2 = cvtpk_bf16(s0[4],  s0[5]);
        unsigned w3 = cvtpk_bf16(s0[6],  s0[7]);
        unsigned w4 = cvtpk_bf16(s0[8],  s0[9]);
        unsigned w5 = cvtpk_bf16(s0[10], s0[11]);
        unsigned w6 = cvtpk_bf16(s0[12], s0[13]);
        unsigned w7 = cvtpk_bf16(s0[14], s0[15]);
        unsigned u0 = cvtpk_bf16(s1[0],  s1[1]);
        unsigned u1 = cvtpk_bf16(s1[2],  s1[3]);
        unsigned u2 = cvtpk_bf16(s1[4],  s1[5]);
        unsigned u3 = cvtpk_bf16(s1[6],  s1[7]);
        unsigned u4 = cvtpk_bf16(s1[8],  s1[9]);
        unsigned u5 = cvtpk_bf16(s1[10], s1[11]);
        unsigned u6 = cvtpk_bf16(s1[12], s1[13]);
        unsigned u7 = cvtpk_bf16(s1[14], s1[15]);

        const unsigned x0 = __shfl_xor(hi ? w0 : w2, 32);
        const unsigned x1 = __shfl_xor(hi ? w1 : w3, 32);
        const unsigned x2 = __shfl_xor(hi ? w4 : w6, 32);
        const unsigned x3 = __shfl_xor(hi ? w5 : w7, 32);
        const unsigned y0 = __shfl_xor(hi ? u0 : u2, 32);
        const unsigned y1 = __shfl_xor(hi ? u1 : u3, 32);
        const unsigned y2 = __shfl_xor(hi ? u4 : u6, 32);
        const unsigned y3 = __shfl_xor(hi ? u5 : u7, 32);

        union { unsigned u[4]; short8 s8; } pa, pb, pc, pd;
        if (hi == 0) {
            pa.u[0] = w0; pa.u[1] = w1; pa.u[2] = x0; pa.u[3] = x1;   // keys 0..7
            pb.u[0] = w4; pb.u[1] = w5; pb.u[2] = x2; pb.u[3] = x3;   // keys 16..23
            pc.u[0] = u0; pc.u[1] = u1; pc.u[2] = y0; pc.u[3] = y1;   // keys 32..39
            pd.u[0] = u4; pd.u[1] = u5; pd.u[2] = y2; pd.u[3] = y3;   // keys 48..55
        } else {
            pa.u[0] = x0; pa.u[1] = x1; pa.u[2] = w2; pa.u[3] = w3;   // keys 8..15
            pb.u[0] = x2; pb.u[1] = x3; pb.u[2] = w6; pb.u[3] = w7;   // keys 24..31
            pc.u[0] = y0; pc.u[1] = y1; pc.u[2] = u2; pc.u[3] = u3;   // keys 40..47
            pd.u[0] = y2; pd.u[1] = y3; pd.u[2] = u6; pd.u[3] = u7;   // keys 56..63
        }

        // ---- PV: O^T[dv][q] += V^T-chunks x P-chunks (4 x k=16) ----
        {
            const int vb = c32 * VSTR + hi * 8;
            const short8 v0 = *(const short8*)&VtS[vb];
            const short8 v1 = *(const short8*)&VtS[vb + 16];
            const short8 v2 = *(const short8*)&VtS[vb + 32];
            const short8 v3 = *(const short8*)&VtS[vb + 48];
            oacc = __builtin_amdgcn_mfma_f32_32x32x16_bf16(v0, pa.s8, oacc, 0, 0, 0);
            oacc = __builtin_amdgcn_mfma_f32_32x32x16_bf16(v1, pb.s8, oacc, 0, 0, 0);
            oacc = __builtin_amdgcn_mfma_f32_32x32x16_bf16(v2, pc.s8, oacc, 0, 0, 0);
            oacc = __builtin_amdgcn_mfma_f32_32x32x16_bf16(v3, pd.s8, oacc, 0, 0, 0);
        }
        __syncthreads();
    }

    // ---- epilogue: unnormalized partials + (m,l); dv rows = (r&3)+8*(r>>2)+4*hi ----
    const size_t pbase = (size_t)(sp * BB * HH + bh) * SS;
    float* op = opart + (pbase + qrow) * DVV;
#pragma unroll
    for (int q4 = 0; q4 < 4; ++q4) {
        f32x4 v;
        v[0] = oacc[4 * q4 + 0]; v[1] = oacc[4 * q4 + 1];
        v[2] = oacc[4 * q4 + 2]; v[3] = oacc[4 * q4 + 3];
        *(f32x4*)(op + 8 * q4 + 4 * hi) = v;
    }
    if (hi == 0) {
        ml[(pbase + qrow) * 2]     = m;
        ml[(pbase + qrow) * 2 + 1] = l;
    }
}

// ---------------- Kernel 2b: split-K merge -> o in concat layout (proven) ----------------
__global__ __launch_bounds__(256) void attn_merge_kernel(
    const float* __restrict__ opart, const float* __restrict__ ml,
    float* __restrict__ o)
{
    const int nch = SS / 128;                // 16
    const int bh = blockIdx.x / nch;
    const int chunk = blockIdx.x % nch;
    const int q0 = chunk * 128;
    const int b = bh >> 3, h = bh & 7;
    const int tid = threadIdx.x;

#pragma unroll
    for (int i = 0; i < 16; ++i) {
        const int p = i * 256 + tid;
        const int ql = p >> 5, dv = p & 31;
        const int qr = q0 + ql;
        float ms[NSPLIT], ls[NSPLIT];
#pragma unroll
        for (int s = 0; s < NSPLIT; ++s) {
            const size_t pb = (size_t)(s * BB * HH + bh) * SS + qr;
            ms[s] = ml[pb * 2];
            ls[s] = ml[pb * 2 + 1];
        }
        float M = ms[0];
#pragma unroll
        for (int s = 1; s < NSPLIT; ++s) M = fmaxf(M, ms[s]);
        float L = 0.f, acc = 0.f;
#pragma unroll
        for (int s = 0; s < NSPLIT; ++s) {
            const float w = __expf(ms[s] - M);
            L += w * ls[s];
            acc += w * opart[((size_t)(s * BB * HH + bh) * SS + qr) * DVV + dv];
        }
        o[(size_t)(b * SS + qr) * (HH * DVV) + h * DVV + dv] = acc / L;
    }
}

// ---------------- Kernel 3: proj via MFMA (proven) ----------------
__global__ __launch_bounds__(256) void proj_mfma_kernel(
    const float* __restrict__ conc, const float* __restrict__ xres,
    const ushort* __restrict__ wth, const ushort* __restrict__ wtl,
    const float* __restrict__ gamma, const float* __restrict__ beta,
    float* __restrict__ xout)
{
    __shared__ __align__(16) ushort Xh[16 * XSTR];
    __shared__ __align__(16) ushort Xl[16 * XSTR];
    __shared__ float Y[16 * YSTR];

    const int tid = threadIdx.x, wave = tid >> 6, lane = tid & 63;
    const int c16 = lane & 15, g = lane >> 4;
    const int row0 = blockIdx.x * 16;

#pragma unroll
    for (int i = 0; i < 16; ++i) {
        const int p = i * 256 + tid;
        const int r = p >> 8, c = p & 255;
        const float f = conc[(size_t)(row0 + r) * DD + c];
        const ushort h = f2bf(f);
        Xh[r * XSTR + c] = h;
        Xl[r * XSTR + c] = f2bf(f - bf2f(h));
    }
    __syncthreads();

    short8 xf_h[8], xf_l[8];
#pragma unroll
    for (int kk = 0; kk < 8; ++kk) {
        xf_h[kk] = *(const short8*)&Xh[c16 * XSTR + kk * 32 + g * 8];
        xf_l[kk] = *(const short8*)&Xl[c16 * XSTR + kk * 32 + g * 8];
    }

    const int wbase = wave * 64;
#pragma unroll 2
    for (int t = 0; t < 4; ++t) {
        const int ncol = wbase + t * 16 + c16;
        const ushort* wh = wth + (size_t)ncol * DD;
        const ushort* wl = wtl + (size_t)ncol * DD;
        f32x4 acc = (f32x4)(0.f);
#pragma unroll
        for (int kk = 0; kk < 8; ++kk) {
            const short8 bh = *(const short8*)(wh + kk * 32 + g * 8);
            const short8 bl = *(const short8*)(wl + kk * 32 + g * 8);
            acc = __builtin_amdgcn_mfma_f32_16x16x32_bf16(xf_h[kk], bh, acc, 0, 0, 0);
            acc = __builtin_amdgcn_mfma_f32_16x16x32_bf16(xf_l[kk], bh, acc, 0, 0, 0);
            acc = __builtin_amdgcn_mfma_f32_16x16x32_bf16(xf_h[kk], bl, acc, 0, 0, 0);
        }
#pragma unroll
        for (int r = 0; r < 4; ++r)
            Y[(4 * g + r) * YSTR + ncol] = acc[r];
    }
    __syncthreads();

    const float g0 = gamma[0], b0 = beta[0];
#pragma unroll
    for (int rr = 0; rr < 4; ++rr) {
        const int row = wave * 4 + rr;
        float v[4];
        float sum = 0.f;
#pragma unroll
        for (int j = 0; j < 4; ++j) {
            const int c = lane + 64 * j;
            v[j] = Y[row * YSTR + c] + xres[(size_t)(row0 + row) * DD + c];
            sum += v[j];
        }
#pragma unroll
        for (int m = 32; m >= 1; m >>= 1) sum += __shfl_xor(sum, m);
        const float mean = sum * (1.0f / DD);
        float var = 0.f;
#pragma unroll
        for (int j = 0; j < 4; ++j) { v[j] -= mean; var += v[j] * v[j]; }
#pragma unroll
        for (int m = 32; m >= 1; m >>= 1) var += __shfl_xor(var, m);
        var *= (1.0f / DD);
        const float rstd = 1.0f / sqrtf(var + ln_eps2());
#pragma unroll
        for (int j = 0; j < 4; ++j)
            xout[(size_t)(row0 + row) * DD + lane + 64 * j] = v[j] * rstd * g0 + b0;
    }
}

// ---------------- Kernel 4: FFN via MFMA + residual + LN (proven) ----------------
__global__ __launch_bounds__(256) void ffn_mfma_kernel(
    const float* __restrict__ xin,
    const ushort* __restrict__ w1th, const ushort* __restrict__ w1tl,
    const ushort* __restrict__ w2th, const ushort* __restrict__ w2tl,
    const float* __restrict__ b1, const float* __restrict__ b2,
    const float* __restrict__ gamma, const float* __restrict__ beta,
    float* __restrict__ xout)
{
    __shared__ __align__(16) char smem[(2 * 16 * XSTR + 2 * 16 * HSTR) * 2];
    ushort* Xh = (ushort*)smem;
    ushort* Xl = Xh + 16 * XSTR;
    ushort* Hh = Xl + 16 * XSTR;
    ushort* Hl = Hh + 16 * HSTR;
    float*  Y  = (float*)smem;

    const int tid  = threadIdx.x;
    const int wave = tid >> 6;
    const int lane = tid & 63;
    const int c16  = lane & 15;
    const int g    = lane >> 4;
    const int row0 = blockIdx.x * 16;

#pragma unroll
    for (int i = 0; i < 16; ++i) {
        const int p = i * 256 + tid;
        const int r = p >> 8, c = p & 255;
        const float f = xin[(size_t)(row0 + r) * DD + c];
        const ushort h = f2bf(f);
        Xh[r * XSTR + c] = h;
        Xl[r * XSTR + c] = f2bf(f - bf2f(h));
    }
    __syncthreads();

    short8 xf_h[8], xf_l[8];
#pragma unroll
    for (int kk = 0; kk < 8; ++kk) {
        xf_h[kk] = *(const short8*)&Xh[c16 * XSTR + kk * 32 + g * 8];
        xf_l[kk] = *(const short8*)&Xl[c16 * XSTR + kk * 32 + g * 8];
    }

    const int wbase = wave * 128;
#pragma unroll 2
    for (int t = 0; t < 8; ++t) {
        const int ncol = wbase + t * 16 + c16;
        const ushort* wh = w1th + (size_t)ncol * DD;
        const ushort* wl = w1tl + (size_t)ncol * DD;
        f32x4 acc = (f32x4)(0.f);
#pragma unroll
        for (int kk = 0; kk < 8; ++kk) {
            const short8 bh = *(const short8*)(wh + kk * 32 + g * 8);
            const short8 bl = *(const short8*)(wl + kk * 32 + g * 8);
            acc = __builtin_amdgcn_mfma_f32_16x16x32_bf16(xf_h[kk], bh, acc, 0, 0, 0);
            acc = __builtin_amdgcn_mfma_f32_16x16x32_bf16(xf_l[kk], bh, acc, 0, 0, 0);
            acc = __builtin_amdgcn_mfma_f32_16x16x32_bf16(xf_h[kk], bl, acc, 0, 0, 0);
        }
        const float bias = b1[ncol];
#pragma unroll
        for (int r = 0; r < 4; ++r) {
            const int mm = 4 * g + r;
            const float hv = fmaxf(acc[r] + bias, 0.f);
            const ushort hh = f2bf(hv);
            Hh[mm * HSTR + ncol] = hh;
            Hl[mm * HSTR + ncol] = f2bf(hv - bf2f(hh));
        }
    }
    __syncthreads();

    const int obase = wave * 64;
    f32x4 acc2[4];
#pragma unroll
    for (int t = 0; t < 4; ++t) acc2[t] = (f32x4)(0.f);
#pragma unroll 2
    for (int kk = 0; kk < 16; ++kk) {
        const short8 ah = *(const short8*)&Hh[c16 * HSTR + kk * 32 + g * 8];
        const short8 al = *(const short8*)&Hl[c16 * HSTR + kk * 32 + g * 8];
#pragma unroll
        for (int t = 0; t < 4; ++t) {
            const int ncol = obase + t * 16 + c16;
            const short8 bh = *(const short8*)(w2th + (size_t)ncol * DFF + kk * 32 + g * 8);
            const short8 bl = *(const short8*)(w2tl + (size_t)ncol * DFF + kk * 32 + g * 8);
            acc2[t] = __builtin_amdgcn_mfma_f32_16x16x32_bf16(ah, bh, acc2[t], 0, 0, 0);
            acc2[t] = __builtin_amdgcn_mfma_f32_16x16x32_bf16(al, bh, acc2[t], 0, 0, 0);
            acc2[t] = __builtin_amdgcn_mfma_f32_16x16x32_bf16(ah, bl, acc2[t], 0, 0, 0);
        }
    }

#pragma unroll
    for (int t = 0; t < 4; ++t) {
        const int ncol = obase + t * 16 + c16;
#pragma unroll
        for (int r = 0; r < 4; ++r)
            Y[(4 * g + r) * YSTR + ncol] = acc2[t][r];
    }
    __syncthreads();

    const float g0 = gamma[0], b0 = beta[0];
#pragma unroll
    for (int rr = 0; rr < 4; ++rr) {
        const int row = wave * 4 + rr;
        float v[4];
        float sum = 0.f;
#pragma unroll
        for (int j = 0; j < 4; ++j) {
            const int c = lane + 64 * j;
            v[j] = Y[row * YSTR + c] + b2[c] + xin[(size_t)(row0 + row) * DD + c];
            sum += v[j];
        }
#pragma unroll
        for (int m = 32; m >= 1; m >>= 1) sum += __shfl_xor(sum, m);
        const float mean = sum * (1.0f / DD);
        float var = 0.f;
#pragma unroll
        for (int j = 0; j < 4; ++j) { v[j] -= mean; var += v[j] * v[j]; }
#pragma unroll
        for (int m = 32; m >= 1; m >>= 1) var += __shfl_xor(var, m);
        var *= (1.0f / DD);
        const float rstd = 1.0f / sqrtf(var + ln_eps2());
#pragma unroll
        for (int j = 0; j < 4; ++j)
            xout[(size_t)(row0 + row) * DD + lane + 64 * j] = v[j] * rstd * g0 + b0;
    }
}

// ---------------- host launch ----------------
extern "C" void kernel_launch(void* const* d_in, const int* in_sizes, int n_in,
                              void* d_out, int out_size, void* d_ws, size_t ws_size,
                              hipStream_t stream) {
    const float* x     = (const float*)d_in[0];
    const float* Wq    = (const float*)d_in[1];
    const float* Wk    = (const float*)d_in[2];
    const float* Wv    = (const float*)d_in[3];
    const float* Wo    = (const float*)d_in[4];
    const float* W1    = (const float*)d_in[5];
    const float* b1    = (const float*)d_in[6];
    const float* W2    = (const float*)d_in[7];
    const float* b2    = (const float*)d_in[8];
    const float* gamma = (const float*)d_in[9];
    const float* beta  = (const float*)d_in[10];
    float* out = (float*)d_out;

    const size_t NTOK = (size_t)BB * SS * DD;       // 1,048,576
    const size_t WFF  = (size_t)NL * DFF * DD;      // 262,144
    const size_t WOO  = (size_t)NL * DD * DD;       // 131,072
    const size_t WQKV = (size_t)NL * 768 * DD;      // 393,216
    float*  q    = (float*)d_ws;
    ushort* khi  = (ushort*)(q + NTOK);
    ushort* klo  = khi + NTOK;
    ushort* vt   = klo + NTOK;
    float*  o    = (float*)(vt + NTOK);
    float*  xa   = o + NTOK;
    float*  xb   = xa + NTOK;
    ushort* w1th = (ushort*)(xb + NTOK);
    ushort* w1tl = w1th + WFF;
    ushort* w2th = w1tl + WFF;
    ushort* w2tl = w2th + WFF;
    ushort* woth = w2tl + WFF;
    ushort* wotl = woth + WOO;
    ushort* wqth = wotl + WOO;
    ushort* wqtl = wqth + WQKV;
    float*  opart = (float*)(wqtl + WQKV);          // NSPLIT*B*H*S*DVV f32 = 16 MB
    float*  ml    = opart + (size_t)NSPLIT * BB * HH * SS * DVV;  // 1 MB

    wtrans_kernel<<<128, 256, 0, stream>>>(W1, W2, w1th, w1tl, w2th, w2tl);
    wotrans_kernel<<<NL * 16, 256, 0, stream>>>(Wo, woth, wotl);
    wqkv_trans_kernel<<<48, 256, 0, stream>>>(Wq, Wk, Wv, wqth, wqtl);

    const float* cur = x;
    for (int l = 0; l < NL; ++l) {
        qkv_mfma_kernel<<<2 * BB * SS / 16, 256, 0, stream>>>(
            cur, wqth + (size_t)l * 768 * DD, wqtl + (size_t)l * 768 * DD,
            q, khi, klo, vt);
        attn_mfma_kernel<<<BB * HH * (SS / 128) * NSPLIT, 256, 0, stream>>>(
            q, khi, klo, vt, opart, ml);
        attn_merge_kernel<<<BB * HH * (SS / 128), 256, 0, stream>>>(opart, ml, o);
        proj_mfma_kernel<<<BB * SS / 16, 256, 0, stream>>>(
            o, cur, woth + (size_t)l * DD * DD, wotl + (size_t)l * DD * DD,
            gamma + 2 * l, beta + 2 * l, xa);
        float* nxt = (l == NL - 1) ? out : xb;
        ffn_mfma_kernel<<<BB * SS / 16, 256, 0, stream>>>(
            xa, w1th + (size_t)l * DFF * DD, w1tl + (size_t)l * DFF * DD,
            w2th + (size_t)l * DD * DFF, w2tl + (size_t)l * DD * DFF,
            b1 + (size_t)l * DFF, b2 + (size_t)l * DD,
            gamma + 2 * l + 1, beta + 2 * l + 1, nxt);
        cur = nxt;
    }
}